// Round 10
// baseline (5494.420 us; speedup 1.0000x reference)
//
#include <hip/hip_runtime.h>
#include <hip/hip_bf16.h>

#define N_NODES 100000
#define N_EDGES 400000
#define F_NODE_ 64
#define F_EDGE_ 16
#define HID_ 128
#define N_GRAPH 1024
#define N_TASK 5

typedef unsigned short u16;
typedef __attribute__((ext_vector_type(8))) short frag8;   // 8 bf16 = 4 VGPRs
typedef __attribute__((ext_vector_type(4))) float f32x4;   // MFMA C/D

__device__ __forceinline__ float bu2f(u16 v){ return __uint_as_float(((unsigned)v) << 16); }
__device__ __forceinline__ float2 bp2f(unsigned u){
  return make_float2(__uint_as_float(u << 16), __uint_as_float(u & 0xFFFF0000u));
}
__device__ __forceinline__ u16 f2bu(float f){
  __hip_bfloat16 h = __float2bfloat16(f);
  return *(u16*)&h;
}

// ---------------- cast f32 -> bf16 ----------------
__global__ __launch_bounds__(256) void k_cast(const float* __restrict__ s, u16* __restrict__ d, int n){
  int i = blockIdx.x*256 + threadIdx.x;
  if (i < n) d[i] = f2bu(s[i]);
}

// ---------------- pre-swizzle [Wl|Wr] into B-fragment order, bf16 (verified R7) ----------------
__global__ __launch_bounds__(256) void k_wswz2(const float* __restrict__ Wl,
                                               const float* __restrict__ Wr,
                                               u16* __restrict__ Wz, int K){
  int i = blockIdx.x*256 + threadIdx.x;
  if (i >= K*256) return;
  int k = i >> 8, n2 = i & 255;
  int which = n2 >> 7, n = n2 & 127;
  const float* src = which ? Wr : Wl;
  int kk = k & 31, c = k >> 5;
  int quad = kk >> 3, j = kk & 7;
  int nt = which*8 + (n >> 4);
  int lane = quad*16 + (n & 15);
  Wz[(((c*16 + nt)*64) + lane)*8 + j] = f2bu(src[k*128 + n]);
}

// ---------------- LDS-free dual MFMA GEMM: [xl|xr] = A @ [Wl|Wr] + bias ----------------
__global__ __launch_bounds__(256) void k_gemm2(const u16* __restrict__ A,
                                               const u16* __restrict__ Wz,
                                               const float* __restrict__ bl,
                                               const float* __restrict__ br,
                                               u16* __restrict__ Cl,
                                               u16* __restrict__ Cr,
                                               int M, int K){
  const int t = threadIdx.x;
  const int w = t >> 6, l = t & 63;
  const int m = l & 15, quad = l >> 4;
  const int row0 = blockIdx.x*64 + w*16 + m;
  f32x4 acc[16];
  #pragma unroll
  for (int i=0;i<16;i++) acc[i] = (f32x4){0.f,0.f,0.f,0.f};
  const int KC = K >> 5;
  for (int c = 0; c < KC; c++){
    frag8 a = {};
    if (row0 < M) a = *(const frag8*)(A + (size_t)row0*K + c*32 + quad*8);
    #pragma unroll
    for (int nt = 0; nt < 16; nt++){
      frag8 b = *(const frag8*)&Wz[(((c*16 + nt)*64) + l)*8];
      acc[nt] = __builtin_amdgcn_mfma_f32_16x16x32_bf16(a, b, acc[nt], 0,0,0);
    }
  }
  const int rbase = blockIdx.x*64 + w*16 + quad*4;
  #pragma unroll
  for (int nt = 0; nt < 8; nt++){
    int col = nt*16 + m;
    float bc = bl[col];
    #pragma unroll
    for (int r = 0; r < 4; r++){
      int row = rbase + r;
      if (row < M) Cl[(size_t)row*128 + col] = f2bu(acc[nt][r] + bc);
    }
  }
  #pragma unroll
  for (int nt = 8; nt < 16; nt++){
    int col = (nt-8)*16 + m;
    float bc = br[col];
    #pragma unroll
    for (int r = 0; r < 4; r++){
      int row = rbase + r;
      if (row < M) Cr[(size_t)row*128 + col] = f2bu(acc[nt][r] + bc);
    }
  }
}

// ---------------- CSR build (once) ----------------
__global__ __launch_bounds__(256) void k_hist(const int* __restrict__ ei, int* __restrict__ counts){
  int e = blockIdx.x*256 + threadIdx.x;
  if (e < N_EDGES) atomicAdd(&counts[ei[N_EDGES + e]], 1);
}

__global__ __launch_bounds__(512) void k_scan1(const int* __restrict__ counts,
                                               int* __restrict__ incl,
                                               int* __restrict__ bsum){
  __shared__ int s[512];
  const int t = threadIdx.x;
  int i = blockIdx.x*512 + t;
  int v = (i < N_NODES) ? counts[i] : 0;
  s[t] = v;
  __syncthreads();
  for (int off = 1; off < 512; off <<= 1){
    int x = (t >= off) ? s[t - off] : 0;
    __syncthreads();
    s[t] += x;
    __syncthreads();
  }
  if (i < N_NODES) incl[i] = s[t];
  if (t == 511) bsum[blockIdx.x] = s[511];
}

__global__ __launch_bounds__(256) void k_scan2(int* __restrict__ bsum, int nb){
  __shared__ int s[256];
  const int t = threadIdx.x;
  int v = (t < nb) ? bsum[t] : 0;
  s[t] = v;
  __syncthreads();
  for (int off = 1; off < 256; off <<= 1){
    int x = (t >= off) ? s[t - off] : 0;
    __syncthreads();
    s[t] += x;
    __syncthreads();
  }
  if (t < nb) bsum[t] = s[t] - v;
}

__global__ __launch_bounds__(512) void k_scan3(const int* __restrict__ counts,
                                               const int* __restrict__ incl,
                                               const int* __restrict__ bsum,
                                               int* __restrict__ offsets,
                                               int* __restrict__ cursor){
  int i = blockIdx.x*512 + threadIdx.x;
  if (i >= N_NODES) return;
  int o = bsum[blockIdx.x] + incl[i];
  offsets[i + 1] = o;
  cursor[i]      = o - counts[i];
  if (i == 0) offsets[0] = 0;
}

// scatter: src index + bf16 edge features into CSR order
__global__ __launch_bounds__(256) void k_scatter(const int* __restrict__ ei,
                                                 int* __restrict__ cursor,
                                                 int* __restrict__ ssrc,
                                                 const float* __restrict__ ea,
                                                 u16* __restrict__ ea_b){
  int e = blockIdx.x*256 + threadIdx.x;
  if (e >= N_EDGES) return;
  int dst = ei[N_EDGES + e];
  int pos = atomicAdd(&cursor[dst], 1);
  ssrc[pos] = ei[e];
  const float* s = ea + (size_t)e*F_EDGE_;
  u16* d = ea_b + (size_t)pos*F_EDGE_;
  #pragma unroll
  for (int k=0;k<16;k++) d[k] = f2bu(s[k]);
}

// ---------------- Graph CSR from sorted batch (once) ----------------
__global__ __launch_bounds__(256) void k_ghist(const int* __restrict__ batch, int* __restrict__ gcnt){
  int i = blockIdx.x*256 + threadIdx.x;
  if (i < N_NODES) atomicAdd(&gcnt[batch[i]], 1);
}

__global__ __launch_bounds__(1024) void k_gscan(const int* __restrict__ gcnt, int* __restrict__ goff){
  __shared__ int s[1024];
  const int t = threadIdx.x;
  int v = gcnt[t];
  s[t] = v;
  __syncthreads();
  for (int off = 1; off < 1024; off <<= 1){
    int x = (t >= off) ? s[t - off] : 0;
    __syncthreads();
    s[t] += x;
    __syncthreads();
  }
  goff[t + 1] = s[t];
  if (t == 0) goff[0] = 0;
}

// ---------------- Fused GAT v5: shfl-free edge features, fused BN-stats ----------------
// wave per node (4 nodes via stride); ea row loaded wave-uniform as 2x uint4 bf16; no LDS.
#define GAT_GRID 6250
__global__ __launch_bounds__(256) void k_gat(const u16* __restrict__ xl,
                                             const u16* __restrict__ xr,
                                             const u16* __restrict__ ea_b,
                                             const float* __restrict__ We,
                                             const float* __restrict__ att,
                                             const int* __restrict__ offsets,
                                             const int* __restrict__ ssrc,
                                             float* __restrict__ aggr,
                                             float* __restrict__ stats){
  const int t = threadIdx.x;
  const int wave = t >> 6, lane = t & 63;
  const int c0 = lane*2;
  const float a0 = att[c0], a1 = att[c0+1];
  float2 wreg[16];                       // We columns c0,c0+1 (coalesced loads)
  #pragma unroll
  for (int k=0;k<16;k++) wreg[k] = *(const float2*)&We[k*128 + c0];

  float ss0 = 0.f, ss1 = 0.f, sq0 = 0.f, sq1 = 0.f;

  for (int node = blockIdx.x*4 + wave; node < N_NODES; node += GAT_GRID*4){
    const float2 xrv = bp2f(*(const unsigned*)(xr + (size_t)node*HID_ + c0));
    float acc0 = 0.f, acc1 = 0.f, den = 0.f;
    const int beg = offsets[node], end = offsets[node+1];
    for (int i = beg; i < end; i += 4){
      const int mm = end - i;
      const int i1 = (mm > 1) ? i+1 : i;
      const int i2 = (mm > 2) ? i+2 : i;
      const int i3 = (mm > 3) ? i+3 : i;
      // independent loads first: 4 src idx, 4 vl gathers, 8 uniform ea vectors
      int s0 = ssrc[i], s1 = ssrc[i1], s2 = ssrc[i2], s3 = ssrc[i3];
      uint4 ra0 = *(const uint4*)(ea_b + (size_t)i *F_EDGE_);
      uint4 rb0 = *(const uint4*)(ea_b + (size_t)i *F_EDGE_ + 8);
      uint4 ra1 = *(const uint4*)(ea_b + (size_t)i1*F_EDGE_);
      uint4 rb1 = *(const uint4*)(ea_b + (size_t)i1*F_EDGE_ + 8);
      uint4 ra2 = *(const uint4*)(ea_b + (size_t)i2*F_EDGE_);
      uint4 rb2 = *(const uint4*)(ea_b + (size_t)i2*F_EDGE_ + 8);
      uint4 ra3 = *(const uint4*)(ea_b + (size_t)i3*F_EDGE_);
      uint4 rb3 = *(const uint4*)(ea_b + (size_t)i3*F_EDGE_ + 8);
      float2 vl0 = bp2f(*(const unsigned*)(xl + (size_t)s0*HID_ + c0));
      float2 vl1 = bp2f(*(const unsigned*)(xl + (size_t)s1*HID_ + c0));
      float2 vl2 = bp2f(*(const unsigned*)(xl + (size_t)s2*HID_ + c0));
      float2 vl3 = bp2f(*(const unsigned*)(xl + (size_t)s3*HID_ + c0));
      float e00=0.f,e01=0.f,e10=0.f,e11=0.f,e20=0.f,e21=0.f,e30=0.f,e31=0.f;
      #define EEK(u, kk, ee_a, ee_b) { float2 p = bp2f(u); \
        ee_a += p.x*wreg[kk].x + p.y*wreg[kk+1].x; \
        ee_b += p.x*wreg[kk].y + p.y*wreg[kk+1].y; }
      EEK(ra0.x, 0, e00,e01) EEK(ra0.y, 2, e00,e01) EEK(ra0.z, 4, e00,e01) EEK(ra0.w, 6, e00,e01)
      EEK(rb0.x, 8, e00,e01) EEK(rb0.y,10, e00,e01) EEK(rb0.z,12, e00,e01) EEK(rb0.w,14, e00,e01)
      EEK(ra1.x, 0, e10,e11) EEK(ra1.y, 2, e10,e11) EEK(ra1.z, 4, e10,e11) EEK(ra1.w, 6, e10,e11)
      EEK(rb1.x, 8, e10,e11) EEK(rb1.y,10, e10,e11) EEK(rb1.z,12, e10,e11) EEK(rb1.w,14, e10,e11)
      EEK(ra2.x, 0, e20,e21) EEK(ra2.y, 2, e20,e21) EEK(ra2.z, 4, e20,e21) EEK(ra2.w, 6, e20,e21)
      EEK(rb2.x, 8, e20,e21) EEK(rb2.y,10, e20,e21) EEK(rb2.z,12, e20,e21) EEK(rb2.w,14, e20,e21)
      EEK(ra3.x, 0, e30,e31) EEK(ra3.y, 2, e30,e31) EEK(ra3.z, 4, e30,e31) EEK(ra3.w, 6, e30,e31)
      EEK(rb3.x, 8, e30,e31) EEK(rb3.y,10, e30,e31) EEK(rb3.z,12, e30,e31) EEK(rb3.w,14, e30,e31)
      #undef EEK
      float v00 = vl0.x + xrv.x + e00, v01 = vl0.y + xrv.y + e01;
      float v10 = vl1.x + xrv.x + e10, v11 = vl1.y + xrv.y + e11;
      float v20 = vl2.x + xrv.x + e20, v21 = vl2.y + xrv.y + e21;
      float v30 = vl3.x + xrv.x + e30, v31 = vl3.y + xrv.y + e31;
      v00 = v00 > 0.f ? v00 : 0.2f*v00;  v01 = v01 > 0.f ? v01 : 0.2f*v01;
      v10 = v10 > 0.f ? v10 : 0.2f*v10;  v11 = v11 > 0.f ? v11 : 0.2f*v11;
      v20 = v20 > 0.f ? v20 : 0.2f*v20;  v21 = v21 > 0.f ? v21 : 0.2f*v21;
      v30 = v30 > 0.f ? v30 : 0.2f*v30;  v31 = v31 > 0.f ? v31 : 0.2f*v31;
      float sc0 = v00*a0 + v01*a1;
      float sc1 = v10*a0 + v11*a1;
      float sc2 = v20*a0 + v21*a1;
      float sc3 = v30*a0 + v31*a1;
      sc0 += __shfl_xor(sc0, 1); sc1 += __shfl_xor(sc1, 1); sc2 += __shfl_xor(sc2, 1); sc3 += __shfl_xor(sc3, 1);
      sc0 += __shfl_xor(sc0, 2); sc1 += __shfl_xor(sc1, 2); sc2 += __shfl_xor(sc2, 2); sc3 += __shfl_xor(sc3, 2);
      sc0 += __shfl_xor(sc0, 4); sc1 += __shfl_xor(sc1, 4); sc2 += __shfl_xor(sc2, 4); sc3 += __shfl_xor(sc3, 4);
      sc0 += __shfl_xor(sc0, 8); sc1 += __shfl_xor(sc1, 8); sc2 += __shfl_xor(sc2, 8); sc3 += __shfl_xor(sc3, 8);
      float p0 = __expf(sc0);
      float p1 = (mm > 1) ? __expf(sc1) : 0.f;
      float p2 = (mm > 2) ? __expf(sc2) : 0.f;
      float p3 = (mm > 3) ? __expf(sc3) : 0.f;
      acc0 += p0*vl0.x + p1*vl1.x + p2*vl2.x + p3*vl3.x;
      acc1 += p0*vl0.y + p1*vl1.y + p2*vl2.y + p3*vl3.y;
      den  += p0 + p1 + p2 + p3;
    }
    float inv = 1.0f / (den + 1e-16f);
    float o0 = acc0*inv, o1 = acc1*inv;
    *(float2*)(aggr + (size_t)node*HID_ + c0) = make_float2(o0, o1);
    ss0 += o0; ss1 += o1; sq0 += o0*o0; sq1 += o1*o1;
  }
  // fused BN-stats: one set of atomics per wave
  atomicAdd(&stats[c0],       ss0);
  atomicAdd(&stats[c0+1],     ss1);
  atomicAdd(&stats[128+c0],   sq0);
  atomicAdd(&stats[128+c0+1], sq1);
}

// ---------------- BN apply + ELU (+ residual), h in bf16 ----------------
__global__ __launch_bounds__(256) void k_bn_apply(const float* __restrict__ aggr,
                                                  const float* __restrict__ stats,
                                                  const float* __restrict__ gamma,
                                                  const float* __restrict__ beta,
                                                  u16* __restrict__ h, int residual){
  size_t i = (size_t)blockIdx.x*256 + threadIdx.x;
  if (i >= (size_t)N_NODES*HID_) return;
  int c = i & 127;
  const float invn = 1.0f / (float)N_NODES;
  float mu  = stats[c] * invn;
  float var = stats[128+c] * invn - mu*mu;
  float sc  = rsqrtf(var + 1e-5f) * gamma[c];
  float val = (aggr[i] - mu) * sc + beta[c];
  val = val > 0.f ? val : expm1f(val);
  if (residual) val += bu2f(h[i]);
  h[i] = f2bu(val);
}

// ---------------- Pool: segmented mean over sorted batch ----------------
__global__ __launch_bounds__(128) void k_pool_seg(const u16* __restrict__ h,
                                                  const int* __restrict__ goff,
                                                  float* __restrict__ emb){
  const int g = blockIdx.x, c = threadIdx.x;
  const int beg = goff[g], end = goff[g+1];
  float acc = 0.f;
  for (int r = beg; r < end; r++) acc += bu2f(h[(size_t)r*HID_ + c]);
  float n = (float)(end - beg);
  emb[(size_t)g*HID_ + c] = acc / fmaxf(n, 1.f);
}

// ---------------- Per-task heads ----------------
__global__ __launch_bounds__(128) void k_heads(const float* __restrict__ emb,
                                               const float* __restrict__ mf,
                                               const int* __restrict__ fpi,
                                               const float* __restrict__ tw1,
                                               const float* __restrict__ tb1,
                                               const float* __restrict__ tw2,
                                               const float* __restrict__ tb2,
                                               float* __restrict__ out){
  const int g = blockIdx.x, task = blockIdx.y;
  const int j = threadIdx.x;
  __shared__ float fused[160];
  __shared__ float red[128];
  fused[j] = emb[(size_t)g*HID_ + j];
  if (j < 32){
    int bit = fpi[task*32 + j];
    fused[128 + j] = mf[(size_t)g*2048 + bit];
  }
  __syncthreads();
  const float* w1 = tw1 + (size_t)task*160*128;
  float acc = tb1[task*128 + j];
  #pragma unroll 8
  for (int i=0;i<160;i++) acc += fused[i] * w1[(size_t)i*128 + j];
  acc = acc > 0.f ? acc : 0.f;
  acc *= tw2[task*128 + j];
  red[j] = acc;
  __syncthreads();
  for (int s=64; s>0; s>>=1){
    if (j < s) red[j] += red[j+s];
    __syncthreads();
  }
  if (j == 0) out[(size_t)g*N_TASK + task] = red[0] + tb2[task];
}

extern "C" void kernel_launch(void* const* d_in, const int* in_sizes, int n_in,
                              void* d_out, int out_size, void* d_ws, size_t ws_size,
                              hipStream_t stream){
  const float* x    = (const float*)d_in[0];
  const int*   ei   = (const int*)  d_in[1];
  const float* ea   = (const float*)d_in[2];
  const int*   batch= (const int*)  d_in[3];
  const float* mf   = (const float*)d_in[4];
  const int*   fpi  = (const int*)  d_in[5];
  const float* Wl0  = (const float*)d_in[6];
  const float* bl0  = (const float*)d_in[7];
  const float* Wr0  = (const float*)d_in[8];
  const float* br0  = (const float*)d_in[9];
  const float* We0  = (const float*)d_in[10];
  const float* att0 = (const float*)d_in[11];
  const float* g0   = (const float*)d_in[13];
  const float* b0   = (const float*)d_in[14];
  const float* Wl   = (const float*)d_in[15];
  const float* bl   = (const float*)d_in[16];
  const float* Wr   = (const float*)d_in[17];
  const float* br   = (const float*)d_in[18];
  const float* We   = (const float*)d_in[19];
  const float* att  = (const float*)d_in[20];
  const float* gg   = (const float*)d_in[22];
  const float* bb   = (const float*)d_in[23];
  const float* tw1  = (const float*)d_in[24];
  const float* tb1  = (const float*)d_in[25];
  const float* tw2  = (const float*)d_in[26];
  const float* tb2  = (const float*)d_in[27];
  float* out = (float*)d_out;

  char* w = (char*)d_ws;
  auto alloc = [&](size_t bytes)->char*{ char* r = w; w += (bytes + 255) & ~(size_t)255; return r; };
  u16*   xl     = (u16*)  alloc((size_t)N_NODES*HID_*2);
  u16*   xr     = (u16*)  alloc((size_t)N_NODES*HID_*2);
  u16*   h      = (u16*)  alloc((size_t)N_NODES*HID_*2);
  u16*   xbf    = (u16*)  alloc((size_t)N_NODES*F_NODE_*2);
  float* aggr   = (float*)alloc((size_t)N_NODES*HID_*4);
  float* stats  = (float*)alloc(256*4);
  float* emb    = (float*)alloc((size_t)N_GRAPH*HID_*4);
  int*   counts = (int*)  alloc((size_t)N_NODES*4);
  int*   offsets= (int*)  alloc((size_t)(N_NODES+1)*4);
  int*   cursor = (int*)  alloc((size_t)N_NODES*4);
  int*   incl   = (int*)  alloc((size_t)N_NODES*4);
  int*   bsum   = (int*)  alloc(256*4);
  int*   ssrc   = (int*)  alloc((size_t)N_EDGES*4);
  u16*   ea_b   = (u16*)  alloc((size_t)N_EDGES*F_EDGE_*2);
  int*   gcnt   = (int*)  alloc((size_t)N_GRAPH*4);
  int*   goff   = (int*)  alloc((size_t)(N_GRAPH+1)*4);
  u16*   Wz0    = (u16*)  alloc((size_t)F_NODE_*256*2);      // K=64 swizzled [Wl0|Wr0]
  u16*   Wz123  = (u16*)  alloc((size_t)3*HID_*256*2);       // K=128 swizzled per layer

  const int eg256 = (N_EDGES + 255)/256;
  const int ng256 = (N_NODES + 255)/256;
  const int nscan = (N_NODES + 511)/512;
  const int gemm_grid = (N_NODES + 63)/64;

  // one-time: input cast + weight pre-swizzles
  hipLaunchKernelGGL(k_cast, dim3((N_NODES*F_NODE_ + 255)/256), dim3(256), 0, stream, x, xbf, N_NODES*F_NODE_);
  hipLaunchKernelGGL(k_wswz2, dim3((F_NODE_*256 + 255)/256), dim3(256), 0, stream, Wl0, Wr0, Wz0, F_NODE_);
  for (int i=0;i<3;i++)
    hipLaunchKernelGGL(k_wswz2, dim3((HID_*256 + 255)/256), dim3(256), 0, stream,
                       Wl + (size_t)i*HID_*HID_, Wr + (size_t)i*HID_*HID_,
                       Wz123 + (size_t)i*HID_*256, HID_);

  // CSR build (topology constant across layers) + graph offsets
  hipMemsetAsync(counts, 0, (size_t)N_NODES*4, stream);
  hipMemsetAsync(gcnt,   0, (size_t)N_GRAPH*4, stream);
  hipLaunchKernelGGL(k_hist,    dim3(eg256), dim3(256), 0, stream, ei, counts);
  hipLaunchKernelGGL(k_ghist,   dim3(ng256), dim3(256), 0, stream, batch, gcnt);
  hipLaunchKernelGGL(k_scan1,   dim3(nscan), dim3(512), 0, stream, counts, incl, bsum);
  hipLaunchKernelGGL(k_scan2,   dim3(1),     dim3(256), 0, stream, bsum, nscan);
  hipLaunchKernelGGL(k_scan3,   dim3(nscan), dim3(512), 0, stream, counts, incl, bsum, offsets, cursor);
  hipLaunchKernelGGL(k_gscan,   dim3(1),     dim3(1024),0, stream, gcnt, goff);
  hipLaunchKernelGGL(k_scatter, dim3(eg256), dim3(256), 0, stream, ei, cursor, ssrc, ea, ea_b);

  for (int layer = 0; layer < 4; layer++){
    const float *bl_, *br_, *We_, *att_, *g_, *b_;
    const u16 *Wz_, *Ain;
    int K;
    if (layer == 0){
      bl_=bl0; br_=br0; We_=We0; att_=att0; g_=g0; b_=b0;
      Wz_ = Wz0; Ain = xbf; K = F_NODE_;
    } else {
      int i = layer - 1;
      bl_ = bl + (size_t)i*HID_;  br_ = br + (size_t)i*HID_;
      We_ = We + (size_t)i*F_EDGE_*HID_;
      att_= att + (size_t)i*HID_;
      g_  = gg + (size_t)i*HID_;  b_  = bb + (size_t)i*HID_;
      Wz_ = Wz123 + (size_t)i*HID_*256;
      Ain = h; K = HID_;
    }
    hipLaunchKernelGGL(k_gemm2, dim3(gemm_grid), dim3(256), 0, stream, Ain, Wz_, bl_, br_, xl, xr, N_NODES, K);
    hipMemsetAsync(stats, 0, 256*4, stream);
    hipLaunchKernelGGL(k_gat, dim3(GAT_GRID), dim3(256), 0, stream,
                       xl, xr, ea_b, We_, att_, offsets, ssrc, aggr, stats);
    hipLaunchKernelGGL(k_bn_apply, dim3((N_NODES*HID_ + 255)/256), dim3(256), 0, stream,
                       aggr, stats, g_, b_, h, layer > 0 ? 1 : 0);
  }
  hipLaunchKernelGGL(k_pool_seg, dim3(N_GRAPH), dim3(128), 0, stream, h, goff, emb);
  hipLaunchKernelGGL(k_heads, dim3(N_GRAPH, N_TASK), dim3(128), 0, stream, emb, mf, fpi, tw1, tb1, tw2, tb2, out);
}

// Round 11
// 1360.874 us; speedup vs baseline: 4.0374x; 4.0374x over previous
//
#include <hip/hip_runtime.h>
#include <hip/hip_bf16.h>

#define N_NODES 100000
#define N_EDGES 400000
#define F_NODE_ 64
#define F_EDGE_ 16
#define HID_ 128
#define N_GRAPH 1024
#define N_TASK 5

typedef unsigned short u16;
typedef __attribute__((ext_vector_type(8))) short frag8;   // 8 bf16 = 4 VGPRs
typedef __attribute__((ext_vector_type(4))) float f32x4;   // MFMA C/D

__device__ __forceinline__ float bu2f(u16 v){ return __uint_as_float(((unsigned)v) << 16); }
__device__ __forceinline__ float2 bp2f(unsigned u){
  return make_float2(__uint_as_float(u << 16), __uint_as_float(u & 0xFFFF0000u));
}
__device__ __forceinline__ u16 f2bu(float f){
  __hip_bfloat16 h = __float2bfloat16(f);
  return *(u16*)&h;
}

// ---------------- cast f32 -> bf16 ----------------
__global__ __launch_bounds__(256) void k_cast(const float* __restrict__ s, u16* __restrict__ d, int n){
  int i = blockIdx.x*256 + threadIdx.x;
  if (i < n) d[i] = f2bu(s[i]);
}

// ---------------- pre-swizzle [Wl|Wr] into B-fragment order, bf16 (verified R7) ----------------
__global__ __launch_bounds__(256) void k_wswz2(const float* __restrict__ Wl,
                                               const float* __restrict__ Wr,
                                               u16* __restrict__ Wz, int K){
  int i = blockIdx.x*256 + threadIdx.x;
  if (i >= K*256) return;
  int k = i >> 8, n2 = i & 255;
  int which = n2 >> 7, n = n2 & 127;
  const float* src = which ? Wr : Wl;
  int kk = k & 31, c = k >> 5;
  int quad = kk >> 3, j = kk & 7;
  int nt = which*8 + (n >> 4);
  int lane = quad*16 + (n & 15);
  Wz[(((c*16 + nt)*64) + lane)*8 + j] = f2bu(src[k*128 + n]);
}

// ---------------- dual MFMA GEMM, LDS-staged B: [xl|xr] = A @ [Wl|Wr] + bias ----------------
// Wz is pre-swizzled to exact fragment read order -> LDS stage is a flat copy (16B vectors).
// block 256 = 4 waves; wave handles 16 rows x 256 cols; grid = ceil(M/64).
__global__ __launch_bounds__(256) void k_gemm2(const u16* __restrict__ A,
                                               const u16* __restrict__ Wz,
                                               const float* __restrict__ bl,
                                               const float* __restrict__ br,
                                               u16* __restrict__ Cl,
                                               u16* __restrict__ Cr,
                                               int M, int K){
  __shared__ u16 WS[128*256];   // 64 KB at K=128 (K=64 uses half)
  const int t = threadIdx.x;
  {
    const uint4* src = (const uint4*)Wz;
    uint4* dst = (uint4*)WS;
    const int n = (K*256) >> 3;
    for (int i = t; i < n; i += 256) dst[i] = src[i];
  }
  __syncthreads();
  const int w = t >> 6, l = t & 63;
  const int m = l & 15, quad = l >> 4;
  const int row0 = blockIdx.x*64 + w*16 + m;
  f32x4 acc[16];
  #pragma unroll
  for (int i=0;i<16;i++) acc[i] = (f32x4){0.f,0.f,0.f,0.f};
  const int KC = K >> 5;
  for (int c = 0; c < KC; c++){
    frag8 a = {};
    if (row0 < M) a = *(const frag8*)(A + (size_t)row0*K + c*32 + quad*8);
    #pragma unroll
    for (int nt = 0; nt < 16; nt++){
      frag8 b = *(const frag8*)&WS[(((c*16 + nt)*64) + l)*8];
      acc[nt] = __builtin_amdgcn_mfma_f32_16x16x32_bf16(a, b, acc[nt], 0,0,0);
    }
  }
  const int rbase = blockIdx.x*64 + w*16 + quad*4;
  #pragma unroll
  for (int nt = 0; nt < 8; nt++){
    int col = nt*16 + m;
    float bc = bl[col];
    #pragma unroll
    for (int r = 0; r < 4; r++){
      int row = rbase + r;
      if (row < M) Cl[(size_t)row*128 + col] = f2bu(acc[nt][r] + bc);
    }
  }
  #pragma unroll
  for (int nt = 8; nt < 16; nt++){
    int col = (nt-8)*16 + m;
    float bc = br[col];
    #pragma unroll
    for (int r = 0; r < 4; r++){
      int row = rbase + r;
      if (row < M) Cr[(size_t)row*128 + col] = f2bu(acc[nt][r] + bc);
    }
  }
}

// ---------------- CSR build (once) ----------------
__global__ __launch_bounds__(256) void k_hist(const int* __restrict__ ei, int* __restrict__ counts){
  int e = blockIdx.x*256 + threadIdx.x;
  if (e < N_EDGES) atomicAdd(&counts[ei[N_EDGES + e]], 1);
}

__global__ __launch_bounds__(512) void k_scan1(const int* __restrict__ counts,
                                               int* __restrict__ incl,
                                               int* __restrict__ bsum){
  __shared__ int s[512];
  const int t = threadIdx.x;
  int i = blockIdx.x*512 + t;
  int v = (i < N_NODES) ? counts[i] : 0;
  s[t] = v;
  __syncthreads();
  for (int off = 1; off < 512; off <<= 1){
    int x = (t >= off) ? s[t - off] : 0;
    __syncthreads();
    s[t] += x;
    __syncthreads();
  }
  if (i < N_NODES) incl[i] = s[t];
  if (t == 511) bsum[blockIdx.x] = s[511];
}

__global__ __launch_bounds__(256) void k_scan2(int* __restrict__ bsum, int nb){
  __shared__ int s[256];
  const int t = threadIdx.x;
  int v = (t < nb) ? bsum[t] : 0;
  s[t] = v;
  __syncthreads();
  for (int off = 1; off < 256; off <<= 1){
    int x = (t >= off) ? s[t - off] : 0;
    __syncthreads();
    s[t] += x;
    __syncthreads();
  }
  if (t < nb) bsum[t] = s[t] - v;
}

__global__ __launch_bounds__(512) void k_scan3(const int* __restrict__ counts,
                                               const int* __restrict__ incl,
                                               const int* __restrict__ bsum,
                                               int* __restrict__ offsets,
                                               int* __restrict__ cursor){
  int i = blockIdx.x*512 + threadIdx.x;
  if (i >= N_NODES) return;
  int o = bsum[blockIdx.x] + incl[i];
  offsets[i + 1] = o;
  cursor[i]      = o - counts[i];
  if (i == 0) offsets[0] = 0;
}

// scatter: src index + edge features (f32) into CSR order
__global__ __launch_bounds__(256) void k_scatter(const int* __restrict__ ei,
                                                 int* __restrict__ cursor,
                                                 int* __restrict__ ssrc,
                                                 const float* __restrict__ ea,
                                                 float* __restrict__ ea_s){
  int e = blockIdx.x*256 + threadIdx.x;
  if (e >= N_EDGES) return;
  int dst = ei[N_EDGES + e];
  int pos = atomicAdd(&cursor[dst], 1);
  ssrc[pos] = ei[e];
  const float4* s4 = (const float4*)(ea + (size_t)e*F_EDGE_);
  float4* d4 = (float4*)(ea_s + (size_t)pos*F_EDGE_);
  d4[0] = s4[0]; d4[1] = s4[1]; d4[2] = s4[2]; d4[3] = s4[3];
}

// ---------------- Graph CSR from sorted batch (once) ----------------
__global__ __launch_bounds__(256) void k_ghist(const int* __restrict__ batch, int* __restrict__ gcnt){
  int i = blockIdx.x*256 + threadIdx.x;
  if (i < N_NODES) atomicAdd(&gcnt[batch[i]], 1);
}

__global__ __launch_bounds__(1024) void k_gscan(const int* __restrict__ gcnt, int* __restrict__ goff){
  __shared__ int s[1024];
  const int t = threadIdx.x;
  int v = gcnt[t];
  s[t] = v;
  __syncthreads();
  for (int off = 1; off < 1024; off <<= 1){
    int x = (t >= off) ? s[t - off] : 0;
    __syncthreads();
    s[t] += x;
    __syncthreads();
  }
  goff[t + 1] = s[t];
  if (t == 0) goff[0] = 0;
}

// ---------------- Fused GAT (R9-proven): per-dst-node softmax + aggregation ----------------
#define GAT_GRID 3125
__global__ __launch_bounds__(256) void k_gat(const u16* __restrict__ xl,
                                             const u16* __restrict__ xr,
                                             const float* __restrict__ ea_s,
                                             const float* __restrict__ We,
                                             const float* __restrict__ att,
                                             const int* __restrict__ offsets,
                                             const int* __restrict__ ssrc,
                                             float* __restrict__ aggr){
  __shared__ float WeS[16*128];
  __shared__ float attS[128];
  const int t = threadIdx.x;
  for (int i=t;i<16*128;i+=256) WeS[i] = We[i];
  if (t < 128) attS[t] = att[t];
  __syncthreads();
  const int wave = t >> 6, lane = t & 63;
  const int c0 = lane*2;
  const int el = lane & 15;
  const float a0 = attS[c0], a1 = attS[c0+1];
  float2 wreg[16];
  #pragma unroll
  for (int k=0;k<16;k++) wreg[k] = *(const float2*)&WeS[k*128 + c0];

  for (int node = blockIdx.x*4 + wave; node < N_NODES; node += GAT_GRID*4){
    const float2 xrv = bp2f(*(const unsigned*)(xr + (size_t)node*HID_ + c0));
    float acc0 = 0.f, acc1 = 0.f, den = 0.f;
    const int beg = offsets[node], end = offsets[node+1];
    for (int i = beg; i < end; i += 4){
      const int mm = end - i;
      const int i1 = (mm > 1) ? i+1 : i;
      const int i2 = (mm > 2) ? i+2 : i;
      const int i3 = (mm > 3) ? i+3 : i;
      int s0 = ssrc[i], s1 = ssrc[i1], s2 = ssrc[i2], s3 = ssrc[i3];
      float av0 = ea_s[(size_t)i *F_EDGE_ + el];
      float av1 = ea_s[(size_t)i1*F_EDGE_ + el];
      float av2 = ea_s[(size_t)i2*F_EDGE_ + el];
      float av3 = ea_s[(size_t)i3*F_EDGE_ + el];
      float2 vl0 = bp2f(*(const unsigned*)(xl + (size_t)s0*HID_ + c0));
      float2 vl1 = bp2f(*(const unsigned*)(xl + (size_t)s1*HID_ + c0));
      float2 vl2 = bp2f(*(const unsigned*)(xl + (size_t)s2*HID_ + c0));
      float2 vl3 = bp2f(*(const unsigned*)(xl + (size_t)s3*HID_ + c0));
      float e00=0.f,e01=0.f,e10=0.f,e11=0.f,e20=0.f,e21=0.f,e30=0.f,e31=0.f;
      #pragma unroll
      for (int k=0;k<16;k++){
        float b0 = __shfl(av0, k);
        float b1 = __shfl(av1, k);
        float b2 = __shfl(av2, k);
        float b3 = __shfl(av3, k);
        e00 += b0*wreg[k].x; e01 += b0*wreg[k].y;
        e10 += b1*wreg[k].x; e11 += b1*wreg[k].y;
        e20 += b2*wreg[k].x; e21 += b2*wreg[k].y;
        e30 += b3*wreg[k].x; e31 += b3*wreg[k].y;
      }
      float v00 = vl0.x + xrv.x + e00, v01 = vl0.y + xrv.y + e01;
      float v10 = vl1.x + xrv.x + e10, v11 = vl1.y + xrv.y + e11;
      float v20 = vl2.x + xrv.x + e20, v21 = vl2.y + xrv.y + e21;
      float v30 = vl3.x + xrv.x + e30, v31 = vl3.y + xrv.y + e31;
      v00 = v00 > 0.f ? v00 : 0.2f*v00;  v01 = v01 > 0.f ? v01 : 0.2f*v01;
      v10 = v10 > 0.f ? v10 : 0.2f*v10;  v11 = v11 > 0.f ? v11 : 0.2f*v11;
      v20 = v20 > 0.f ? v20 : 0.2f*v20;  v21 = v21 > 0.f ? v21 : 0.2f*v21;
      v30 = v30 > 0.f ? v30 : 0.2f*v30;  v31 = v31 > 0.f ? v31 : 0.2f*v31;
      float sc0 = v00*a0 + v01*a1;
      float sc1 = v10*a0 + v11*a1;
      float sc2 = v20*a0 + v21*a1;
      float sc3 = v30*a0 + v31*a1;
      sc0 += __shfl_xor(sc0, 1); sc1 += __shfl_xor(sc1, 1); sc2 += __shfl_xor(sc2, 1); sc3 += __shfl_xor(sc3, 1);
      sc0 += __shfl_xor(sc0, 2); sc1 += __shfl_xor(sc1, 2); sc2 += __shfl_xor(sc2, 2); sc3 += __shfl_xor(sc3, 2);
      sc0 += __shfl_xor(sc0, 4); sc1 += __shfl_xor(sc1, 4); sc2 += __shfl_xor(sc2, 4); sc3 += __shfl_xor(sc3, 4);
      sc0 += __shfl_xor(sc0, 8); sc1 += __shfl_xor(sc1, 8); sc2 += __shfl_xor(sc2, 8); sc3 += __shfl_xor(sc3, 8);
      float p0 = __expf(sc0);
      float p1 = (mm > 1) ? __expf(sc1) : 0.f;
      float p2 = (mm > 2) ? __expf(sc2) : 0.f;
      float p3 = (mm > 3) ? __expf(sc3) : 0.f;
      acc0 += p0*vl0.x + p1*vl1.x + p2*vl2.x + p3*vl3.x;
      acc1 += p0*vl0.y + p1*vl1.y + p2*vl2.y + p3*vl3.y;
      den  += p0 + p1 + p2 + p3;
    }
    float inv = 1.0f / (den + 1e-16f);
    *(float2*)(aggr + (size_t)node*HID_ + c0) = make_float2(acc0*inv, acc1*inv);
  }
}

// ---------------- BN stats ----------------
__global__ __launch_bounds__(256) void k_bn_stats(const float* __restrict__ aggr,
                                                  float* __restrict__ stats){
  __shared__ float redS[256], redS2[256];
  const int t = threadIdx.x;
  const int c = t & 127, half = t >> 7;
  float s = 0.f, s2 = 0.f;
  for (int r = blockIdx.x*2 + half; r < N_NODES; r += gridDim.x*2){
    float v = aggr[(size_t)r*HID_ + c];
    s += v; s2 += v*v;
  }
  redS[t] = s; redS2[t] = s2;
  __syncthreads();
  if (half == 0){
    s  += redS[t+128];
    s2 += redS2[t+128];
    atomicAdd(&stats[c], s);
    atomicAdd(&stats[128+c], s2);
  }
}

// ---------------- BN apply + ELU (+ residual), h in bf16 ----------------
__global__ __launch_bounds__(256) void k_bn_apply(const float* __restrict__ aggr,
                                                  const float* __restrict__ stats,
                                                  const float* __restrict__ gamma,
                                                  const float* __restrict__ beta,
                                                  u16* __restrict__ h, int residual){
  size_t i = (size_t)blockIdx.x*256 + threadIdx.x;
  if (i >= (size_t)N_NODES*HID_) return;
  int c = i & 127;
  const float invn = 1.0f / (float)N_NODES;
  float mu  = stats[c] * invn;
  float var = stats[128+c] * invn - mu*mu;
  float sc  = rsqrtf(var + 1e-5f) * gamma[c];
  float val = (aggr[i] - mu) * sc + beta[c];
  val = val > 0.f ? val : expm1f(val);
  if (residual) val += bu2f(h[i]);
  h[i] = f2bu(val);
}

// ---------------- Pool: segmented mean over sorted batch ----------------
__global__ __launch_bounds__(128) void k_pool_seg(const u16* __restrict__ h,
                                                  const int* __restrict__ goff,
                                                  float* __restrict__ emb){
  const int g = blockIdx.x, c = threadIdx.x;
  const int beg = goff[g], end = goff[g+1];
  float acc = 0.f;
  for (int r = beg; r < end; r++) acc += bu2f(h[(size_t)r*HID_ + c]);
  float n = (float)(end - beg);
  emb[(size_t)g*HID_ + c] = acc / fmaxf(n, 1.f);
}

// ---------------- Per-task heads ----------------
__global__ __launch_bounds__(128) void k_heads(const float* __restrict__ emb,
                                               const float* __restrict__ mf,
                                               const int* __restrict__ fpi,
                                               const float* __restrict__ tw1,
                                               const float* __restrict__ tb1,
                                               const float* __restrict__ tw2,
                                               const float* __restrict__ tb2,
                                               float* __restrict__ out){
  const int g = blockIdx.x, task = blockIdx.y;
  const int j = threadIdx.x;
  __shared__ float fused[160];
  __shared__ float red[128];
  fused[j] = emb[(size_t)g*HID_ + j];
  if (j < 32){
    int bit = fpi[task*32 + j];
    fused[128 + j] = mf[(size_t)g*2048 + bit];
  }
  __syncthreads();
  const float* w1 = tw1 + (size_t)task*160*128;
  float acc = tb1[task*128 + j];
  #pragma unroll 8
  for (int i=0;i<160;i++) acc += fused[i] * w1[(size_t)i*128 + j];
  acc = acc > 0.f ? acc : 0.f;
  acc *= tw2[task*128 + j];
  red[j] = acc;
  __syncthreads();
  for (int s=64; s>0; s>>=1){
    if (j < s) red[j] += red[j+s];
    __syncthreads();
  }
  if (j == 0) out[(size_t)g*N_TASK + task] = red[0] + tb2[task];
}

extern "C" void kernel_launch(void* const* d_in, const int* in_sizes, int n_in,
                              void* d_out, int out_size, void* d_ws, size_t ws_size,
                              hipStream_t stream){
  const float* x    = (const float*)d_in[0];
  const int*   ei   = (const int*)  d_in[1];
  const float* ea   = (const float*)d_in[2];
  const int*   batch= (const int*)  d_in[3];
  const float* mf   = (const float*)d_in[4];
  const int*   fpi  = (const int*)  d_in[5];
  const float* Wl0  = (const float*)d_in[6];
  const float* bl0  = (const float*)d_in[7];
  const float* Wr0  = (const float*)d_in[8];
  const float* br0  = (const float*)d_in[9];
  const float* We0  = (const float*)d_in[10];
  const float* att0 = (const float*)d_in[11];
  const float* g0   = (const float*)d_in[13];
  const float* b0   = (const float*)d_in[14];
  const float* Wl   = (const float*)d_in[15];
  const float* bl   = (const float*)d_in[16];
  const float* Wr   = (const float*)d_in[17];
  const float* br   = (const float*)d_in[18];
  const float* We   = (const float*)d_in[19];
  const float* att  = (const float*)d_in[20];
  const float* gg   = (const float*)d_in[22];
  const float* bb   = (const float*)d_in[23];
  const float* tw1  = (const float*)d_in[24];
  const float* tb1  = (const float*)d_in[25];
  const float* tw2  = (const float*)d_in[26];
  const float* tb2  = (const float*)d_in[27];
  float* out = (float*)d_out;

  char* w = (char*)d_ws;
  auto alloc = [&](size_t bytes)->char*{ char* r = w; w += (bytes + 255) & ~(size_t)255; return r; };
  u16*   xl     = (u16*)  alloc((size_t)N_NODES*HID_*2);
  u16*   xr     = (u16*)  alloc((size_t)N_NODES*HID_*2);
  u16*   h      = (u16*)  alloc((size_t)N_NODES*HID_*2);
  u16*   xbf    = (u16*)  alloc((size_t)N_NODES*F_NODE_*2);
  float* aggr   = (float*)alloc((size_t)N_NODES*HID_*4);
  float* stats  = (float*)alloc(256*4);
  float* emb    = (float*)alloc((size_t)N_GRAPH*HID_*4);
  int*   counts = (int*)  alloc((size_t)N_NODES*4);
  int*   offsets= (int*)  alloc((size_t)(N_NODES+1)*4);
  int*   cursor = (int*)  alloc((size_t)N_NODES*4);
  int*   incl   = (int*)  alloc((size_t)N_NODES*4);
  int*   bsum   = (int*)  alloc(256*4);
  int*   ssrc   = (int*)  alloc((size_t)N_EDGES*4);
  float* ea_s   = (float*)alloc((size_t)N_EDGES*F_EDGE_*4);
  int*   gcnt   = (int*)  alloc((size_t)N_GRAPH*4);
  int*   goff   = (int*)  alloc((size_t)(N_GRAPH+1)*4);
  u16*   Wz0    = (u16*)  alloc((size_t)F_NODE_*256*2);      // K=64 swizzled [Wl0|Wr0]
  u16*   Wz123  = (u16*)  alloc((size_t)3*HID_*256*2);       // K=128 swizzled per layer

  const int eg256 = (N_EDGES + 255)/256;
  const int ng256 = (N_NODES + 255)/256;
  const int nscan = (N_NODES + 511)/512;
  const int gemm_grid = (N_NODES + 63)/64;

  // one-time: input cast + weight pre-swizzles
  hipLaunchKernelGGL(k_cast, dim3((N_NODES*F_NODE_ + 255)/256), dim3(256), 0, stream, x, xbf, N_NODES*F_NODE_);
  hipLaunchKernelGGL(k_wswz2, dim3((F_NODE_*256 + 255)/256), dim3(256), 0, stream, Wl0, Wr0, Wz0, F_NODE_);
  for (int i=0;i<3;i++)
    hipLaunchKernelGGL(k_wswz2, dim3((HID_*256 + 255)/256), dim3(256), 0, stream,
                       Wl + (size_t)i*HID_*HID_, Wr + (size_t)i*HID_*HID_,
                       Wz123 + (size_t)i*HID_*256, HID_);

  // CSR build (topology constant across layers) + graph offsets
  hipMemsetAsync(counts, 0, (size_t)N_NODES*4, stream);
  hipMemsetAsync(gcnt,   0, (size_t)N_GRAPH*4, stream);
  hipLaunchKernelGGL(k_hist,    dim3(eg256), dim3(256), 0, stream, ei, counts);
  hipLaunchKernelGGL(k_ghist,   dim3(ng256), dim3(256), 0, stream, batch, gcnt);
  hipLaunchKernelGGL(k_scan1,   dim3(nscan), dim3(512), 0, stream, counts, incl, bsum);
  hipLaunchKernelGGL(k_scan2,   dim3(1),     dim3(256), 0, stream, bsum, nscan);
  hipLaunchKernelGGL(k_scan3,   dim3(nscan), dim3(512), 0, stream, counts, incl, bsum, offsets, cursor);
  hipLaunchKernelGGL(k_gscan,   dim3(1),     dim3(1024),0, stream, gcnt, goff);
  hipLaunchKernelGGL(k_scatter, dim3(eg256), dim3(256), 0, stream, ei, cursor, ssrc, ea, ea_s);

  for (int layer = 0; layer < 4; layer++){
    const float *bl_, *br_, *We_, *att_, *g_, *b_;
    const u16 *Wz_, *Ain;
    int K;
    if (layer == 0){
      bl_=bl0; br_=br0; We_=We0; att_=att0; g_=g0; b_=b0;
      Wz_ = Wz0; Ain = xbf; K = F_NODE_;
    } else {
      int i = layer - 1;
      bl_ = bl + (size_t)i*HID_;  br_ = br + (size_t)i*HID_;
      We_ = We + (size_t)i*F_EDGE_*HID_;
      att_= att + (size_t)i*HID_;
      g_  = gg + (size_t)i*HID_;  b_  = bb + (size_t)i*HID_;
      Wz_ = Wz123 + (size_t)i*HID_*256;
      Ain = h; K = HID_;
    }
    hipLaunchKernelGGL(k_gemm2, dim3(gemm_grid), dim3(256), 0, stream, Ain, Wz_, bl_, br_, xl, xr, N_NODES, K);
    hipMemsetAsync(stats, 0, 256*4, stream);
    hipLaunchKernelGGL(k_gat, dim3(GAT_GRID), dim3(256), 0, stream,
                       xl, xr, ea_s, We_, att_, offsets, ssrc, aggr);
    hipLaunchKernelGGL(k_bn_stats, dim3(512), dim3(256), 0, stream, aggr, stats);
    hipLaunchKernelGGL(k_bn_apply, dim3((N_NODES*HID_ + 255)/256), dim3(256), 0, stream,
                       aggr, stats, g_, b_, h, layer > 0 ? 1 : 0);
  }
  hipLaunchKernelGGL(k_pool_seg, dim3(N_GRAPH), dim3(128), 0, stream, h, goff, emb);
  hipLaunchKernelGGL(k_heads, dim3(N_GRAPH, N_TASK), dim3(128), 0, stream, emb, mf, fpi, tw1, tb1, tw2, tb2, out);
}

// Round 12
// 1227.098 us; speedup vs baseline: 4.4776x; 1.1090x over previous
//
#include <hip/hip_runtime.h>
#include <hip/hip_bf16.h>

#define N_NODES 100000
#define N_EDGES 400000
#define F_NODE_ 64
#define F_EDGE_ 16
#define HID_ 128
#define N_GRAPH 1024
#define N_TASK 5

typedef unsigned short u16;
typedef __attribute__((ext_vector_type(8))) short frag8;   // 8 bf16 = 4 VGPRs
typedef __attribute__((ext_vector_type(4))) float f32x4;   // MFMA C/D

__device__ __forceinline__ float bu2f(u16 v){ return __uint_as_float(((unsigned)v) << 16); }
__device__ __forceinline__ float2 bp2f(unsigned u){
  return make_float2(__uint_as_float(u << 16), __uint_as_float(u & 0xFFFF0000u));
}
__device__ __forceinline__ u16 f2bu(float f){
  __hip_bfloat16 h = __float2bfloat16(f);
  return *(u16*)&h;
}

// ---------------- cast f32 -> bf16 ----------------
__global__ __launch_bounds__(256) void k_cast(const float* __restrict__ s, u16* __restrict__ d, int n){
  int i = blockIdx.x*256 + threadIdx.x;
  if (i < n) d[i] = f2bu(s[i]);
}

// ---------------- pre-swizzle [Wl|Wr] into B-fragment order, bf16 (verified R7) ----------------
__global__ __launch_bounds__(256) void k_wswz2(const float* __restrict__ Wl,
                                               const float* __restrict__ Wr,
                                               u16* __restrict__ Wz, int K){
  int i = blockIdx.x*256 + threadIdx.x;
  if (i >= K*256) return;
  int k = i >> 8, n2 = i & 255;
  int which = n2 >> 7, n = n2 & 127;
  const float* src = which ? Wr : Wl;
  int kk = k & 31, c = k >> 5;
  int quad = kk >> 3, j = kk & 7;
  int nt = which*8 + (n >> 4);
  int lane = quad*16 + (n & 15);
  Wz[(((c*16 + nt)*64) + lane)*8 + j] = f2bu(src[k*128 + n]);
}

// ---------------- dual MFMA GEMM, LDS-staged B: [xl|xr] = A @ [Wl|Wr] + bias ----------------
__global__ __launch_bounds__(256) void k_gemm2(const u16* __restrict__ A,
                                               const u16* __restrict__ Wz,
                                               const float* __restrict__ bl,
                                               const float* __restrict__ br,
                                               u16* __restrict__ Cl,
                                               u16* __restrict__ Cr,
                                               int M, int K){
  __shared__ u16 WS[128*256];   // 64 KB at K=128 (K=64 uses half)
  const int t = threadIdx.x;
  {
    const uint4* src = (const uint4*)Wz;
    uint4* dst = (uint4*)WS;
    const int n = (K*256) >> 3;
    for (int i = t; i < n; i += 256) dst[i] = src[i];
  }
  __syncthreads();
  const int w = t >> 6, l = t & 63;
  const int m = l & 15, quad = l >> 4;
  const int row0 = blockIdx.x*64 + w*16 + m;
  f32x4 acc[16];
  #pragma unroll
  for (int i=0;i<16;i++) acc[i] = (f32x4){0.f,0.f,0.f,0.f};
  const int KC = K >> 5;
  for (int c = 0; c < KC; c++){
    frag8 a = {};
    if (row0 < M) a = *(const frag8*)(A + (size_t)row0*K + c*32 + quad*8);
    #pragma unroll
    for (int nt = 0; nt < 16; nt++){
      frag8 b = *(const frag8*)&WS[(((c*16 + nt)*64) + l)*8];
      acc[nt] = __builtin_amdgcn_mfma_f32_16x16x32_bf16(a, b, acc[nt], 0,0,0);
    }
  }
  const int rbase = blockIdx.x*64 + w*16 + quad*4;
  #pragma unroll
  for (int nt = 0; nt < 8; nt++){
    int col = nt*16 + m;
    float bc = bl[col];
    #pragma unroll
    for (int r = 0; r < 4; r++){
      int row = rbase + r;
      if (row < M) Cl[(size_t)row*128 + col] = f2bu(acc[nt][r] + bc);
    }
  }
  #pragma unroll
  for (int nt = 8; nt < 16; nt++){
    int col = (nt-8)*16 + m;
    float bc = br[col];
    #pragma unroll
    for (int r = 0; r < 4; r++){
      int row = rbase + r;
      if (row < M) Cr[(size_t)row*128 + col] = f2bu(acc[nt][r] + bc);
    }
  }
}

// ---------------- CSR build (once) ----------------
__global__ __launch_bounds__(256) void k_hist(const int* __restrict__ ei, int* __restrict__ counts){
  int e = blockIdx.x*256 + threadIdx.x;
  if (e < N_EDGES) atomicAdd(&counts[ei[N_EDGES + e]], 1);
}

__global__ __launch_bounds__(512) void k_scan1(const int* __restrict__ counts,
                                               int* __restrict__ incl,
                                               int* __restrict__ bsum){
  __shared__ int s[512];
  const int t = threadIdx.x;
  int i = blockIdx.x*512 + t;
  int v = (i < N_NODES) ? counts[i] : 0;
  s[t] = v;
  __syncthreads();
  for (int off = 1; off < 512; off <<= 1){
    int x = (t >= off) ? s[t - off] : 0;
    __syncthreads();
    s[t] += x;
    __syncthreads();
  }
  if (i < N_NODES) incl[i] = s[t];
  if (t == 511) bsum[blockIdx.x] = s[511];
}

__global__ __launch_bounds__(256) void k_scan2(int* __restrict__ bsum, int nb){
  __shared__ int s[256];
  const int t = threadIdx.x;
  int v = (t < nb) ? bsum[t] : 0;
  s[t] = v;
  __syncthreads();
  for (int off = 1; off < 256; off <<= 1){
    int x = (t >= off) ? s[t - off] : 0;
    __syncthreads();
    s[t] += x;
    __syncthreads();
  }
  if (t < nb) bsum[t] = s[t] - v;
}

__global__ __launch_bounds__(512) void k_scan3(const int* __restrict__ counts,
                                               const int* __restrict__ incl,
                                               const int* __restrict__ bsum,
                                               int* __restrict__ offsets,
                                               int* __restrict__ cursor){
  int i = blockIdx.x*512 + threadIdx.x;
  if (i >= N_NODES) return;
  int o = bsum[blockIdx.x] + incl[i];
  offsets[i + 1] = o;
  cursor[i]      = o - counts[i];
  if (i == 0) offsets[0] = 0;
}

// scatter: src index + bf16 edge features into CSR order
__global__ __launch_bounds__(256) void k_scatter(const int* __restrict__ ei,
                                                 int* __restrict__ cursor,
                                                 int* __restrict__ ssrc,
                                                 const float* __restrict__ ea,
                                                 u16* __restrict__ ea_b){
  int e = blockIdx.x*256 + threadIdx.x;
  if (e >= N_EDGES) return;
  int dst = ei[N_EDGES + e];
  int pos = atomicAdd(&cursor[dst], 1);
  ssrc[pos] = ei[e];
  const float* s = ea + (size_t)e*F_EDGE_;
  u16* d = ea_b + (size_t)pos*F_EDGE_;
  #pragma unroll
  for (int k=0;k<16;k++) d[k] = f2bu(s[k]);
}

// ---------------- Graph CSR from sorted batch (once) ----------------
__global__ __launch_bounds__(256) void k_ghist(const int* __restrict__ batch, int* __restrict__ gcnt){
  int i = blockIdx.x*256 + threadIdx.x;
  if (i < N_NODES) atomicAdd(&gcnt[batch[i]], 1);
}

__global__ __launch_bounds__(1024) void k_gscan(const int* __restrict__ gcnt, int* __restrict__ goff){
  __shared__ int s[1024];
  const int t = threadIdx.x;
  int v = gcnt[t];
  s[t] = v;
  __syncthreads();
  for (int off = 1; off < 1024; off <<= 1){
    int x = (t >= off) ? s[t - off] : 0;
    __syncthreads();
    s[t] += x;
    __syncthreads();
  }
  goff[t + 1] = s[t];
  if (t == 0) goff[0] = 0;
}

// ---------------- Fused GAT v6: shfl-free ea (wave-uniform bf16 loads), no LDS, no fused stats ----------------
#define GAT_GRID 6250
__global__ __launch_bounds__(256) void k_gat(const u16* __restrict__ xl,
                                             const u16* __restrict__ xr,
                                             const u16* __restrict__ ea_b,
                                             const float* __restrict__ We,
                                             const float* __restrict__ att,
                                             const int* __restrict__ offsets,
                                             const int* __restrict__ ssrc,
                                             float* __restrict__ aggr){
  const int t = threadIdx.x;
  const int wave = t >> 6, lane = t & 63;
  const int c0 = lane*2;
  const float a0 = att[c0], a1 = att[c0+1];
  float2 wreg[16];                       // We columns c0,c0+1 (coalesced loads)
  #pragma unroll
  for (int k=0;k<16;k++) wreg[k] = *(const float2*)&We[k*128 + c0];

  for (int node = blockIdx.x*4 + wave; node < N_NODES; node += GAT_GRID*4){
    const float2 xrv = bp2f(*(const unsigned*)(xr + (size_t)node*HID_ + c0));
    float acc0 = 0.f, acc1 = 0.f, den = 0.f;
    const int beg = offsets[node], end = offsets[node+1];
    for (int i = beg; i < end; i += 4){
      const int mm = end - i;
      const int i1 = (mm > 1) ? i+1 : i;
      const int i2 = (mm > 2) ? i+2 : i;
      const int i3 = (mm > 3) ? i+3 : i;
      // independent loads first: 4 src idx, 4 vl gathers, 8 uniform ea vectors
      int s0 = ssrc[i], s1 = ssrc[i1], s2 = ssrc[i2], s3 = ssrc[i3];
      uint4 ra0 = *(const uint4*)(ea_b + (size_t)i *F_EDGE_);
      uint4 rb0 = *(const uint4*)(ea_b + (size_t)i *F_EDGE_ + 8);
      uint4 ra1 = *(const uint4*)(ea_b + (size_t)i1*F_EDGE_);
      uint4 rb1 = *(const uint4*)(ea_b + (size_t)i1*F_EDGE_ + 8);
      uint4 ra2 = *(const uint4*)(ea_b + (size_t)i2*F_EDGE_);
      uint4 rb2 = *(const uint4*)(ea_b + (size_t)i2*F_EDGE_ + 8);
      uint4 ra3 = *(const uint4*)(ea_b + (size_t)i3*F_EDGE_);
      uint4 rb3 = *(const uint4*)(ea_b + (size_t)i3*F_EDGE_ + 8);
      float2 vl0 = bp2f(*(const unsigned*)(xl + (size_t)s0*HID_ + c0));
      float2 vl1 = bp2f(*(const unsigned*)(xl + (size_t)s1*HID_ + c0));
      float2 vl2 = bp2f(*(const unsigned*)(xl + (size_t)s2*HID_ + c0));
      float2 vl3 = bp2f(*(const unsigned*)(xl + (size_t)s3*HID_ + c0));
      float e00=0.f,e01=0.f,e10=0.f,e11=0.f,e20=0.f,e21=0.f,e30=0.f,e31=0.f;
      #define EEK(u, kk, ee_a, ee_b) { float2 p = bp2f(u); \
        ee_a += p.x*wreg[kk].x + p.y*wreg[kk+1].x; \
        ee_b += p.x*wreg[kk].y + p.y*wreg[kk+1].y; }
      EEK(ra0.x, 0, e00,e01) EEK(ra0.y, 2, e00,e01) EEK(ra0.z, 4, e00,e01) EEK(ra0.w, 6, e00,e01)
      EEK(rb0.x, 8, e00,e01) EEK(rb0.y,10, e00,e01) EEK(rb0.z,12, e00,e01) EEK(rb0.w,14, e00,e01)
      EEK(ra1.x, 0, e10,e11) EEK(ra1.y, 2, e10,e11) EEK(ra1.z, 4, e10,e11) EEK(ra1.w, 6, e10,e11)
      EEK(rb1.x, 8, e10,e11) EEK(rb1.y,10, e10,e11) EEK(rb1.z,12, e10,e11) EEK(rb1.w,14, e10,e11)
      EEK(ra2.x, 0, e20,e21) EEK(ra2.y, 2, e20,e21) EEK(ra2.z, 4, e20,e21) EEK(ra2.w, 6, e20,e21)
      EEK(rb2.x, 8, e20,e21) EEK(rb2.y,10, e20,e21) EEK(rb2.z,12, e20,e21) EEK(rb2.w,14, e20,e21)
      EEK(ra3.x, 0, e30,e31) EEK(ra3.y, 2, e30,e31) EEK(ra3.z, 4, e30,e31) EEK(ra3.w, 6, e30,e31)
      EEK(rb3.x, 8, e30,e31) EEK(rb3.y,10, e30,e31) EEK(rb3.z,12, e30,e31) EEK(rb3.w,14, e30,e31)
      #undef EEK
      float v00 = vl0.x + xrv.x + e00, v01 = vl0.y + xrv.y + e01;
      float v10 = vl1.x + xrv.x + e10, v11 = vl1.y + xrv.y + e11;
      float v20 = vl2.x + xrv.x + e20, v21 = vl2.y + xrv.y + e21;
      float v30 = vl3.x + xrv.x + e30, v31 = vl3.y + xrv.y + e31;
      v00 = v00 > 0.f ? v00 : 0.2f*v00;  v01 = v01 > 0.f ? v01 : 0.2f*v01;
      v10 = v10 > 0.f ? v10 : 0.2f*v10;  v11 = v11 > 0.f ? v11 : 0.2f*v11;
      v20 = v20 > 0.f ? v20 : 0.2f*v20;  v21 = v21 > 0.f ? v21 : 0.2f*v21;
      v30 = v30 > 0.f ? v30 : 0.2f*v30;  v31 = v31 > 0.f ? v31 : 0.2f*v31;
      float sc0 = v00*a0 + v01*a1;
      float sc1 = v10*a0 + v11*a1;
      float sc2 = v20*a0 + v21*a1;
      float sc3 = v30*a0 + v31*a1;
      sc0 += __shfl_xor(sc0, 1); sc1 += __shfl_xor(sc1, 1); sc2 += __shfl_xor(sc2, 1); sc3 += __shfl_xor(sc3, 1);
      sc0 += __shfl_xor(sc0, 2); sc1 += __shfl_xor(sc1, 2); sc2 += __shfl_xor(sc2, 2); sc3 += __shfl_xor(sc3, 2);
      sc0 += __shfl_xor(sc0, 4); sc1 += __shfl_xor(sc1, 4); sc2 += __shfl_xor(sc2, 4); sc3 += __shfl_xor(sc3, 4);
      sc0 += __shfl_xor(sc0, 8); sc1 += __shfl_xor(sc1, 8); sc2 += __shfl_xor(sc2, 8); sc3 += __shfl_xor(sc3, 8);
      float p0 = __expf(sc0);
      float p1 = (mm > 1) ? __expf(sc1) : 0.f;
      float p2 = (mm > 2) ? __expf(sc2) : 0.f;
      float p3 = (mm > 3) ? __expf(sc3) : 0.f;
      acc0 += p0*vl0.x + p1*vl1.x + p2*vl2.x + p3*vl3.x;
      acc1 += p0*vl0.y + p1*vl1.y + p2*vl2.y + p3*vl3.y;
      den  += p0 + p1 + p2 + p3;
    }
    float inv = 1.0f / (den + 1e-16f);
    *(float2*)(aggr + (size_t)node*HID_ + c0) = make_float2(acc0*inv, acc1*inv);
  }
}

// ---------------- BN stats ----------------
__global__ __launch_bounds__(256) void k_bn_stats(const float* __restrict__ aggr,
                                                  float* __restrict__ stats){
  __shared__ float redS[256], redS2[256];
  const int t = threadIdx.x;
  const int c = t & 127, half = t >> 7;
  float s = 0.f, s2 = 0.f;
  for (int r = blockIdx.x*2 + half; r < N_NODES; r += gridDim.x*2){
    float v = aggr[(size_t)r*HID_ + c];
    s += v; s2 += v*v;
  }
  redS[t] = s; redS2[t] = s2;
  __syncthreads();
  if (half == 0){
    s  += redS[t+128];
    s2 += redS2[t+128];
    atomicAdd(&stats[c], s);
    atomicAdd(&stats[128+c], s2);
  }
}

// ---------------- BN apply + ELU (+ residual), h in bf16 ----------------
__global__ __launch_bounds__(256) void k_bn_apply(const float* __restrict__ aggr,
                                                  const float* __restrict__ stats,
                                                  const float* __restrict__ gamma,
                                                  const float* __restrict__ beta,
                                                  u16* __restrict__ h, int residual){
  size_t i = (size_t)blockIdx.x*256 + threadIdx.x;
  if (i >= (size_t)N_NODES*HID_) return;
  int c = i & 127;
  const float invn = 1.0f / (float)N_NODES;
  float mu  = stats[c] * invn;
  float var = stats[128+c] * invn - mu*mu;
  float sc  = rsqrtf(var + 1e-5f) * gamma[c];
  float val = (aggr[i] - mu) * sc + beta[c];
  val = val > 0.f ? val : expm1f(val);
  if (residual) val += bu2f(h[i]);
  h[i] = f2bu(val);
}

// ---------------- Pool: segmented mean over sorted batch ----------------
__global__ __launch_bounds__(128) void k_pool_seg(const u16* __restrict__ h,
                                                  const int* __restrict__ goff,
                                                  float* __restrict__ emb){
  const int g = blockIdx.x, c = threadIdx.x;
  const int beg = goff[g], end = goff[g+1];
  float acc = 0.f;
  for (int r = beg; r < end; r++) acc += bu2f(h[(size_t)r*HID_ + c]);
  float n = (float)(end - beg);
  emb[(size_t)g*HID_ + c] = acc / fmaxf(n, 1.f);
}

// ---------------- Per-task heads ----------------
__global__ __launch_bounds__(128) void k_heads(const float* __restrict__ emb,
                                               const float* __restrict__ mf,
                                               const int* __restrict__ fpi,
                                               const float* __restrict__ tw1,
                                               const float* __restrict__ tb1,
                                               const float* __restrict__ tw2,
                                               const float* __restrict__ tb2,
                                               float* __restrict__ out){
  const int g = blockIdx.x, task = blockIdx.y;
  const int j = threadIdx.x;
  __shared__ float fused[160];
  __shared__ float red[128];
  fused[j] = emb[(size_t)g*HID_ + j];
  if (j < 32){
    int bit = fpi[task*32 + j];
    fused[128 + j] = mf[(size_t)g*2048 + bit];
  }
  __syncthreads();
  const float* w1 = tw1 + (size_t)task*160*128;
  float acc = tb1[task*128 + j];
  #pragma unroll 8
  for (int i=0;i<160;i++) acc += fused[i] * w1[(size_t)i*128 + j];
  acc = acc > 0.f ? acc : 0.f;
  acc *= tw2[task*128 + j];
  red[j] = acc;
  __syncthreads();
  for (int s=64; s>0; s>>=1){
    if (j < s) red[j] += red[j+s];
    __syncthreads();
  }
  if (j == 0) out[(size_t)g*N_TASK + task] = red[0] + tb2[task];
}

extern "C" void kernel_launch(void* const* d_in, const int* in_sizes, int n_in,
                              void* d_out, int out_size, void* d_ws, size_t ws_size,
                              hipStream_t stream){
  const float* x    = (const float*)d_in[0];
  const int*   ei   = (const int*)  d_in[1];
  const float* ea   = (const float*)d_in[2];
  const int*   batch= (const int*)  d_in[3];
  const float* mf   = (const float*)d_in[4];
  const int*   fpi  = (const int*)  d_in[5];
  const float* Wl0  = (const float*)d_in[6];
  const float* bl0  = (const float*)d_in[7];
  const float* Wr0  = (const float*)d_in[8];
  const float* br0  = (const float*)d_in[9];
  const float* We0  = (const float*)d_in[10];
  const float* att0 = (const float*)d_in[11];
  const float* g0   = (const float*)d_in[13];
  const float* b0   = (const float*)d_in[14];
  const float* Wl   = (const float*)d_in[15];
  const float* bl   = (const float*)d_in[16];
  const float* Wr   = (const float*)d_in[17];
  const float* br   = (const float*)d_in[18];
  const float* We   = (const float*)d_in[19];
  const float* att  = (const float*)d_in[20];
  const float* gg   = (const float*)d_in[22];
  const float* bb   = (const float*)d_in[23];
  const float* tw1  = (const float*)d_in[24];
  const float* tb1  = (const float*)d_in[25];
  const float* tw2  = (const float*)d_in[26];
  const float* tb2  = (const float*)d_in[27];
  float* out = (float*)d_out;

  char* w = (char*)d_ws;
  auto alloc = [&](size_t bytes)->char*{ char* r = w; w += (bytes + 255) & ~(size_t)255; return r; };
  u16*   xl     = (u16*)  alloc((size_t)N_NODES*HID_*2);
  u16*   xr     = (u16*)  alloc((size_t)N_NODES*HID_*2);
  u16*   h      = (u16*)  alloc((size_t)N_NODES*HID_*2);
  u16*   xbf    = (u16*)  alloc((size_t)N_NODES*F_NODE_*2);
  float* aggr   = (float*)alloc((size_t)N_NODES*HID_*4);
  float* stats  = (float*)alloc(256*4);
  float* emb    = (float*)alloc((size_t)N_GRAPH*HID_*4);
  int*   counts = (int*)  alloc((size_t)N_NODES*4);
  int*   offsets= (int*)  alloc((size_t)(N_NODES+1)*4);
  int*   cursor = (int*)  alloc((size_t)N_NODES*4);
  int*   incl   = (int*)  alloc((size_t)N_NODES*4);
  int*   bsum   = (int*)  alloc(256*4);
  int*   ssrc   = (int*)  alloc((size_t)N_EDGES*4);
  u16*   ea_b   = (u16*)  alloc((size_t)N_EDGES*F_EDGE_*2);
  int*   gcnt   = (int*)  alloc((size_t)N_GRAPH*4);
  int*   goff   = (int*)  alloc((size_t)(N_GRAPH+1)*4);
  u16*   Wz0    = (u16*)  alloc((size_t)F_NODE_*256*2);      // K=64 swizzled [Wl0|Wr0]
  u16*   Wz123  = (u16*)  alloc((size_t)3*HID_*256*2);       // K=128 swizzled per layer

  const int eg256 = (N_EDGES + 255)/256;
  const int ng256 = (N_NODES + 255)/256;
  const int nscan = (N_NODES + 511)/512;
  const int gemm_grid = (N_NODES + 63)/64;

  // one-time: input cast + weight pre-swizzles
  hipLaunchKernelGGL(k_cast, dim3((N_NODES*F_NODE_ + 255)/256), dim3(256), 0, stream, x, xbf, N_NODES*F_NODE_);
  hipLaunchKernelGGL(k_wswz2, dim3((F_NODE_*256 + 255)/256), dim3(256), 0, stream, Wl0, Wr0, Wz0, F_NODE_);
  for (int i=0;i<3;i++)
    hipLaunchKernelGGL(k_wswz2, dim3((HID_*256 + 255)/256), dim3(256), 0, stream,
                       Wl + (size_t)i*HID_*HID_, Wr + (size_t)i*HID_*HID_,
                       Wz123 + (size_t)i*HID_*256, HID_);

  // CSR build (topology constant across layers) + graph offsets
  hipMemsetAsync(counts, 0, (size_t)N_NODES*4, stream);
  hipMemsetAsync(gcnt,   0, (size_t)N_GRAPH*4, stream);
  hipLaunchKernelGGL(k_hist,    dim3(eg256), dim3(256), 0, stream, ei, counts);
  hipLaunchKernelGGL(k_ghist,   dim3(ng256), dim3(256), 0, stream, batch, gcnt);
  hipLaunchKernelGGL(k_scan1,   dim3(nscan), dim3(512), 0, stream, counts, incl, bsum);
  hipLaunchKernelGGL(k_scan2,   dim3(1),     dim3(256), 0, stream, bsum, nscan);
  hipLaunchKernelGGL(k_scan3,   dim3(nscan), dim3(512), 0, stream, counts, incl, bsum, offsets, cursor);
  hipLaunchKernelGGL(k_gscan,   dim3(1),     dim3(1024),0, stream, gcnt, goff);
  hipLaunchKernelGGL(k_scatter, dim3(eg256), dim3(256), 0, stream, ei, cursor, ssrc, ea, ea_b);

  for (int layer = 0; layer < 4; layer++){
    const float *bl_, *br_, *We_, *att_, *g_, *b_;
    const u16 *Wz_, *Ain;
    int K;
    if (layer == 0){
      bl_=bl0; br_=br0; We_=We0; att_=att0; g_=g0; b_=b0;
      Wz_ = Wz0; Ain = xbf; K = F_NODE_;
    } else {
      int i = layer - 1;
      bl_ = bl + (size_t)i*HID_;  br_ = br + (size_t)i*HID_;
      We_ = We + (size_t)i*F_EDGE_*HID_;
      att_= att + (size_t)i*HID_;
      g_  = gg + (size_t)i*HID_;  b_  = bb + (size_t)i*HID_;
      Wz_ = Wz123 + (size_t)i*HID_*256;
      Ain = h; K = HID_;
    }
    hipLaunchKernelGGL(k_gemm2, dim3(gemm_grid), dim3(256), 0, stream, Ain, Wz_, bl_, br_, xl, xr, N_NODES, K);
    hipMemsetAsync(stats, 0, 256*4, stream);
    hipLaunchKernelGGL(k_gat, dim3(GAT_GRID), dim3(256), 0, stream,
                       xl, xr, ea_b, We_, att_, offsets, ssrc, aggr);
    hipLaunchKernelGGL(k_bn_stats, dim3(512), dim3(256), 0, stream, aggr, stats);
    hipLaunchKernelGGL(k_bn_apply, dim3((N_NODES*HID_ + 255)/256), dim3(256), 0, stream,
                       aggr, stats, g_, b_, h, layer > 0 ? 1 : 0);
  }
  hipLaunchKernelGGL(k_pool_seg, dim3(N_GRAPH), dim3(128), 0, stream, h, goff, emb);
  hipLaunchKernelGGL(k_heads, dim3(N_GRAPH, N_TASK), dim3(128), 0, stream, emb, mf, fpi, tw1, tb1, tw2, tb2, out);
}

// Round 13
// 1183.010 us; speedup vs baseline: 4.6444x; 1.0373x over previous
//
#include <hip/hip_runtime.h>
#include <hip/hip_bf16.h>

#define N_NODES 100000
#define N_EDGES 400000
#define F_NODE_ 64
#define F_EDGE_ 16
#define HID_ 128
#define N_GRAPH 1024
#define N_TASK 5

typedef unsigned short u16;
typedef __attribute__((ext_vector_type(8))) short frag8;   // 8 bf16 = 4 VGPRs
typedef __attribute__((ext_vector_type(4))) float f32x4;   // MFMA C/D

__device__ __forceinline__ float bu2f(u16 v){ return __uint_as_float(((unsigned)v) << 16); }
__device__ __forceinline__ float2 bp2f(unsigned u){
  return make_float2(__uint_as_float(u << 16), __uint_as_float(u & 0xFFFF0000u));
}
__device__ __forceinline__ u16 f2bu(float f){
  __hip_bfloat16 h = __float2bfloat16(f);
  return *(u16*)&h;
}

// ---------------- cast f32 -> bf16 ----------------
__global__ __launch_bounds__(256) void k_cast(const float* __restrict__ s, u16* __restrict__ d, int n){
  int i = blockIdx.x*256 + threadIdx.x;
  if (i < n) d[i] = f2bu(s[i]);
}

// ---------------- pre-swizzle one W (K x 128, f32) into B-fragment order, bf16 ----------------
// B-frag mapping (verified R7): lane = quad*16 + (n&15), j = k&7, quad = (k&31)>>3, chunk c = k>>5
// Wz[(((c*8 + nt)*64) + lane)*8 + j], nt = n>>4
__global__ __launch_bounds__(256) void k_wswz1(const float* __restrict__ W,
                                               u16* __restrict__ Wz, int K){
  int i = blockIdx.x*256 + threadIdx.x;
  if (i >= K*128) return;
  int k = i >> 7, n = i & 127;
  int kk = k & 31, c = k >> 5;
  int quad = kk >> 3, j = kk & 7;
  int nt = n >> 4;
  int lane = quad*16 + (n & 15);
  Wz[(((c*8 + nt)*64) + lane)*8 + j] = f2bu(W[k*128 + n]);
}

// ---------------- single-output MFMA GEMM, 32KB LDS: C = A @ W + bias ----------------
// 256 thr = 4 waves; 64 rows/block (16/wave); acc = 8 f32x4 (32 VGPR) -> high occupancy.
__global__ __launch_bounds__(256) void k_gemm1(const u16* __restrict__ A,
                                               const u16* __restrict__ Wz,
                                               const float* __restrict__ bias,
                                               u16* __restrict__ C,
                                               int M, int K){
  __shared__ u16 WS[128*128];   // 32 KB at K=128; K=64 uses 16 KB
  const int t = threadIdx.x;
  {
    const uint4* src = (const uint4*)Wz;
    uint4* dst = (uint4*)WS;
    const int n = (K*128) >> 3;
    for (int i = t; i < n; i += 256) dst[i] = src[i];
  }
  __syncthreads();
  const int w = t >> 6, l = t & 63;
  const int m = l & 15, quad = l >> 4;
  const int row0 = blockIdx.x*64 + w*16 + m;
  f32x4 acc[8];
  #pragma unroll
  for (int i=0;i<8;i++) acc[i] = (f32x4){0.f,0.f,0.f,0.f};
  const int KC = K >> 5;
  for (int c = 0; c < KC; c++){
    frag8 a = {};
    if (row0 < M) a = *(const frag8*)(A + (size_t)row0*K + c*32 + quad*8);
    #pragma unroll
    for (int nt = 0; nt < 8; nt++){
      frag8 b = *(const frag8*)&WS[(((c*8 + nt)*64) + l)*8];
      acc[nt] = __builtin_amdgcn_mfma_f32_16x16x32_bf16(a, b, acc[nt], 0,0,0);
    }
  }
  const int rbase = blockIdx.x*64 + w*16 + quad*4;
  #pragma unroll
  for (int nt = 0; nt < 8; nt++){
    int col = nt*16 + m;
    float bc = bias[col];
    #pragma unroll
    for (int r = 0; r < 4; r++){
      int row = rbase + r;
      if (row < M) C[(size_t)row*128 + col] = f2bu(acc[nt][r] + bc);
    }
  }
}

// ---------------- CSR build (once) ----------------
__global__ __launch_bounds__(256) void k_hist(const int* __restrict__ ei, int* __restrict__ counts){
  int e = blockIdx.x*256 + threadIdx.x;
  if (e < N_EDGES) atomicAdd(&counts[ei[N_EDGES + e]], 1);
}

__global__ __launch_bounds__(512) void k_scan1(const int* __restrict__ counts,
                                               int* __restrict__ incl,
                                               int* __restrict__ bsum){
  __shared__ int s[512];
  const int t = threadIdx.x;
  int i = blockIdx.x*512 + t;
  int v = (i < N_NODES) ? counts[i] : 0;
  s[t] = v;
  __syncthreads();
  for (int off = 1; off < 512; off <<= 1){
    int x = (t >= off) ? s[t - off] : 0;
    __syncthreads();
    s[t] += x;
    __syncthreads();
  }
  if (i < N_NODES) incl[i] = s[t];
  if (t == 511) bsum[blockIdx.x] = s[511];
}

__global__ __launch_bounds__(256) void k_scan2(int* __restrict__ bsum, int nb){
  __shared__ int s[256];
  const int t = threadIdx.x;
  int v = (t < nb) ? bsum[t] : 0;
  s[t] = v;
  __syncthreads();
  for (int off = 1; off < 256; off <<= 1){
    int x = (t >= off) ? s[t - off] : 0;
    __syncthreads();
    s[t] += x;
    __syncthreads();
  }
  if (t < nb) bsum[t] = s[t] - v;
}

__global__ __launch_bounds__(512) void k_scan3(const int* __restrict__ counts,
                                               const int* __restrict__ incl,
                                               const int* __restrict__ bsum,
                                               int* __restrict__ offsets,
                                               int* __restrict__ cursor){
  int i = blockIdx.x*512 + threadIdx.x;
  if (i >= N_NODES) return;
  int o = bsum[blockIdx.x] + incl[i];
  offsets[i + 1] = o;
  cursor[i]      = o - counts[i];
  if (i == 0) offsets[0] = 0;
}

// scatter: src index + bf16 edge features into CSR order
__global__ __launch_bounds__(256) void k_scatter(const int* __restrict__ ei,
                                                 int* __restrict__ cursor,
                                                 int* __restrict__ ssrc,
                                                 const float* __restrict__ ea,
                                                 u16* __restrict__ ea_b){
  int e = blockIdx.x*256 + threadIdx.x;
  if (e >= N_EDGES) return;
  int dst = ei[N_EDGES + e];
  int pos = atomicAdd(&cursor[dst], 1);
  ssrc[pos] = ei[e];
  const float* s = ea + (size_t)e*F_EDGE_;
  u16* d = ea_b + (size_t)pos*F_EDGE_;
  #pragma unroll
  for (int k=0;k<16;k++) d[k] = f2bu(s[k]);
}

// ---------------- Graph CSR from sorted batch (once) ----------------
__global__ __launch_bounds__(256) void k_ghist(const int* __restrict__ batch, int* __restrict__ gcnt){
  int i = blockIdx.x*256 + threadIdx.x;
  if (i < N_NODES) atomicAdd(&gcnt[batch[i]], 1);
}

__global__ __launch_bounds__(1024) void k_gscan(const int* __restrict__ gcnt, int* __restrict__ goff){
  __shared__ int s[1024];
  const int t = threadIdx.x;
  int v = gcnt[t];
  s[t] = v;
  __syncthreads();
  for (int off = 1; off < 1024; off <<= 1){
    int x = (t >= off) ? s[t - off] : 0;
    __syncthreads();
    s[t] += x;
    __syncthreads();
  }
  goff[t + 1] = s[t];
  if (t == 0) goff[0] = 0;
}

// ---------------- Fused GAT v6 (R12-proven): shfl-free ea, no LDS ----------------
#define GAT_GRID 6250
__global__ __launch_bounds__(256) void k_gat(const u16* __restrict__ xl,
                                             const u16* __restrict__ xr,
                                             const u16* __restrict__ ea_b,
                                             const float* __restrict__ We,
                                             const float* __restrict__ att,
                                             const int* __restrict__ offsets,
                                             const int* __restrict__ ssrc,
                                             float* __restrict__ aggr){
  const int t = threadIdx.x;
  const int wave = t >> 6, lane = t & 63;
  const int c0 = lane*2;
  const float a0 = att[c0], a1 = att[c0+1];
  float2 wreg[16];
  #pragma unroll
  for (int k=0;k<16;k++) wreg[k] = *(const float2*)&We[k*128 + c0];

  for (int node = blockIdx.x*4 + wave; node < N_NODES; node += GAT_GRID*4){
    const float2 xrv = bp2f(*(const unsigned*)(xr + (size_t)node*HID_ + c0));
    float acc0 = 0.f, acc1 = 0.f, den = 0.f;
    const int beg = offsets[node], end = offsets[node+1];
    for (int i = beg; i < end; i += 4){
      const int mm = end - i;
      const int i1 = (mm > 1) ? i+1 : i;
      const int i2 = (mm > 2) ? i+2 : i;
      const int i3 = (mm > 3) ? i+3 : i;
      int s0 = ssrc[i], s1 = ssrc[i1], s2 = ssrc[i2], s3 = ssrc[i3];
      uint4 ra0 = *(const uint4*)(ea_b + (size_t)i *F_EDGE_);
      uint4 rb0 = *(const uint4*)(ea_b + (size_t)i *F_EDGE_ + 8);
      uint4 ra1 = *(const uint4*)(ea_b + (size_t)i1*F_EDGE_);
      uint4 rb1 = *(const uint4*)(ea_b + (size_t)i1*F_EDGE_ + 8);
      uint4 ra2 = *(const uint4*)(ea_b + (size_t)i2*F_EDGE_);
      uint4 rb2 = *(const uint4*)(ea_b + (size_t)i2*F_EDGE_ + 8);
      uint4 ra3 = *(const uint4*)(ea_b + (size_t)i3*F_EDGE_);
      uint4 rb3 = *(const uint4*)(ea_b + (size_t)i3*F_EDGE_ + 8);
      float2 vl0 = bp2f(*(const unsigned*)(xl + (size_t)s0*HID_ + c0));
      float2 vl1 = bp2f(*(const unsigned*)(xl + (size_t)s1*HID_ + c0));
      float2 vl2 = bp2f(*(const unsigned*)(xl + (size_t)s2*HID_ + c0));
      float2 vl3 = bp2f(*(const unsigned*)(xl + (size_t)s3*HID_ + c0));
      float e00=0.f,e01=0.f,e10=0.f,e11=0.f,e20=0.f,e21=0.f,e30=0.f,e31=0.f;
      #define EEK(u, kk, ee_a, ee_b) { float2 p = bp2f(u); \
        ee_a += p.x*wreg[kk].x + p.y*wreg[kk+1].x; \
        ee_b += p.x*wreg[kk].y + p.y*wreg[kk+1].y; }
      EEK(ra0.x, 0, e00,e01) EEK(ra0.y, 2, e00,e01) EEK(ra0.z, 4, e00,e01) EEK(ra0.w, 6, e00,e01)
      EEK(rb0.x, 8, e00,e01) EEK(rb0.y,10, e00,e01) EEK(rb0.z,12, e00,e01) EEK(rb0.w,14, e00,e01)
      EEK(ra1.x, 0, e10,e11) EEK(ra1.y, 2, e10,e11) EEK(ra1.z, 4, e10,e11) EEK(ra1.w, 6, e10,e11)
      EEK(rb1.x, 8, e10,e11) EEK(rb1.y,10, e10,e11) EEK(rb1.z,12, e10,e11) EEK(rb1.w,14, e10,e11)
      EEK(ra2.x, 0, e20,e21) EEK(ra2.y, 2, e20,e21) EEK(ra2.z, 4, e20,e21) EEK(ra2.w, 6, e20,e21)
      EEK(rb2.x, 8, e20,e21) EEK(rb2.y,10, e20,e21) EEK(rb2.z,12, e20,e21) EEK(rb2.w,14, e20,e21)
      EEK(ra3.x, 0, e30,e31) EEK(ra3.y, 2, e30,e31) EEK(ra3.z, 4, e30,e31) EEK(ra3.w, 6, e30,e31)
      EEK(rb3.x, 8, e30,e31) EEK(rb3.y,10, e30,e31) EEK(rb3.z,12, e30,e31) EEK(rb3.w,14, e30,e31)
      #undef EEK
      float v00 = vl0.x + xrv.x + e00, v01 = vl0.y + xrv.y + e01;
      float v10 = vl1.x + xrv.x + e10, v11 = vl1.y + xrv.y + e11;
      float v20 = vl2.x + xrv.x + e20, v21 = vl2.y + xrv.y + e21;
      float v30 = vl3.x + xrv.x + e30, v31 = vl3.y + xrv.y + e31;
      v00 = v00 > 0.f ? v00 : 0.2f*v00;  v01 = v01 > 0.f ? v01 : 0.2f*v01;
      v10 = v10 > 0.f ? v10 : 0.2f*v10;  v11 = v11 > 0.f ? v11 : 0.2f*v11;
      v20 = v20 > 0.f ? v20 : 0.2f*v20;  v21 = v21 > 0.f ? v21 : 0.2f*v21;
      v30 = v30 > 0.f ? v30 : 0.2f*v30;  v31 = v31 > 0.f ? v31 : 0.2f*v31;
      float sc0 = v00*a0 + v01*a1;
      float sc1 = v10*a0 + v11*a1;
      float sc2 = v20*a0 + v21*a1;
      float sc3 = v30*a0 + v31*a1;
      sc0 += __shfl_xor(sc0, 1); sc1 += __shfl_xor(sc1, 1); sc2 += __shfl_xor(sc2, 1); sc3 += __shfl_xor(sc3, 1);
      sc0 += __shfl_xor(sc0, 2); sc1 += __shfl_xor(sc1, 2); sc2 += __shfl_xor(sc2, 2); sc3 += __shfl_xor(sc3, 2);
      sc0 += __shfl_xor(sc0, 4); sc1 += __shfl_xor(sc1, 4); sc2 += __shfl_xor(sc2, 4); sc3 += __shfl_xor(sc3, 4);
      sc0 += __shfl_xor(sc0, 8); sc1 += __shfl_xor(sc1, 8); sc2 += __shfl_xor(sc2, 8); sc3 += __shfl_xor(sc3, 8);
      float p0 = __expf(sc0);
      float p1 = (mm > 1) ? __expf(sc1) : 0.f;
      float p2 = (mm > 2) ? __expf(sc2) : 0.f;
      float p3 = (mm > 3) ? __expf(sc3) : 0.f;
      acc0 += p0*vl0.x + p1*vl1.x + p2*vl2.x + p3*vl3.x;
      acc1 += p0*vl0.y + p1*vl1.y + p2*vl2.y + p3*vl3.y;
      den  += p0 + p1 + p2 + p3;
    }
    float inv = 1.0f / (den + 1e-16f);
    *(float2*)(aggr + (size_t)node*HID_ + c0) = make_float2(acc0*inv, acc1*inv);
  }
}

// ---------------- BN stats ----------------
__global__ __launch_bounds__(256) void k_bn_stats(const float* __restrict__ aggr,
                                                  float* __restrict__ stats){
  __shared__ float redS[256], redS2[256];
  const int t = threadIdx.x;
  const int c = t & 127, half = t >> 7;
  float s = 0.f, s2 = 0.f;
  for (int r = blockIdx.x*2 + half; r < N_NODES; r += gridDim.x*2){
    float v = aggr[(size_t)r*HID_ + c];
    s += v; s2 += v*v;
  }
  redS[t] = s; redS2[t] = s2;
  __syncthreads();
  if (half == 0){
    s  += redS[t+128];
    s2 += redS2[t+128];
    atomicAdd(&stats[c], s);
    atomicAdd(&stats[128+c], s2);
  }
}

// ---------------- BN apply + ELU (+ residual), h in bf16 ----------------
__global__ __launch_bounds__(256) void k_bn_apply(const float* __restrict__ aggr,
                                                  const float* __restrict__ stats,
                                                  const float* __restrict__ gamma,
                                                  const float* __restrict__ beta,
                                                  u16* __restrict__ h, int residual){
  size_t i = (size_t)blockIdx.x*256 + threadIdx.x;
  if (i >= (size_t)N_NODES*HID_) return;
  int c = i & 127;
  const float invn = 1.0f / (float)N_NODES;
  float mu  = stats[c] * invn;
  float var = stats[128+c] * invn - mu*mu;
  float sc  = rsqrtf(var + 1e-5f) * gamma[c];
  float val = (aggr[i] - mu) * sc + beta[c];
  val = val > 0.f ? val : expm1f(val);
  if (residual) val += bu2f(h[i]);
  h[i] = f2bu(val);
}

// ---------------- Pool: segmented mean over sorted batch ----------------
__global__ __launch_bounds__(128) void k_pool_seg(const u16* __restrict__ h,
                                                  const int* __restrict__ goff,
                                                  float* __restrict__ emb){
  const int g = blockIdx.x, c = threadIdx.x;
  const int beg = goff[g], end = goff[g+1];
  float acc = 0.f;
  for (int r = beg; r < end; r++) acc += bu2f(h[(size_t)r*HID_ + c]);
  float n = (float)(end - beg);
  emb[(size_t)g*HID_ + c] = acc / fmaxf(n, 1.f);
}

// ---------------- Per-task heads ----------------
__global__ __launch_bounds__(128) void k_heads(const float* __restrict__ emb,
                                               const float* __restrict__ mf,
                                               const int* __restrict__ fpi,
                                               const float* __restrict__ tw1,
                                               const float* __restrict__ tb1,
                                               const float* __restrict__ tw2,
                                               const float* __restrict__ tb2,
                                               float* __restrict__ out){
  const int g = blockIdx.x, task = blockIdx.y;
  const int j = threadIdx.x;
  __shared__ float fused[160];
  __shared__ float red[128];
  fused[j] = emb[(size_t)g*HID_ + j];
  if (j < 32){
    int bit = fpi[task*32 + j];
    fused[128 + j] = mf[(size_t)g*2048 + bit];
  }
  __syncthreads();
  const float* w1 = tw1 + (size_t)task*160*128;
  float acc = tb1[task*128 + j];
  #pragma unroll 8
  for (int i=0;i<160;i++) acc += fused[i] * w1[(size_t)i*128 + j];
  acc = acc > 0.f ? acc : 0.f;
  acc *= tw2[task*128 + j];
  red[j] = acc;
  __syncthreads();
  for (int s=64; s>0; s>>=1){
    if (j < s) red[j] += red[j+s];
    __syncthreads();
  }
  if (j == 0) out[(size_t)g*N_TASK + task] = red[0] + tb2[task];
}

extern "C" void kernel_launch(void* const* d_in, const int* in_sizes, int n_in,
                              void* d_out, int out_size, void* d_ws, size_t ws_size,
                              hipStream_t stream){
  const float* x    = (const float*)d_in[0];
  const int*   ei   = (const int*)  d_in[1];
  const float* ea   = (const float*)d_in[2];
  const int*   batch= (const int*)  d_in[3];
  const float* mf   = (const float*)d_in[4];
  const int*   fpi  = (const int*)  d_in[5];
  const float* Wl0  = (const float*)d_in[6];
  const float* bl0  = (const float*)d_in[7];
  const float* Wr0  = (const float*)d_in[8];
  const float* br0  = (const float*)d_in[9];
  const float* We0  = (const float*)d_in[10];
  const float* att0 = (const float*)d_in[11];
  const float* g0   = (const float*)d_in[13];
  const float* b0   = (const float*)d_in[14];
  const float* Wl   = (const float*)d_in[15];
  const float* bl   = (const float*)d_in[16];
  const float* Wr   = (const float*)d_in[17];
  const float* br   = (const float*)d_in[18];
  const float* We   = (const float*)d_in[19];
  const float* att  = (const float*)d_in[20];
  const float* gg   = (const float*)d_in[22];
  const float* bb   = (const float*)d_in[23];
  const float* tw1  = (const float*)d_in[24];
  const float* tb1  = (const float*)d_in[25];
  const float* tw2  = (const float*)d_in[26];
  const float* tb2  = (const float*)d_in[27];
  float* out = (float*)d_out;

  char* w = (char*)d_ws;
  auto alloc = [&](size_t bytes)->char*{ char* r = w; w += (bytes + 255) & ~(size_t)255; return r; };
  u16*   xl     = (u16*)  alloc((size_t)N_NODES*HID_*2);
  u16*   xr     = (u16*)  alloc((size_t)N_NODES*HID_*2);
  u16*   h      = (u16*)  alloc((size_t)N_NODES*HID_*2);
  u16*   xbf    = (u16*)  alloc((size_t)N_NODES*F_NODE_*2);
  float* aggr   = (float*)alloc((size_t)N_NODES*HID_*4);
  float* stats  = (float*)alloc(256*4);
  float* emb    = (float*)alloc((size_t)N_GRAPH*HID_*4);
  int*   counts = (int*)  alloc((size_t)N_NODES*4);
  int*   offsets= (int*)  alloc((size_t)(N_NODES+1)*4);
  int*   cursor = (int*)  alloc((size_t)N_NODES*4);
  int*   incl   = (int*)  alloc((size_t)N_NODES*4);
  int*   bsum   = (int*)  alloc(256*4);
  int*   ssrc   = (int*)  alloc((size_t)N_EDGES*4);
  u16*   ea_b   = (u16*)  alloc((size_t)N_EDGES*F_EDGE_*2);
  int*   gcnt   = (int*)  alloc((size_t)N_GRAPH*4);
  int*   goff   = (int*)  alloc((size_t)(N_GRAPH+1)*4);
  u16*   Wzl0   = (u16*)  alloc((size_t)F_NODE_*128*2);
  u16*   Wzr0   = (u16*)  alloc((size_t)F_NODE_*128*2);
  u16*   Wzl123 = (u16*)  alloc((size_t)3*HID_*128*2);
  u16*   Wzr123 = (u16*)  alloc((size_t)3*HID_*128*2);

  const int eg256 = (N_EDGES + 255)/256;
  const int ng256 = (N_NODES + 255)/256;
  const int nscan = (N_NODES + 511)/512;
  const int gemm_grid = (N_NODES + 63)/64;

  // one-time: input cast + weight pre-swizzles
  hipLaunchKernelGGL(k_cast, dim3((N_NODES*F_NODE_ + 255)/256), dim3(256), 0, stream, x, xbf, N_NODES*F_NODE_);
  hipLaunchKernelGGL(k_wswz1, dim3((F_NODE_*128 + 255)/256), dim3(256), 0, stream, Wl0, Wzl0, F_NODE_);
  hipLaunchKernelGGL(k_wswz1, dim3((F_NODE_*128 + 255)/256), dim3(256), 0, stream, Wr0, Wzr0, F_NODE_);
  for (int i=0;i<3;i++){
    hipLaunchKernelGGL(k_wswz1, dim3((HID_*128 + 255)/256), dim3(256), 0, stream,
                       Wl + (size_t)i*HID_*HID_, Wzl123 + (size_t)i*HID_*128, HID_);
    hipLaunchKernelGGL(k_wswz1, dim3((HID_*128 + 255)/256), dim3(256), 0, stream,
                       Wr + (size_t)i*HID_*HID_, Wzr123 + (size_t)i*HID_*128, HID_);
  }

  // CSR build (topology constant across layers) + graph offsets
  hipMemsetAsync(counts, 0, (size_t)N_NODES*4, stream);
  hipMemsetAsync(gcnt,   0, (size_t)N_GRAPH*4, stream);
  hipLaunchKernelGGL(k_hist,    dim3(eg256), dim3(256), 0, stream, ei, counts);
  hipLaunchKernelGGL(k_ghist,   dim3(ng256), dim3(256), 0, stream, batch, gcnt);
  hipLaunchKernelGGL(k_scan1,   dim3(nscan), dim3(512), 0, stream, counts, incl, bsum);
  hipLaunchKernelGGL(k_scan2,   dim3(1),     dim3(256), 0, stream, bsum, nscan);
  hipLaunchKernelGGL(k_scan3,   dim3(nscan), dim3(512), 0, stream, counts, incl, bsum, offsets, cursor);
  hipLaunchKernelGGL(k_gscan,   dim3(1),     dim3(1024),0, stream, gcnt, goff);
  hipLaunchKernelGGL(k_scatter, dim3(eg256), dim3(256), 0, stream, ei, cursor, ssrc, ea, ea_b);

  for (int layer = 0; layer < 4; layer++){
    const float *bl_, *br_, *We_, *att_, *g_, *b_;
    const u16 *Wzl_, *Wzr_, *Ain;
    int K;
    if (layer == 0){
      bl_=bl0; br_=br0; We_=We0; att_=att0; g_=g0; b_=b0;
      Wzl_ = Wzl0; Wzr_ = Wzr0; Ain = xbf; K = F_NODE_;
    } else {
      int i = layer - 1;
      bl_ = bl + (size_t)i*HID_;  br_ = br + (size_t)i*HID_;
      We_ = We + (size_t)i*F_EDGE_*HID_;
      att_= att + (size_t)i*HID_;
      g_  = gg + (size_t)i*HID_;  b_  = bb + (size_t)i*HID_;
      Wzl_ = Wzl123 + (size_t)i*HID_*128;
      Wzr_ = Wzr123 + (size_t)i*HID_*128;
      Ain = h; K = HID_;
    }
    hipLaunchKernelGGL(k_gemm1, dim3(gemm_grid), dim3(256), 0, stream, Ain, Wzl_, bl_, xl, N_NODES, K);
    hipLaunchKernelGGL(k_gemm1, dim3(gemm_grid), dim3(256), 0, stream, Ain, Wzr_, br_, xr, N_NODES, K);
    hipMemsetAsync(stats, 0, 256*4, stream);
    hipLaunchKernelGGL(k_gat, dim3(GAT_GRID), dim3(256), 0, stream,
                       xl, xr, ea_b, We_, att_, offsets, ssrc, aggr);
    hipLaunchKernelGGL(k_bn_stats, dim3(512), dim3(256), 0, stream, aggr, stats);
    hipLaunchKernelGGL(k_bn_apply, dim3((N_NODES*HID_ + 255)/256), dim3(256), 0, stream,
                       aggr, stats, g_, b_, h, layer > 0 ? 1 : 0);
  }
  hipLaunchKernelGGL(k_pool_seg, dim3(N_GRAPH), dim3(128), 0, stream, h, goff, emb);
  hipLaunchKernelGGL(k_heads, dim3(N_GRAPH, N_TASK), dim3(128), 0, stream, emb, mf, fpi, tw1, tb1, tw2, tb2, out);
}

// Round 14
// 1103.240 us; speedup vs baseline: 4.9803x; 1.0723x over previous
//
#include <hip/hip_runtime.h>
#include <hip/hip_bf16.h>

#define N_NODES 100000
#define N_EDGES 400000
#define F_NODE_ 64
#define F_EDGE_ 16
#define HID_ 128
#define N_GRAPH 1024
#define N_TASK 5

typedef unsigned short u16;
typedef __attribute__((ext_vector_type(8))) short frag8;   // 8 bf16 = 4 VGPRs
typedef __attribute__((ext_vector_type(4))) float f32x4;   // MFMA C/D

__device__ __forceinline__ float bu2f(u16 v){ return __uint_as_float(((unsigned)v) << 16); }
__device__ __forceinline__ float2 bp2f(unsigned u){
  return make_float2(__uint_as_float(u << 16), __uint_as_float(u & 0xFFFF0000u));
}
__device__ __forceinline__ u16 f2bu(float f){
  __hip_bfloat16 h = __float2bfloat16(f);
  return *(u16*)&h;
}

// ---------------- cast f32 -> bf16 ----------------
__global__ __launch_bounds__(256) void k_cast(const float* __restrict__ s, u16* __restrict__ d, int n){
  int i = blockIdx.x*256 + threadIdx.x;
  if (i < n) d[i] = f2bu(s[i]);
}

// ---------------- pre-swizzle one W (K x 128, f32) into B-fragment order, bf16 (verified R7/R13) ----------------
__global__ __launch_bounds__(256) void k_wswz1(const float* __restrict__ W,
                                               u16* __restrict__ Wz, int K){
  int i = blockIdx.x*256 + threadIdx.x;
  if (i >= K*128) return;
  int k = i >> 7, n = i & 127;
  int kk = k & 31, c = k >> 5;
  int quad = kk >> 3, j = kk & 7;
  int nt = n >> 4;
  int lane = quad*16 + (n & 15);
  Wz[(((c*8 + nt)*64) + lane)*8 + j] = f2bu(W[k*128 + n]);
}

// ---------------- paired single-output MFMA GEMMs (blockIdx.y selects L/R), 32KB LDS ----------------
__global__ __launch_bounds__(256) void k_gemm_pair(const u16* __restrict__ A,
                                                   const u16* __restrict__ Wzl,
                                                   const u16* __restrict__ Wzr,
                                                   const float* __restrict__ bl,
                                                   const float* __restrict__ br,
                                                   u16* __restrict__ Cl,
                                                   u16* __restrict__ Cr,
                                                   int M, int K){
  const u16*   Wz   = blockIdx.y ? Wzr : Wzl;
  const float* bias = blockIdx.y ? br  : bl;
  u16*         C    = blockIdx.y ? Cr  : Cl;
  __shared__ u16 WS[128*128];   // 32 KB at K=128; K=64 uses 16 KB
  const int t = threadIdx.x;
  {
    const uint4* src = (const uint4*)Wz;
    uint4* dst = (uint4*)WS;
    const int n = (K*128) >> 3;
    for (int i = t; i < n; i += 256) dst[i] = src[i];
  }
  __syncthreads();
  const int w = t >> 6, l = t & 63;
  const int m = l & 15, quad = l >> 4;
  const int row0 = blockIdx.x*64 + w*16 + m;
  f32x4 acc[8];
  #pragma unroll
  for (int i=0;i<8;i++) acc[i] = (f32x4){0.f,0.f,0.f,0.f};
  const int KC = K >> 5;
  for (int c = 0; c < KC; c++){
    frag8 a = {};
    if (row0 < M) a = *(const frag8*)(A + (size_t)row0*K + c*32 + quad*8);
    #pragma unroll
    for (int nt = 0; nt < 8; nt++){
      frag8 b = *(const frag8*)&WS[(((c*8 + nt)*64) + l)*8];
      acc[nt] = __builtin_amdgcn_mfma_f32_16x16x32_bf16(a, b, acc[nt], 0,0,0);
    }
  }
  const int rbase = blockIdx.x*64 + w*16 + quad*4;
  #pragma unroll
  for (int nt = 0; nt < 8; nt++){
    int col = nt*16 + m;
    float bc = bias[col];
    #pragma unroll
    for (int r = 0; r < 4; r++){
      int row = rbase + r;
      if (row < M) C[(size_t)row*128 + col] = f2bu(acc[nt][r] + bc);
    }
  }
}

// ---------------- CSR build (once) ----------------
__global__ __launch_bounds__(256) void k_hist(const int* __restrict__ ei, int* __restrict__ counts){
  int e = blockIdx.x*256 + threadIdx.x;
  if (e < N_EDGES) atomicAdd(&counts[ei[N_EDGES + e]], 1);
}

__global__ __launch_bounds__(512) void k_scan1(const int* __restrict__ counts,
                                               int* __restrict__ incl,
                                               int* __restrict__ bsum){
  __shared__ int s[512];
  const int t = threadIdx.x;
  int i = blockIdx.x*512 + t;
  int v = (i < N_NODES) ? counts[i] : 0;
  s[t] = v;
  __syncthreads();
  for (int off = 1; off < 512; off <<= 1){
    int x = (t >= off) ? s[t - off] : 0;
    __syncthreads();
    s[t] += x;
    __syncthreads();
  }
  if (i < N_NODES) incl[i] = s[t];
  if (t == 511) bsum[blockIdx.x] = s[511];
}

__global__ __launch_bounds__(256) void k_scan2(int* __restrict__ bsum, int nb){
  __shared__ int s[256];
  const int t = threadIdx.x;
  int v = (t < nb) ? bsum[t] : 0;
  s[t] = v;
  __syncthreads();
  for (int off = 1; off < 256; off <<= 1){
    int x = (t >= off) ? s[t - off] : 0;
    __syncthreads();
    s[t] += x;
    __syncthreads();
  }
  if (t < nb) bsum[t] = s[t] - v;
}

__global__ __launch_bounds__(512) void k_scan3(const int* __restrict__ counts,
                                               const int* __restrict__ incl,
                                               const int* __restrict__ bsum,
                                               int* __restrict__ offsets,
                                               int* __restrict__ cursor){
  int i = blockIdx.x*512 + threadIdx.x;
  if (i >= N_NODES) return;
  int o = bsum[blockIdx.x] + incl[i];
  offsets[i + 1] = o;
  cursor[i]      = o - counts[i];
  if (i == 0) offsets[0] = 0;
}

// scatter: src index + bf16 edge features (packed 16B stores) into CSR order
__global__ __launch_bounds__(256) void k_scatter(const int* __restrict__ ei,
                                                 int* __restrict__ cursor,
                                                 int* __restrict__ ssrc,
                                                 const float* __restrict__ ea,
                                                 u16* __restrict__ ea_b){
  int e = blockIdx.x*256 + threadIdx.x;
  if (e >= N_EDGES) return;
  int dst = ei[N_EDGES + e];
  int pos = atomicAdd(&cursor[dst], 1);
  ssrc[pos] = ei[e];
  const float* s = ea + (size_t)e*F_EDGE_;
  unsigned p[8];
  #pragma unroll
  for (int k=0;k<8;k++)
    p[k] = (unsigned)f2bu(s[2*k]) | ((unsigned)f2bu(s[2*k+1]) << 16);
  uint4* d4 = (uint4*)(ea_b + (size_t)pos*F_EDGE_);
  d4[0] = make_uint4(p[0],p[1],p[2],p[3]);
  d4[1] = make_uint4(p[4],p[5],p[6],p[7]);
}

// ---------------- Graph CSR from sorted batch (once) ----------------
__global__ __launch_bounds__(256) void k_ghist(const int* __restrict__ batch, int* __restrict__ gcnt){
  int i = blockIdx.x*256 + threadIdx.x;
  if (i < N_NODES) atomicAdd(&gcnt[batch[i]], 1);
}

__global__ __launch_bounds__(1024) void k_gscan(const int* __restrict__ gcnt, int* __restrict__ goff){
  __shared__ int s[1024];
  const int t = threadIdx.x;
  int v = gcnt[t];
  s[t] = v;
  __syncthreads();
  for (int off = 1; off < 1024; off <<= 1){
    int x = (t >= off) ? s[t - off] : 0;
    __syncthreads();
    s[t] += x;
    __syncthreads();
  }
  goff[t + 1] = s[t];
  if (t == 0) goff[0] = 0;
}

// ---------------- Fused GAT v7: scalar (SGPR) ea path via readfirstlane ----------------
// ea row is wave-uniform per edge -> readfirstlane moves unpack to the scalar pipe;
// FMAs consume the SGPR operand directly (1 sgpr/VALU-op is legal).
#define GAT_GRID 6250
__global__ __launch_bounds__(256) void k_gat(const u16* __restrict__ xl,
                                             const u16* __restrict__ xr,
                                             const u16* __restrict__ ea_b,
                                             const float* __restrict__ We,
                                             const float* __restrict__ att,
                                             const int* __restrict__ offsets,
                                             const int* __restrict__ ssrc,
                                             float* __restrict__ aggr){
  const int t = threadIdx.x;
  const int wave = t >> 6, lane = t & 63;
  const int c0 = lane*2;
  const float a0 = att[c0], a1 = att[c0+1];
  float2 wreg[16];
  #pragma unroll
  for (int k=0;k<16;k++) wreg[k] = *(const float2*)&We[k*128 + c0];

  for (int node = blockIdx.x*4 + wave; node < N_NODES; node += GAT_GRID*4){
    const float2 xrv = bp2f(*(const unsigned*)(xr + (size_t)node*HID_ + c0));
    float acc0 = 0.f, acc1 = 0.f, den = 0.f;
    const int beg = offsets[node], end = offsets[node+1];
    for (int i = beg; i < end; i += 4){
      const int mm = end - i;
      const int i1 = (mm > 1) ? i+1 : i;
      const int i2 = (mm > 2) ? i+2 : i;
      const int i3 = (mm > 3) ? i+3 : i;
      int s0 = ssrc[i], s1 = ssrc[i1], s2 = ssrc[i2], s3 = ssrc[i3];
      uint4 ra0 = *(const uint4*)(ea_b + (size_t)i *F_EDGE_);
      uint4 rb0 = *(const uint4*)(ea_b + (size_t)i *F_EDGE_ + 8);
      uint4 ra1 = *(const uint4*)(ea_b + (size_t)i1*F_EDGE_);
      uint4 rb1 = *(const uint4*)(ea_b + (size_t)i1*F_EDGE_ + 8);
      uint4 ra2 = *(const uint4*)(ea_b + (size_t)i2*F_EDGE_);
      uint4 rb2 = *(const uint4*)(ea_b + (size_t)i2*F_EDGE_ + 8);
      uint4 ra3 = *(const uint4*)(ea_b + (size_t)i3*F_EDGE_);
      uint4 rb3 = *(const uint4*)(ea_b + (size_t)i3*F_EDGE_ + 8);
      float2 vl0 = bp2f(*(const unsigned*)(xl + (size_t)s0*HID_ + c0));
      float2 vl1 = bp2f(*(const unsigned*)(xl + (size_t)s1*HID_ + c0));
      float2 vl2 = bp2f(*(const unsigned*)(xl + (size_t)s2*HID_ + c0));
      float2 vl3 = bp2f(*(const unsigned*)(xl + (size_t)s3*HID_ + c0));
      float e00=0.f,e01=0.f,e10=0.f,e11=0.f,e20=0.f,e21=0.f,e30=0.f,e31=0.f;
      #define EEK(u, kk, ee_a, ee_b) { \
        unsigned su = __builtin_amdgcn_readfirstlane(u); \
        float plo = __uint_as_float(su << 16); \
        float phi = __uint_as_float(su & 0xFFFF0000u); \
        ee_a += plo*wreg[kk].x + phi*wreg[kk+1].x; \
        ee_b += plo*wreg[kk].y + phi*wreg[kk+1].y; }
      EEK(ra0.x, 0, e00,e01) EEK(ra0.y, 2, e00,e01) EEK(ra0.z, 4, e00,e01) EEK(ra0.w, 6, e00,e01)
      EEK(rb0.x, 8, e00,e01) EEK(rb0.y,10, e00,e01) EEK(rb0.z,12, e00,e01) EEK(rb0.w,14, e00,e01)
      EEK(ra1.x, 0, e10,e11) EEK(ra1.y, 2, e10,e11) EEK(ra1.z, 4, e10,e11) EEK(ra1.w, 6, e10,e11)
      EEK(rb1.x, 8, e10,e11) EEK(rb1.y,10, e10,e11) EEK(rb1.z,12, e10,e11) EEK(rb1.w,14, e10,e11)
      EEK(ra2.x, 0, e20,e21) EEK(ra2.y, 2, e20,e21) EEK(ra2.z, 4, e20,e21) EEK(ra2.w, 6, e20,e21)
      EEK(rb2.x, 8, e20,e21) EEK(rb2.y,10, e20,e21) EEK(rb2.z,12, e20,e21) EEK(rb2.w,14, e20,e21)
      EEK(ra3.x, 0, e30,e31) EEK(ra3.y, 2, e30,e31) EEK(ra3.z, 4, e30,e31) EEK(ra3.w, 6, e30,e31)
      EEK(rb3.x, 8, e30,e31) EEK(rb3.y,10, e30,e31) EEK(rb3.z,12, e30,e31) EEK(rb3.w,14, e30,e31)
      #undef EEK
      float v00 = vl0.x + xrv.x + e00, v01 = vl0.y + xrv.y + e01;
      float v10 = vl1.x + xrv.x + e10, v11 = vl1.y + xrv.y + e11;
      float v20 = vl2.x + xrv.x + e20, v21 = vl2.y + xrv.y + e21;
      float v30 = vl3.x + xrv.x + e30, v31 = vl3.y + xrv.y + e31;
      v00 = v00 > 0.f ? v00 : 0.2f*v00;  v01 = v01 > 0.f ? v01 : 0.2f*v01;
      v10 = v10 > 0.f ? v10 : 0.2f*v10;  v11 = v11 > 0.f ? v11 : 0.2f*v11;
      v20 = v20 > 0.f ? v20 : 0.2f*v20;  v21 = v21 > 0.f ? v21 : 0.2f*v21;
      v30 = v30 > 0.f ? v30 : 0.2f*v30;  v31 = v31 > 0.f ? v31 : 0.2f*v31;
      float sc0 = v00*a0 + v01*a1;
      float sc1 = v10*a0 + v11*a1;
      float sc2 = v20*a0 + v21*a1;
      float sc3 = v30*a0 + v31*a1;
      sc0 += __shfl_xor(sc0, 1); sc1 += __shfl_xor(sc1, 1); sc2 += __shfl_xor(sc2, 1); sc3 += __shfl_xor(sc3, 1);
      sc0 += __shfl_xor(sc0, 2); sc1 += __shfl_xor(sc1, 2); sc2 += __shfl_xor(sc2, 2); sc3 += __shfl_xor(sc3, 2);
      sc0 += __shfl_xor(sc0, 4); sc1 += __shfl_xor(sc1, 4); sc2 += __shfl_xor(sc2, 4); sc3 += __shfl_xor(sc3, 4);
      sc0 += __shfl_xor(sc0, 8); sc1 += __shfl_xor(sc1, 8); sc2 += __shfl_xor(sc2, 8); sc3 += __shfl_xor(sc3, 8);
      float p0 = __expf(sc0);
      float p1 = (mm > 1) ? __expf(sc1) : 0.f;
      float p2 = (mm > 2) ? __expf(sc2) : 0.f;
      float p3 = (mm > 3) ? __expf(sc3) : 0.f;
      acc0 += p0*vl0.x + p1*vl1.x + p2*vl2.x + p3*vl3.x;
      acc1 += p0*vl0.y + p1*vl1.y + p2*vl2.y + p3*vl3.y;
      den  += p0 + p1 + p2 + p3;
    }
    float inv = 1.0f / (den + 1e-16f);
    *(float2*)(aggr + (size_t)node*HID_ + c0) = make_float2(acc0*inv, acc1*inv);
  }
}

// ---------------- BN stats ----------------
__global__ __launch_bounds__(256) void k_bn_stats(const float* __restrict__ aggr,
                                                  float* __restrict__ stats){
  __shared__ float redS[256], redS2[256];
  const int t = threadIdx.x;
  const int c = t & 127, half = t >> 7;
  float s = 0.f, s2 = 0.f;
  for (int r = blockIdx.x*2 + half; r < N_NODES; r += gridDim.x*2){
    float v = aggr[(size_t)r*HID_ + c];
    s += v; s2 += v*v;
  }
  redS[t] = s; redS2[t] = s2;
  __syncthreads();
  if (half == 0){
    s  += redS[t+128];
    s2 += redS2[t+128];
    atomicAdd(&stats[c], s);
    atomicAdd(&stats[128+c], s2);
  }
}

// ---------------- BN apply + ELU (+ residual), vectorized x2, h in bf16 ----------------
__global__ __launch_bounds__(256) void k_bn_apply(const float* __restrict__ aggr,
                                                  const float* __restrict__ stats,
                                                  const float* __restrict__ gamma,
                                                  const float* __restrict__ beta,
                                                  u16* __restrict__ h, int residual){
  size_t i = (size_t)blockIdx.x*256 + threadIdx.x;   // pair index
  if (i >= (size_t)N_NODES*HID_/2) return;
  int c = (int)((i*2) & 127);
  const float invn = 1.0f / (float)N_NODES;
  float mu0  = stats[c]   * invn,  mu1  = stats[c+1]   * invn;
  float var0 = stats[128+c]*invn - mu0*mu0;
  float var1 = stats[129+c]*invn - mu1*mu1;
  float sc0 = rsqrtf(var0 + 1e-5f) * gamma[c];
  float sc1 = rsqrtf(var1 + 1e-5f) * gamma[c+1];
  float2 v = *(const float2*)(aggr + i*2);
  float val0 = (v.x - mu0) * sc0 + beta[c];
  float val1 = (v.y - mu1) * sc1 + beta[c+1];
  val0 = val0 > 0.f ? val0 : expm1f(val0);
  val1 = val1 > 0.f ? val1 : expm1f(val1);
  unsigned* hp = (unsigned*)h + i;
  if (residual){
    float2 hv = bp2f(*hp);
    val0 += hv.x; val1 += hv.y;
  }
  *hp = (unsigned)f2bu(val0) | ((unsigned)f2bu(val1) << 16);
}

// ---------------- Pool: segmented mean over sorted batch ----------------
__global__ __launch_bounds__(128) void k_pool_seg(const u16* __restrict__ h,
                                                  const int* __restrict__ goff,
                                                  float* __restrict__ emb){
  const int g = blockIdx.x, c = threadIdx.x;
  const int beg = goff[g], end = goff[g+1];
  float acc = 0.f;
  for (int r = beg; r < end; r++) acc += bu2f(h[(size_t)r*HID_ + c]);
  float n = (float)(end - beg);
  emb[(size_t)g*HID_ + c] = acc / fmaxf(n, 1.f);
}

// ---------------- Per-task heads ----------------
__global__ __launch_bounds__(128) void k_heads(const float* __restrict__ emb,
                                               const float* __restrict__ mf,
                                               const int* __restrict__ fpi,
                                               const float* __restrict__ tw1,
                                               const float* __restrict__ tb1,
                                               const float* __restrict__ tw2,
                                               const float* __restrict__ tb2,
                                               float* __restrict__ out){
  const int g = blockIdx.x, task = blockIdx.y;
  const int j = threadIdx.x;
  __shared__ float fused[160];
  __shared__ float red[128];
  fused[j] = emb[(size_t)g*HID_ + j];
  if (j < 32){
    int bit = fpi[task*32 + j];
    fused[128 + j] = mf[(size_t)g*2048 + bit];
  }
  __syncthreads();
  const float* w1 = tw1 + (size_t)task*160*128;
  float acc = tb1[task*128 + j];
  #pragma unroll 8
  for (int i=0;i<160;i++) acc += fused[i] * w1[(size_t)i*128 + j];
  acc = acc > 0.f ? acc : 0.f;
  acc *= tw2[task*128 + j];
  red[j] = acc;
  __syncthreads();
  for (int s=64; s>0; s>>=1){
    if (j < s) red[j] += red[j+s];
    __syncthreads();
  }
  if (j == 0) out[(size_t)g*N_TASK + task] = red[0] + tb2[task];
}

extern "C" void kernel_launch(void* const* d_in, const int* in_sizes, int n_in,
                              void* d_out, int out_size, void* d_ws, size_t ws_size,
                              hipStream_t stream){
  const float* x    = (const float*)d_in[0];
  const int*   ei   = (const int*)  d_in[1];
  const float* ea   = (const float*)d_in[2];
  const int*   batch= (const int*)  d_in[3];
  const float* mf   = (const float*)d_in[4];
  const int*   fpi  = (const int*)  d_in[5];
  const float* Wl0  = (const float*)d_in[6];
  const float* bl0  = (const float*)d_in[7];
  const float* Wr0  = (const float*)d_in[8];
  const float* br0  = (const float*)d_in[9];
  const float* We0  = (const float*)d_in[10];
  const float* att0 = (const float*)d_in[11];
  const float* g0   = (const float*)d_in[13];
  const float* b0   = (const float*)d_in[14];
  const float* Wl   = (const float*)d_in[15];
  const float* bl   = (const float*)d_in[16];
  const float* Wr   = (const float*)d_in[17];
  const float* br   = (const float*)d_in[18];
  const float* We   = (const float*)d_in[19];
  const float* att  = (const float*)d_in[20];
  const float* gg   = (const float*)d_in[22];
  const float* bb   = (const float*)d_in[23];
  const float* tw1  = (const float*)d_in[24];
  const float* tb1  = (const float*)d_in[25];
  const float* tw2  = (const float*)d_in[26];
  const float* tb2  = (const float*)d_in[27];
  float* out = (float*)d_out;

  char* w = (char*)d_ws;
  auto alloc = [&](size_t bytes)->char*{ char* r = w; w += (bytes + 255) & ~(size_t)255; return r; };
  u16*   xl     = (u16*)  alloc((size_t)N_NODES*HID_*2);
  u16*   xr     = (u16*)  alloc((size_t)N_NODES*HID_*2);
  u16*   h      = (u16*)  alloc((size_t)N_NODES*HID_*2);
  u16*   xbf    = (u16*)  alloc((size_t)N_NODES*F_NODE_*2);
  float* aggr   = (float*)alloc((size_t)N_NODES*HID_*4);
  float* stats4 = (float*)alloc(4*256*4);
  float* emb    = (float*)alloc((size_t)N_GRAPH*HID_*4);
  int*   counts = (int*)  alloc((size_t)N_NODES*4);
  int*   offsets= (int*)  alloc((size_t)(N_NODES+1)*4);
  int*   cursor = (int*)  alloc((size_t)N_NODES*4);
  int*   incl   = (int*)  alloc((size_t)N_NODES*4);
  int*   bsum   = (int*)  alloc(256*4);
  int*   ssrc   = (int*)  alloc((size_t)N_EDGES*4);
  u16*   ea_b   = (u16*)  alloc((size_t)N_EDGES*F_EDGE_*2);
  int*   gcnt   = (int*)  alloc((size_t)N_GRAPH*4);
  int*   goff   = (int*)  alloc((size_t)(N_GRAPH+1)*4);
  u16*   Wzl0   = (u16*)  alloc((size_t)F_NODE_*128*2);
  u16*   Wzr0   = (u16*)  alloc((size_t)F_NODE_*128*2);
  u16*   Wzl123 = (u16*)  alloc((size_t)3*HID_*128*2);
  u16*   Wzr123 = (u16*)  alloc((size_t)3*HID_*128*2);

  const int eg256 = (N_EDGES + 255)/256;
  const int ng256 = (N_NODES + 255)/256;
  const int nscan = (N_NODES + 511)/512;
  const int gemm_grid = (N_NODES + 63)/64;

  // one-time: input cast + weight pre-swizzles
  hipLaunchKernelGGL(k_cast, dim3((N_NODES*F_NODE_ + 255)/256), dim3(256), 0, stream, x, xbf, N_NODES*F_NODE_);
  hipLaunchKernelGGL(k_wswz1, dim3((F_NODE_*128 + 255)/256), dim3(256), 0, stream, Wl0, Wzl0, F_NODE_);
  hipLaunchKernelGGL(k_wswz1, dim3((F_NODE_*128 + 255)/256), dim3(256), 0, stream, Wr0, Wzr0, F_NODE_);
  for (int i=0;i<3;i++){
    hipLaunchKernelGGL(k_wswz1, dim3((HID_*128 + 255)/256), dim3(256), 0, stream,
                       Wl + (size_t)i*HID_*HID_, Wzl123 + (size_t)i*HID_*128, HID_);
    hipLaunchKernelGGL(k_wswz1, dim3((HID_*128 + 255)/256), dim3(256), 0, stream,
                       Wr + (size_t)i*HID_*HID_, Wzr123 + (size_t)i*HID_*128, HID_);
  }

  // CSR build (topology constant across layers) + graph offsets + stats zero (all 4 layers)
  hipMemsetAsync(counts, 0, (size_t)N_NODES*4, stream);
  hipMemsetAsync(gcnt,   0, (size_t)N_GRAPH*4, stream);
  hipMemsetAsync(stats4, 0, 4*256*4, stream);
  hipLaunchKernelGGL(k_hist,    dim3(eg256), dim3(256), 0, stream, ei, counts);
  hipLaunchKernelGGL(k_ghist,   dim3(ng256), dim3(256), 0, stream, batch, gcnt);
  hipLaunchKernelGGL(k_scan1,   dim3(nscan), dim3(512), 0, stream, counts, incl, bsum);
  hipLaunchKernelGGL(k_scan2,   dim3(1),     dim3(256), 0, stream, bsum, nscan);
  hipLaunchKernelGGL(k_scan3,   dim3(nscan), dim3(512), 0, stream, counts, incl, bsum, offsets, cursor);
  hipLaunchKernelGGL(k_gscan,   dim3(1),     dim3(1024),0, stream, gcnt, goff);
  hipLaunchKernelGGL(k_scatter, dim3(eg256), dim3(256), 0, stream, ei, cursor, ssrc, ea, ea_b);

  for (int layer = 0; layer < 4; layer++){
    const float *bl_, *br_, *We_, *att_, *g_, *b_;
    const u16 *Wzl_, *Wzr_, *Ain;
    int K;
    if (layer == 0){
      bl_=bl0; br_=br0; We_=We0; att_=att0; g_=g0; b_=b0;
      Wzl_ = Wzl0; Wzr_ = Wzr0; Ain = xbf; K = F_NODE_;
    } else {
      int i = layer - 1;
      bl_ = bl + (size_t)i*HID_;  br_ = br + (size_t)i*HID_;
      We_ = We + (size_t)i*F_EDGE_*HID_;
      att_= att + (size_t)i*HID_;
      g_  = gg + (size_t)i*HID_;  b_  = bb + (size_t)i*HID_;
      Wzl_ = Wzl123 + (size_t)i*HID_*128;
      Wzr_ = Wzr123 + (size_t)i*HID_*128;
      Ain = h; K = HID_;
    }
    float* stats = stats4 + layer*256;
    hipLaunchKernelGGL(k_gemm_pair, dim3(gemm_grid, 2), dim3(256), 0, stream,
                       Ain, Wzl_, Wzr_, bl_, br_, xl, xr, N_NODES, K);
    hipLaunchKernelGGL(k_gat, dim3(GAT_GRID), dim3(256), 0, stream,
                       xl, xr, ea_b, We_, att_, offsets, ssrc, aggr);
    hipLaunchKernelGGL(k_bn_stats, dim3(512), dim3(256), 0, stream, aggr, stats);
    hipLaunchKernelGGL(k_bn_apply, dim3((N_NODES*HID_/2 + 255)/256), dim3(256), 0, stream,
                       aggr, stats, g_, b_, h, layer > 0 ? 1 : 0);
  }
  hipLaunchKernelGGL(k_pool_seg, dim3(N_GRAPH), dim3(128), 0, stream, h, goff, emb);
  hipLaunchKernelGGL(k_heads, dim3(N_GRAPH, N_TASK), dim3(128), 0, stream, emb, mf, fpi, tw1, tb1, tw2, tb2, out);
}

// Round 15
// 1075.376 us; speedup vs baseline: 5.1093x; 1.0259x over previous
//
#include <hip/hip_runtime.h>
#include <hip/hip_bf16.h>

#define N_NODES 100000
#define N_EDGES 400000
#define F_NODE_ 64
#define F_EDGE_ 16
#define HID_ 128
#define N_GRAPH 1024
#define N_TASK 5

typedef unsigned short u16;
typedef __attribute__((ext_vector_type(8))) short frag8;   // 8 bf16 = 4 VGPRs
typedef __attribute__((ext_vector_type(4))) float f32x4;   // MFMA C/D
typedef __attribute__((ext_vector_type(2))) float f32x2;   // packed f32 (v_pk_*_f32)

__device__ __forceinline__ float bu2f(u16 v){ return __uint_as_float(((unsigned)v) << 16); }
__device__ __forceinline__ float2 bp2f(unsigned u){
  return make_float2(__uint_as_float(u << 16), __uint_as_float(u & 0xFFFF0000u));
}
__device__ __forceinline__ f32x2 bp2v(unsigned u){
  f32x2 r; r.x = __uint_as_float(u << 16); r.y = __uint_as_float(u & 0xFFFF0000u); return r;
}
__device__ __forceinline__ u16 f2bu(float f){
  __hip_bfloat16 h = __float2bfloat16(f);
  return *(u16*)&h;
}
__device__ __forceinline__ unsigned packbf(float a, float b){
  return (unsigned)f2bu(a) | ((unsigned)f2bu(b) << 16);
}

// ---------------- cast f32 -> bf16 ----------------
__global__ __launch_bounds__(256) void k_cast(const float* __restrict__ s, u16* __restrict__ d, int n){
  int i = blockIdx.x*256 + threadIdx.x;
  if (i < n) d[i] = f2bu(s[i]);
}

// ---------------- pre-swizzle one W (K x 128, f32) into B-fragment order, bf16 (verified R7/R13) ----------------
__global__ __launch_bounds__(256) void k_wswz1(const float* __restrict__ W,
                                               u16* __restrict__ Wz, int K){
  int i = blockIdx.x*256 + threadIdx.x;
  if (i >= K*128) return;
  int k = i >> 7, n = i & 127;
  int kk = k & 31, c = k >> 5;
  int quad = kk >> 3, j = kk & 7;
  int nt = n >> 4;
  int lane = quad*16 + (n & 15);
  Wz[(((c*8 + nt)*64) + lane)*8 + j] = f2bu(W[k*128 + n]);
}

// ---------------- paired single-output MFMA GEMMs (blockIdx.y selects L/R), 32KB LDS ----------------
__global__ __launch_bounds__(256) void k_gemm_pair(const u16* __restrict__ A,
                                                   const u16* __restrict__ Wzl,
                                                   const u16* __restrict__ Wzr,
                                                   const float* __restrict__ bl,
                                                   const float* __restrict__ br,
                                                   u16* __restrict__ Cl,
                                                   u16* __restrict__ Cr,
                                                   int M, int K){
  const u16*   Wz   = blockIdx.y ? Wzr : Wzl;
  const float* bias = blockIdx.y ? br  : bl;
  u16*         C    = blockIdx.y ? Cr  : Cl;
  __shared__ u16 WS[128*128];   // 32 KB at K=128; K=64 uses 16 KB
  const int t = threadIdx.x;
  {
    const uint4* src = (const uint4*)Wz;
    uint4* dst = (uint4*)WS;
    const int n = (K*128) >> 3;
    for (int i = t; i < n; i += 256) dst[i] = src[i];
  }
  __syncthreads();
  const int w = t >> 6, l = t & 63;
  const int m = l & 15, quad = l >> 4;
  const int row0 = blockIdx.x*64 + w*16 + m;
  f32x4 acc[8];
  #pragma unroll
  for (int i=0;i<8;i++) acc[i] = (f32x4){0.f,0.f,0.f,0.f};
  const int KC = K >> 5;
  for (int c = 0; c < KC; c++){
    frag8 a = {};
    if (row0 < M) a = *(const frag8*)(A + (size_t)row0*K + c*32 + quad*8);
    #pragma unroll
    for (int nt = 0; nt < 8; nt++){
      frag8 b = *(const frag8*)&WS[(((c*8 + nt)*64) + l)*8];
      acc[nt] = __builtin_amdgcn_mfma_f32_16x16x32_bf16(a, b, acc[nt], 0,0,0);
    }
  }
  const int rbase = blockIdx.x*64 + w*16 + quad*4;
  #pragma unroll
  for (int nt = 0; nt < 8; nt++){
    int col = nt*16 + m;
    float bc = bias[col];
    #pragma unroll
    for (int r = 0; r < 4; r++){
      int row = rbase + r;
      if (row < M) C[(size_t)row*128 + col] = f2bu(acc[nt][r] + bc);
    }
  }
}

// ---------------- CSR build (once) ----------------
__global__ __launch_bounds__(256) void k_hist(const int* __restrict__ ei, int* __restrict__ counts){
  int e = blockIdx.x*256 + threadIdx.x;
  if (e < N_EDGES) atomicAdd(&counts[ei[N_EDGES + e]], 1);
}

__global__ __launch_bounds__(512) void k_scan1(const int* __restrict__ counts,
                                               int* __restrict__ incl,
                                               int* __restrict__ bsum){
  __shared__ int s[512];
  const int t = threadIdx.x;
  int i = blockIdx.x*512 + t;
  int v = (i < N_NODES) ? counts[i] : 0;
  s[t] = v;
  __syncthreads();
  for (int off = 1; off < 512; off <<= 1){
    int x = (t >= off) ? s[t - off] : 0;
    __syncthreads();
    s[t] += x;
    __syncthreads();
  }
  if (i < N_NODES) incl[i] = s[t];
  if (t == 511) bsum[blockIdx.x] = s[511];
}

__global__ __launch_bounds__(256) void k_scan2(int* __restrict__ bsum, int nb){
  __shared__ int s[256];
  const int t = threadIdx.x;
  int v = (t < nb) ? bsum[t] : 0;
  s[t] = v;
  __syncthreads();
  for (int off = 1; off < 256; off <<= 1){
    int x = (t >= off) ? s[t - off] : 0;
    __syncthreads();
    s[t] += x;
    __syncthreads();
  }
  if (t < nb) bsum[t] = s[t] - v;
}

__global__ __launch_bounds__(512) void k_scan3(const int* __restrict__ counts,
                                               const int* __restrict__ incl,
                                               const int* __restrict__ bsum,
                                               int* __restrict__ offsets,
                                               int* __restrict__ cursor){
  int i = blockIdx.x*512 + threadIdx.x;
  if (i >= N_NODES) return;
  int o = bsum[blockIdx.x] + incl[i];
  offsets[i + 1] = o;
  cursor[i]      = o - counts[i];
  if (i == 0) offsets[0] = 0;
}

// scatter: src index + bf16 edge features (packed 16B stores) into CSR order
__global__ __launch_bounds__(256) void k_scatter(const int* __restrict__ ei,
                                                 int* __restrict__ cursor,
                                                 int* __restrict__ ssrc,
                                                 const float* __restrict__ ea,
                                                 u16* __restrict__ ea_b){
  int e = blockIdx.x*256 + threadIdx.x;
  if (e >= N_EDGES) return;
  int dst = ei[N_EDGES + e];
  int pos = atomicAdd(&cursor[dst], 1);
  ssrc[pos] = ei[e];
  const float* s = ea + (size_t)e*F_EDGE_;
  unsigned p[8];
  #pragma unroll
  for (int k=0;k<8;k++) p[k] = packbf(s[2*k], s[2*k+1]);
  uint4* d4 = (uint4*)(ea_b + (size_t)pos*F_EDGE_);
  d4[0] = make_uint4(p[0],p[1],p[2],p[3]);
  d4[1] = make_uint4(p[4],p[5],p[6],p[7]);
}

// ---------------- Graph CSR from sorted batch (once) ----------------
__global__ __launch_bounds__(256) void k_ghist(const int* __restrict__ batch, int* __restrict__ gcnt){
  int i = blockIdx.x*256 + threadIdx.x;
  if (i < N_NODES) atomicAdd(&gcnt[batch[i]], 1);
}

__global__ __launch_bounds__(1024) void k_gscan(const int* __restrict__ gcnt, int* __restrict__ goff){
  __shared__ int s[1024];
  const int t = threadIdx.x;
  int v = gcnt[t];
  s[t] = v;
  __syncthreads();
  for (int off = 1; off < 1024; off <<= 1){
    int x = (t >= off) ? s[t - off] : 0;
    __syncthreads();
    s[t] += x;
    __syncthreads();
  }
  goff[t + 1] = s[t];
  if (t == 0) goff[0] = 0;
}

// ---------------- Fused GAT v8: scalar ea path + packed-f32 math, bf16 aggr out ----------------
#define GAT_GRID 6250
__global__ __launch_bounds__(256) void k_gat(const u16* __restrict__ xl,
                                             const u16* __restrict__ xr,
                                             const u16* __restrict__ ea_b,
                                             const float* __restrict__ We,
                                             const float* __restrict__ att,
                                             const int* __restrict__ offsets,
                                             const int* __restrict__ ssrc,
                                             unsigned* __restrict__ aggr_b){
  const int t = threadIdx.x;
  const int wave = t >> 6, lane = t & 63;
  const int c0 = lane*2;
  const float a0 = att[c0], a1 = att[c0+1];
  f32x2 wreg[16];
  #pragma unroll
  for (int k=0;k<16;k++){
    float2 v = *(const float2*)&We[k*128 + c0];
    wreg[k].x = v.x; wreg[k].y = v.y;
  }

  for (int node = blockIdx.x*4 + wave; node < N_NODES; node += GAT_GRID*4){
    const f32x2 xrv = bp2v(*(const unsigned*)(xr + (size_t)node*HID_ + c0));
    f32x2 accv = {0.f, 0.f};
    float den = 0.f;
    const int beg = offsets[node], end = offsets[node+1];
    for (int i = beg; i < end; i += 4){
      const int mm = end - i;
      const int i1 = (mm > 1) ? i+1 : i;
      const int i2 = (mm > 2) ? i+2 : i;
      const int i3 = (mm > 3) ? i+3 : i;
      int s0 = ssrc[i], s1 = ssrc[i1], s2 = ssrc[i2], s3 = ssrc[i3];
      uint4 ra0 = *(const uint4*)(ea_b + (size_t)i *F_EDGE_);
      uint4 rb0 = *(const uint4*)(ea_b + (size_t)i *F_EDGE_ + 8);
      uint4 ra1 = *(const uint4*)(ea_b + (size_t)i1*F_EDGE_);
      uint4 rb1 = *(const uint4*)(ea_b + (size_t)i1*F_EDGE_ + 8);
      uint4 ra2 = *(const uint4*)(ea_b + (size_t)i2*F_EDGE_);
      uint4 rb2 = *(const uint4*)(ea_b + (size_t)i2*F_EDGE_ + 8);
      uint4 ra3 = *(const uint4*)(ea_b + (size_t)i3*F_EDGE_);
      uint4 rb3 = *(const uint4*)(ea_b + (size_t)i3*F_EDGE_ + 8);
      f32x2 vl0 = bp2v(*(const unsigned*)(xl + (size_t)s0*HID_ + c0));
      f32x2 vl1 = bp2v(*(const unsigned*)(xl + (size_t)s1*HID_ + c0));
      f32x2 vl2 = bp2v(*(const unsigned*)(xl + (size_t)s2*HID_ + c0));
      f32x2 vl3 = bp2v(*(const unsigned*)(xl + (size_t)s3*HID_ + c0));
      f32x2 ee0 = {0.f,0.f}, ee1 = {0.f,0.f}, ee2 = {0.f,0.f}, ee3 = {0.f,0.f};
      #define EEK(u, kk, ee) { \
        unsigned su = __builtin_amdgcn_readfirstlane(u); \
        float plo = __uint_as_float(su << 16); \
        float phi = __uint_as_float(su & 0xFFFF0000u); \
        ee += plo*wreg[kk] + phi*wreg[kk+1]; }
      EEK(ra0.x, 0, ee0) EEK(ra0.y, 2, ee0) EEK(ra0.z, 4, ee0) EEK(ra0.w, 6, ee0)
      EEK(rb0.x, 8, ee0) EEK(rb0.y,10, ee0) EEK(rb0.z,12, ee0) EEK(rb0.w,14, ee0)
      EEK(ra1.x, 0, ee1) EEK(ra1.y, 2, ee1) EEK(ra1.z, 4, ee1) EEK(ra1.w, 6, ee1)
      EEK(rb1.x, 8, ee1) EEK(rb1.y,10, ee1) EEK(rb1.z,12, ee1) EEK(rb1.w,14, ee1)
      EEK(ra2.x, 0, ee2) EEK(ra2.y, 2, ee2) EEK(ra2.z, 4, ee2) EEK(ra2.w, 6, ee2)
      EEK(rb2.x, 8, ee2) EEK(rb2.y,10, ee2) EEK(rb2.z,12, ee2) EEK(rb2.w,14, ee2)
      EEK(ra3.x, 0, ee3) EEK(ra3.y, 2, ee3) EEK(ra3.z, 4, ee3) EEK(ra3.w, 6, ee3)
      EEK(rb3.x, 8, ee3) EEK(rb3.y,10, ee3) EEK(rb3.z,12, ee3) EEK(rb3.w,14, ee3)
      #undef EEK
      f32x2 v0 = vl0 + xrv + ee0;
      f32x2 v1 = vl1 + xrv + ee1;
      f32x2 v2 = vl2 + xrv + ee2;
      f32x2 v3 = vl3 + xrv + ee3;
      // leakyrelu(v) = max(v, 0.2v) (slope < 1)
      f32x2 w0 = v0*0.2f, w1 = v1*0.2f, w2 = v2*0.2f, w3 = v3*0.2f;
      v0.x = fmaxf(v0.x,w0.x); v0.y = fmaxf(v0.y,w0.y);
      v1.x = fmaxf(v1.x,w1.x); v1.y = fmaxf(v1.y,w1.y);
      v2.x = fmaxf(v2.x,w2.x); v2.y = fmaxf(v2.y,w2.y);
      v3.x = fmaxf(v3.x,w3.x); v3.y = fmaxf(v3.y,w3.y);
      float sc0 = v0.x*a0 + v0.y*a1;
      float sc1 = v1.x*a0 + v1.y*a1;
      float sc2 = v2.x*a0 + v2.y*a1;
      float sc3 = v3.x*a0 + v3.y*a1;
      sc0 += __shfl_xor(sc0, 1); sc1 += __shfl_xor(sc1, 1); sc2 += __shfl_xor(sc2, 1); sc3 += __shfl_xor(sc3, 1);
      sc0 += __shfl_xor(sc0, 2); sc1 += __shfl_xor(sc1, 2); sc2 += __shfl_xor(sc2, 2); sc3 += __shfl_xor(sc3, 2);
      sc0 += __shfl_xor(sc0, 4); sc1 += __shfl_xor(sc1, 4); sc2 += __shfl_xor(sc2, 4); sc3 += __shfl_xor(sc3, 4);
      sc0 += __shfl_xor(sc0, 8); sc1 += __shfl_xor(sc1, 8); sc2 += __shfl_xor(sc2, 8); sc3 += __shfl_xor(sc3, 8);
      float p0 = __expf(sc0);
      float p1 = (mm > 1) ? __expf(sc1) : 0.f;
      float p2 = (mm > 2) ? __expf(sc2) : 0.f;
      float p3 = (mm > 3) ? __expf(sc3) : 0.f;
      accv += p0*vl0 + p1*vl1 + p2*vl2 + p3*vl3;
      den  += p0 + p1 + p2 + p3;
    }
    float inv = 1.0f / (den + 1e-16f);
    aggr_b[(size_t)node*64 + lane] = packbf(accv.x*inv, accv.y*inv);
  }
}

// ---------------- BN stats (bf16 aggr input) ----------------
__global__ __launch_bounds__(256) void k_bn_stats(const unsigned* __restrict__ aggr_b,
                                                  float* __restrict__ stats){
  __shared__ float redS[4][128], redQ[4][128];
  const int t = threadIdx.x;
  const int p = t & 63, rg = t >> 6;     // pair index, row group
  const int c0 = p*2;
  float s0=0.f, s1=0.f, q0=0.f, q1=0.f;
  for (int r = blockIdx.x*4 + rg; r < N_NODES; r += gridDim.x*4){
    float2 v = bp2f(aggr_b[(size_t)r*64 + p]);
    s0 += v.x; s1 += v.y; q0 += v.x*v.x; q1 += v.y*v.y;
  }
  redS[rg][c0] = s0; redS[rg][c0+1] = s1;
  redQ[rg][c0] = q0; redQ[rg][c0+1] = q1;
  __syncthreads();
  if (rg == 0){
    #pragma unroll
    for (int g=1; g<4; g++){
      s0 += redS[g][c0]; s1 += redS[g][c0+1];
      q0 += redQ[g][c0]; q1 += redQ[g][c0+1];
    }
    atomicAdd(&stats[c0],     s0);
    atomicAdd(&stats[c0+1],   s1);
    atomicAdd(&stats[128+c0],   q0);
    atomicAdd(&stats[128+c0+1], q1);
  }
}

// ---------------- BN apply + ELU (+ residual), bf16 aggr input, h in bf16 ----------------
__global__ __launch_bounds__(256) void k_bn_apply(const unsigned* __restrict__ aggr_b,
                                                  const float* __restrict__ stats,
                                                  const float* __restrict__ gamma,
                                                  const float* __restrict__ beta,
                                                  u16* __restrict__ h, int residual){
  size_t i = (size_t)blockIdx.x*256 + threadIdx.x;   // pair index
  if (i >= (size_t)N_NODES*64) return;
  int c = (int)((i & 63)*2);
  const float invn = 1.0f / (float)N_NODES;
  float mu0  = stats[c]   * invn,  mu1  = stats[c+1]   * invn;
  float var0 = stats[128+c]*invn - mu0*mu0;
  float var1 = stats[129+c]*invn - mu1*mu1;
  float sc0 = rsqrtf(var0 + 1e-5f) * gamma[c];
  float sc1 = rsqrtf(var1 + 1e-5f) * gamma[c+1];
  float2 v = bp2f(aggr_b[i]);
  float val0 = (v.x - mu0) * sc0 + beta[c];
  float val1 = (v.y - mu1) * sc1 + beta[c+1];
  val0 = val0 > 0.f ? val0 : expm1f(val0);
  val1 = val1 > 0.f ? val1 : expm1f(val1);
  unsigned* hp = (unsigned*)h + i;
  if (residual){
    float2 hv = bp2f(*hp);
    val0 += hv.x; val1 += hv.y;
  }
  *hp = packbf(val0, val1);
}

// ---------------- Pool: segmented mean over sorted batch ----------------
__global__ __launch_bounds__(128) void k_pool_seg(const u16* __restrict__ h,
                                                  const int* __restrict__ goff,
                                                  float* __restrict__ emb){
  const int g = blockIdx.x, c = threadIdx.x;
  const int beg = goff[g], end = goff[g+1];
  float acc = 0.f;
  for (int r = beg; r < end; r++) acc += bu2f(h[(size_t)r*HID_ + c]);
  float n = (float)(end - beg);
  emb[(size_t)g*HID_ + c] = acc / fmaxf(n, 1.f);
}

// ---------------- Per-task heads ----------------
__global__ __launch_bounds__(128) void k_heads(const float* __restrict__ emb,
                                               const float* __restrict__ mf,
                                               const int* __restrict__ fpi,
                                               const float* __restrict__ tw1,
                                               const float* __restrict__ tb1,
                                               const float* __restrict__ tw2,
                                               const float* __restrict__ tb2,
                                               float* __restrict__ out){
  const int g = blockIdx.x, task = blockIdx.y;
  const int j = threadIdx.x;
  __shared__ float fused[160];
  __shared__ float red[128];
  fused[j] = emb[(size_t)g*HID_ + j];
  if (j < 32){
    int bit = fpi[task*32 + j];
    fused[128 + j] = mf[(size_t)g*2048 + bit];
  }
  __syncthreads();
  const float* w1 = tw1 + (size_t)task*160*128;
  float acc = tb1[task*128 + j];
  #pragma unroll 8
  for (int i=0;i<160;i++) acc += fused[i] * w1[(size_t)i*128 + j];
  acc = acc > 0.f ? acc : 0.f;
  acc *= tw2[task*128 + j];
  red[j] = acc;
  __syncthreads();
  for (int s=64; s>0; s>>=1){
    if (j < s) red[j] += red[j+s];
    __syncthreads();
  }
  if (j == 0) out[(size_t)g*N_TASK + task] = red[0] + tb2[task];
}

extern "C" void kernel_launch(void* const* d_in, const int* in_sizes, int n_in,
                              void* d_out, int out_size, void* d_ws, size_t ws_size,
                              hipStream_t stream){
  const float* x    = (const float*)d_in[0];
  const int*   ei   = (const int*)  d_in[1];
  const float* ea   = (const float*)d_in[2];
  const int*   batch= (const int*)  d_in[3];
  const float* mf   = (const float*)d_in[4];
  const int*   fpi  = (const int*)  d_in[5];
  const float* Wl0  = (const float*)d_in[6];
  const float* bl0  = (const float*)d_in[7];
  const float* Wr0  = (const float*)d_in[8];
  const float* br0  = (const float*)d_in[9];
  const float* We0  = (const float*)d_in[10];
  const float* att0 = (const float*)d_in[11];
  const float* g0   = (const float*)d_in[13];
  const float* b0   = (const float*)d_in[14];
  const float* Wl   = (const float*)d_in[15];
  const float* bl   = (const float*)d_in[16];
  const float* Wr   = (const float*)d_in[17];
  const float* br   = (const float*)d_in[18];
  const float* We   = (const float*)d_in[19];
  const float* att  = (const float*)d_in[20];
  const float* gg   = (const float*)d_in[22];
  const float* bb   = (const float*)d_in[23];
  const float* tw1  = (const float*)d_in[24];
  const float* tb1  = (const float*)d_in[25];
  const float* tw2  = (const float*)d_in[26];
  const float* tb2  = (const float*)d_in[27];
  float* out = (float*)d_out;

  char* w = (char*)d_ws;
  auto alloc = [&](size_t bytes)->char*{ char* r = w; w += (bytes + 255) & ~(size_t)255; return r; };
  u16*   xl     = (u16*)  alloc((size_t)N_NODES*HID_*2);
  u16*   xr     = (u16*)  alloc((size_t)N_NODES*HID_*2);
  u16*   h      = (u16*)  alloc((size_t)N_NODES*HID_*2);
  u16*   xbf    = (u16*)  alloc((size_t)N_NODES*F_NODE_*2);
  unsigned* aggr_b = (unsigned*)alloc((size_t)N_NODES*64*4);
  float* stats4 = (float*)alloc(4*256*4);
  float* emb    = (float*)alloc((size_t)N_GRAPH*HID_*4);
  int*   counts = (int*)  alloc((size_t)N_NODES*4);
  int*   offsets= (int*)  alloc((size_t)(N_NODES+1)*4);
  int*   cursor = (int*)  alloc((size_t)N_NODES*4);
  int*   incl   = (int*)  alloc((size_t)N_NODES*4);
  int*   bsum   = (int*)  alloc(256*4);
  int*   ssrc   = (int*)  alloc((size_t)N_EDGES*4);
  u16*   ea_b   = (u16*)  alloc((size_t)N_EDGES*F_EDGE_*2);
  int*   gcnt   = (int*)  alloc((size_t)N_GRAPH*4);
  int*   goff   = (int*)  alloc((size_t)(N_GRAPH+1)*4);
  u16*   Wzl0   = (u16*)  alloc((size_t)F_NODE_*128*2);
  u16*   Wzr0   = (u16*)  alloc((size_t)F_NODE_*128*2);
  u16*   Wzl123 = (u16*)  alloc((size_t)3*HID_*128*2);
  u16*   Wzr123 = (u16*)  alloc((size_t)3*HID_*128*2);

  const int eg256 = (N_EDGES + 255)/256;
  const int ng256 = (N_NODES + 255)/256;
  const int nscan = (N_NODES + 511)/512;
  const int gemm_grid = (N_NODES + 63)/64;

  // one-time: input cast + weight pre-swizzles
  hipLaunchKernelGGL(k_cast, dim3((N_NODES*F_NODE_ + 255)/256), dim3(256), 0, stream, x, xbf, N_NODES*F_NODE_);
  hipLaunchKernelGGL(k_wswz1, dim3((F_NODE_*128 + 255)/256), dim3(256), 0, stream, Wl0, Wzl0, F_NODE_);
  hipLaunchKernelGGL(k_wswz1, dim3((F_NODE_*128 + 255)/256), dim3(256), 0, stream, Wr0, Wzr0, F_NODE_);
  for (int i=0;i<3;i++){
    hipLaunchKernelGGL(k_wswz1, dim3((HID_*128 + 255)/256), dim3(256), 0, stream,
                       Wl + (size_t)i*HID_*HID_, Wzl123 + (size_t)i*HID_*128, HID_);
    hipLaunchKernelGGL(k_wswz1, dim3((HID_*128 + 255)/256), dim3(256), 0, stream,
                       Wr + (size_t)i*HID_*HID_, Wzr123 + (size_t)i*HID_*128, HID_);
  }

  // CSR build (topology constant across layers) + graph offsets + stats zero (all 4 layers)
  hipMemsetAsync(counts, 0, (size_t)N_NODES*4, stream);
  hipMemsetAsync(gcnt,   0, (size_t)N_GRAPH*4, stream);
  hipMemsetAsync(stats4, 0, 4*256*4, stream);
  hipLaunchKernelGGL(k_hist,    dim3(eg256), dim3(256), 0, stream, ei, counts);
  hipLaunchKernelGGL(k_ghist,   dim3(ng256), dim3(256), 0, stream, batch, gcnt);
  hipLaunchKernelGGL(k_scan1,   dim3(nscan), dim3(512), 0, stream, counts, incl, bsum);
  hipLaunchKernelGGL(k_scan2,   dim3(1),     dim3(256), 0, stream, bsum, nscan);
  hipLaunchKernelGGL(k_scan3,   dim3(nscan), dim3(512), 0, stream, counts, incl, bsum, offsets, cursor);
  hipLaunchKernelGGL(k_gscan,   dim3(1),     dim3(1024),0, stream, gcnt, goff);
  hipLaunchKernelGGL(k_scatter, dim3(eg256), dim3(256), 0, stream, ei, cursor, ssrc, ea, ea_b);

  for (int layer = 0; layer < 4; layer++){
    const float *bl_, *br_, *We_, *att_, *g_, *b_;
    const u16 *Wzl_, *Wzr_, *Ain;
    int K;
    if (layer == 0){
      bl_=bl0; br_=br0; We_=We0; att_=att0; g_=g0; b_=b0;
      Wzl_ = Wzl0; Wzr_ = Wzr0; Ain = xbf; K = F_NODE_;
    } else {
      int i = layer - 1;
      bl_ = bl + (size_t)i*HID_;  br_ = br + (size_t)i*HID_;
      We_ = We + (size_t)i*F_EDGE_*HID_;
      att_= att + (size_t)i*HID_;
      g_  = gg + (size_t)i*HID_;  b_  = bb + (size_t)i*HID_;
      Wzl_ = Wzl123 + (size_t)i*HID_*128;
      Wzr_ = Wzr123 + (size_t)i*HID_*128;
      Ain = h; K = HID_;
    }
    float* stats = stats4 + layer*256;
    hipLaunchKernelGGL(k_gemm_pair, dim3(gemm_grid, 2), dim3(256), 0, stream,
                       Ain, Wzl_, Wzr_, bl_, br_, xl, xr, N_NODES, K);
    hipLaunchKernelGGL(k_gat, dim3(GAT_GRID), dim3(256), 0, stream,
                       xl, xr, ea_b, We_, att_, offsets, ssrc, aggr_b);
    hipLaunchKernelGGL(k_bn_stats, dim3(512), dim3(256), 0, stream, aggr_b, stats);
    hipLaunchKernelGGL(k_bn_apply, dim3((N_NODES*64 + 255)/256), dim3(256), 0, stream,
                       aggr_b, stats, g_, b_, h, layer > 0 ? 1 : 0);
  }
  hipLaunchKernelGGL(k_pool_seg, dim3(N_GRAPH), dim3(128), 0, stream, h, goff, emb);
  hipLaunchKernelGGL(k_heads, dim3(N_GRAPH, N_TASK), dim3(128), 0, stream, emb, mf, fpi, tw1, tb1, tw2, tb2, out);
}

// Round 16
// 1033.806 us; speedup vs baseline: 5.3148x; 1.0402x over previous
//
#include <hip/hip_runtime.h>
#include <hip/hip_bf16.h>

#define N_NODES 100000
#define N_EDGES 400000
#define F_NODE_ 64
#define F_EDGE_ 16
#define HID_ 128
#define N_GRAPH 1024
#define N_TASK 5

typedef unsigned short u16;
typedef __attribute__((ext_vector_type(8))) short frag8;   // 8 bf16 = 4 VGPRs
typedef __attribute__((ext_vector_type(4))) float f32x4;   // MFMA C/D
typedef __attribute__((ext_vector_type(2))) float f32x2;   // packed f32

__device__ __forceinline__ float bu2f(u16 v){ return __uint_as_float(((unsigned)v) << 16); }
__device__ __forceinline__ float2 bp2f(unsigned u){
  return make_float2(__uint_as_float(u << 16), __uint_as_float(u & 0xFFFF0000u));
}
__device__ __forceinline__ f32x2 bp2v(unsigned u){
  f32x2 r; r.x = __uint_as_float(u << 16); r.y = __uint_as_float(u & 0xFFFF0000u); return r;
}
__device__ __forceinline__ u16 f2bu(float f){
  __hip_bfloat16 h = __float2bfloat16(f);
  return *(u16*)&h;
}
__device__ __forceinline__ unsigned packbf(float a, float b){
  return (unsigned)f2bu(a) | ((unsigned)f2bu(b) << 16);
}

// ---------------- cast f32 -> bf16 ----------------
__global__ __launch_bounds__(256) void k_cast(const float* __restrict__ s, u16* __restrict__ d, int n){
  int i = blockIdx.x*256 + threadIdx.x;
  if (i < n) d[i] = f2bu(s[i]);
}

// ---------------- batched pre-swizzle of all 8 W matrices into B-fragment order ----------------
struct WZ8 { const float* src[8]; u16* dst[8]; int K[8]; };
__global__ __launch_bounds__(256) void k_wswz_all(WZ8 p){
  const int slot = blockIdx.y;
  const int K = p.K[slot];
  int i = blockIdx.x*256 + threadIdx.x;
  if (i >= K*128) return;
  int k = i >> 7, n = i & 127;
  int kk = k & 31, c = k >> 5;
  int quad = kk >> 3, j = kk & 7;
  int nt = n >> 4;
  int lane = quad*16 + (n & 15);
  p.dst[slot][(((c*8 + nt)*64) + lane)*8 + j] = f2bu(p.src[slot][k*128 + n]);
}

// ---------------- paired MFMA GEMMs (blockIdx.y = L/R), 128 rows/block, 2 MFMA per ds_read ----------------
__global__ __launch_bounds__(256) void k_gemm_pair(const u16* __restrict__ A,
                                                   const u16* __restrict__ Wzl,
                                                   const u16* __restrict__ Wzr,
                                                   const float* __restrict__ bl,
                                                   const float* __restrict__ br,
                                                   u16* __restrict__ Cl,
                                                   u16* __restrict__ Cr,
                                                   int M, int K){
  const u16*   Wz   = blockIdx.y ? Wzr : Wzl;
  const float* bias = blockIdx.y ? br  : bl;
  u16*         C    = blockIdx.y ? Cr  : Cl;
  __shared__ u16 WS[128*128];   // 32 KB at K=128; K=64 uses 16 KB
  const int t = threadIdx.x;
  {
    const uint4* src = (const uint4*)Wz;
    uint4* dst = (uint4*)WS;
    const int n = (K*128) >> 3;
    for (int i = t; i < n; i += 256) dst[i] = src[i];
  }
  __syncthreads();
  const int w = t >> 6, l = t & 63;
  const int m = l & 15, quad = l >> 4;
  const int rowA0 = blockIdx.x*128 + w*32 + m;
  const int rowA1 = rowA0 + 16;
  f32x4 acc[2][8];
  #pragma unroll
  for (int i=0;i<2;i++)
    #pragma unroll
    for (int j=0;j<8;j++) acc[i][j] = (f32x4){0.f,0.f,0.f,0.f};
  const int KC = K >> 5;
  for (int c = 0; c < KC; c++){
    frag8 a0 = {}, a1 = {};
    if (rowA0 < M) a0 = *(const frag8*)(A + (size_t)rowA0*K + c*32 + quad*8);
    if (rowA1 < M) a1 = *(const frag8*)(A + (size_t)rowA1*K + c*32 + quad*8);
    #pragma unroll
    for (int nt = 0; nt < 8; nt++){
      frag8 b = *(const frag8*)&WS[(((c*8 + nt)*64) + l)*8];
      acc[0][nt] = __builtin_amdgcn_mfma_f32_16x16x32_bf16(a0, b, acc[0][nt], 0,0,0);
      acc[1][nt] = __builtin_amdgcn_mfma_f32_16x16x32_bf16(a1, b, acc[1][nt], 0,0,0);
    }
  }
  #pragma unroll
  for (int rt = 0; rt < 2; rt++){
    int rbase = blockIdx.x*128 + w*32 + rt*16 + quad*4;
    #pragma unroll
    for (int nt = 0; nt < 8; nt++){
      int col = nt*16 + m;
      float bc = bias[col];
      #pragma unroll
      for (int r = 0; r < 4; r++){
        int row = rbase + r;
        if (row < M) C[(size_t)row*128 + col] = f2bu(acc[rt][nt][r] + bc);
      }
    }
  }
}

// ---------------- CSR build (once) ----------------
__global__ __launch_bounds__(256) void k_hist(const int* __restrict__ ei, int* __restrict__ counts){
  int e = blockIdx.x*256 + threadIdx.x;
  if (e < N_EDGES) atomicAdd(&counts[ei[N_EDGES + e]], 1);
}

__global__ __launch_bounds__(512) void k_scan1(const int* __restrict__ counts,
                                               int* __restrict__ incl,
                                               int* __restrict__ bsum){
  __shared__ int s[512];
  const int t = threadIdx.x;
  int i = blockIdx.x*512 + t;
  int v = (i < N_NODES) ? counts[i] : 0;
  s[t] = v;
  __syncthreads();
  for (int off = 1; off < 512; off <<= 1){
    int x = (t >= off) ? s[t - off] : 0;
    __syncthreads();
    s[t] += x;
    __syncthreads();
  }
  if (i < N_NODES) incl[i] = s[t];
  if (t == 511) bsum[blockIdx.x] = s[511];
}

__global__ __launch_bounds__(256) void k_scan2(int* __restrict__ bsum, int nb){
  __shared__ int s[256];
  const int t = threadIdx.x;
  int v = (t < nb) ? bsum[t] : 0;
  s[t] = v;
  __syncthreads();
  for (int off = 1; off < 256; off <<= 1){
    int x = (t >= off) ? s[t - off] : 0;
    __syncthreads();
    s[t] += x;
    __syncthreads();
  }
  if (t < nb) bsum[t] = s[t] - v;
}

__global__ __launch_bounds__(512) void k_scan3(const int* __restrict__ counts,
                                               const int* __restrict__ incl,
                                               const int* __restrict__ bsum,
                                               int* __restrict__ offsets,
                                               int* __restrict__ cursor){
  int i = blockIdx.x*512 + threadIdx.x;
  if (i >= N_NODES) return;
  int o = bsum[blockIdx.x] + incl[i];
  offsets[i + 1] = o;
  cursor[i]      = o - counts[i];
  if (i == 0) offsets[0] = 0;
}

// scatter: src index + bf16 edge features (packed 16B stores) into CSR order
__global__ __launch_bounds__(256) void k_scatter(const int* __restrict__ ei,
                                                 int* __restrict__ cursor,
                                                 int* __restrict__ ssrc,
                                                 const float* __restrict__ ea,
                                                 u16* __restrict__ ea_b){
  int e = blockIdx.x*256 + threadIdx.x;
  if (e >= N_EDGES) return;
  int dst = ei[N_EDGES + e];
  int pos = atomicAdd(&cursor[dst], 1);
  ssrc[pos] = ei[e];
  const float* s = ea + (size_t)e*F_EDGE_;
  unsigned p[8];
  #pragma unroll
  for (int k=0;k<8;k++) p[k] = packbf(s[2*k], s[2*k+1]);
  uint4* d4 = (uint4*)(ea_b + (size_t)pos*F_EDGE_);
  d4[0] = make_uint4(p[0],p[1],p[2],p[3]);
  d4[1] = make_uint4(p[4],p[5],p[6],p[7]);
}

// ---------------- Graph CSR from sorted batch (once) ----------------
__global__ __launch_bounds__(256) void k_ghist(const int* __restrict__ batch, int* __restrict__ gcnt){
  int i = blockIdx.x*256 + threadIdx.x;
  if (i < N_NODES) atomicAdd(&gcnt[batch[i]], 1);
}

__global__ __launch_bounds__(1024) void k_gscan(const int* __restrict__ gcnt, int* __restrict__ goff){
  __shared__ int s[1024];
  const int t = threadIdx.x;
  int v = gcnt[t];
  s[t] = v;
  __syncthreads();
  for (int off = 1; off < 1024; off <<= 1){
    int x = (t >= off) ? s[t - off] : 0;
    __syncthreads();
    s[t] += x;
    __syncthreads();
  }
  goff[t + 1] = s[t];
  if (t == 0) goff[0] = 0;
}

// ---------------- Fused GAT v8 (R15-proven): scalar ea path + packed math, bf16 aggr out ----------------
#define GAT_GRID 6250
__global__ __launch_bounds__(256) void k_gat(const u16* __restrict__ xl,
                                             const u16* __restrict__ xr,
                                             const u16* __restrict__ ea_b,
                                             const float* __restrict__ We,
                                             const float* __restrict__ att,
                                             const int* __restrict__ offsets,
                                             const int* __restrict__ ssrc,
                                             unsigned* __restrict__ aggr_b){
  const int t = threadIdx.x;
  const int wave = t >> 6, lane = t & 63;
  const int c0 = lane*2;
  const float a0 = att[c0], a1 = att[c0+1];
  f32x2 wreg[16];
  #pragma unroll
  for (int k=0;k<16;k++){
    float2 v = *(const float2*)&We[k*128 + c0];
    wreg[k].x = v.x; wreg[k].y = v.y;
  }

  for (int node = blockIdx.x*4 + wave; node < N_NODES; node += GAT_GRID*4){
    const f32x2 xrv = bp2v(*(const unsigned*)(xr + (size_t)node*HID_ + c0));
    f32x2 accv = {0.f, 0.f};
    float den = 0.f;
    const int beg = offsets[node], end = offsets[node+1];
    for (int i = beg; i < end; i += 4){
      const int mm = end - i;
      const int i1 = (mm > 1) ? i+1 : i;
      const int i2 = (mm > 2) ? i+2 : i;
      const int i3 = (mm > 3) ? i+3 : i;
      int s0 = ssrc[i], s1 = ssrc[i1], s2 = ssrc[i2], s3 = ssrc[i3];
      uint4 ra0 = *(const uint4*)(ea_b + (size_t)i *F_EDGE_);
      uint4 rb0 = *(const uint4*)(ea_b + (size_t)i *F_EDGE_ + 8);
      uint4 ra1 = *(const uint4*)(ea_b + (size_t)i1*F_EDGE_);
      uint4 rb1 = *(const uint4*)(ea_b + (size_t)i1*F_EDGE_ + 8);
      uint4 ra2 = *(const uint4*)(ea_b + (size_t)i2*F_EDGE_);
      uint4 rb2 = *(const uint4*)(ea_b + (size_t)i2*F_EDGE_ + 8);
      uint4 ra3 = *(const uint4*)(ea_b + (size_t)i3*F_EDGE_);
      uint4 rb3 = *(const uint4*)(ea_b + (size_t)i3*F_EDGE_ + 8);
      f32x2 vl0 = bp2v(*(const unsigned*)(xl + (size_t)s0*HID_ + c0));
      f32x2 vl1 = bp2v(*(const unsigned*)(xl + (size_t)s1*HID_ + c0));
      f32x2 vl2 = bp2v(*(const unsigned*)(xl + (size_t)s2*HID_ + c0));
      f32x2 vl3 = bp2v(*(const unsigned*)(xl + (size_t)s3*HID_ + c0));
      f32x2 ee0 = {0.f,0.f}, ee1 = {0.f,0.f}, ee2 = {0.f,0.f}, ee3 = {0.f,0.f};
      #define EEK(u, kk, ee) { \
        unsigned su = __builtin_amdgcn_readfirstlane(u); \
        float plo = __uint_as_float(su << 16); \
        float phi = __uint_as_float(su & 0xFFFF0000u); \
        ee += plo*wreg[kk] + phi*wreg[kk+1]; }
      EEK(ra0.x, 0, ee0) EEK(ra0.y, 2, ee0) EEK(ra0.z, 4, ee0) EEK(ra0.w, 6, ee0)
      EEK(rb0.x, 8, ee0) EEK(rb0.y,10, ee0) EEK(rb0.z,12, ee0) EEK(rb0.w,14, ee0)
      EEK(ra1.x, 0, ee1) EEK(ra1.y, 2, ee1) EEK(ra1.z, 4, ee1) EEK(ra1.w, 6, ee1)
      EEK(rb1.x, 8, ee1) EEK(rb1.y,10, ee1) EEK(rb1.z,12, ee1) EEK(rb1.w,14, ee1)
      EEK(ra2.x, 0, ee2) EEK(ra2.y, 2, ee2) EEK(ra2.z, 4, ee2) EEK(ra2.w, 6, ee2)
      EEK(rb2.x, 8, ee2) EEK(rb2.y,10, ee2) EEK(rb2.z,12, ee2) EEK(rb2.w,14, ee2)
      EEK(ra3.x, 0, ee3) EEK(ra3.y, 2, ee3) EEK(ra3.z, 4, ee3) EEK(ra3.w, 6, ee3)
      EEK(rb3.x, 8, ee3) EEK(rb3.y,10, ee3) EEK(rb3.z,12, ee3) EEK(rb3.w,14, ee3)
      #undef EEK
      f32x2 v0 = vl0 + xrv + ee0;
      f32x2 v1 = vl1 + xrv + ee1;
      f32x2 v2 = vl2 + xrv + ee2;
      f32x2 v3 = vl3 + xrv + ee3;
      f32x2 w0 = v0*0.2f, w1 = v1*0.2f, w2 = v2*0.2f, w3 = v3*0.2f;
      v0.x = fmaxf(v0.x,w0.x); v0.y = fmaxf(v0.y,w0.y);
      v1.x = fmaxf(v1.x,w1.x); v1.y = fmaxf(v1.y,w1.y);
      v2.x = fmaxf(v2.x,w2.x); v2.y = fmaxf(v2.y,w2.y);
      v3.x = fmaxf(v3.x,w3.x); v3.y = fmaxf(v3.y,w3.y);
      float sc0 = v0.x*a0 + v0.y*a1;
      float sc1 = v1.x*a0 + v1.y*a1;
      float sc2 = v2.x*a0 + v2.y*a1;
      float sc3 = v3.x*a0 + v3.y*a1;
      sc0 += __shfl_xor(sc0, 1); sc1 += __shfl_xor(sc1, 1); sc2 += __shfl_xor(sc2, 1); sc3 += __shfl_xor(sc3, 1);
      sc0 += __shfl_xor(sc0, 2); sc1 += __shfl_xor(sc1, 2); sc2 += __shfl_xor(sc2, 2); sc3 += __shfl_xor(sc3, 2);
      sc0 += __shfl_xor(sc0, 4); sc1 += __shfl_xor(sc1, 4); sc2 += __shfl_xor(sc2, 4); sc3 += __shfl_xor(sc3, 4);
      sc0 += __shfl_xor(sc0, 8); sc1 += __shfl_xor(sc1, 8); sc2 += __shfl_xor(sc2, 8); sc3 += __shfl_xor(sc3, 8);
      float p0 = __expf(sc0);
      float p1 = (mm > 1) ? __expf(sc1) : 0.f;
      float p2 = (mm > 2) ? __expf(sc2) : 0.f;
      float p3 = (mm > 3) ? __expf(sc3) : 0.f;
      accv += p0*vl0 + p1*vl1 + p2*vl2 + p3*vl3;
      den  += p0 + p1 + p2 + p3;
    }
    float inv = 1.0f / (den + 1e-16f);
    aggr_b[(size_t)node*64 + lane] = packbf(accv.x*inv, accv.y*inv);
  }
}

// ---------------- BN stats (bf16 aggr input) ----------------
__global__ __launch_bounds__(256) void k_bn_stats(const unsigned* __restrict__ aggr_b,
                                                  float* __restrict__ stats){
  __shared__ float redS[4][128], redQ[4][128];
  const int t = threadIdx.x;
  const int p = t & 63, rg = t >> 6;
  const int c0 = p*2;
  float s0=0.f, s1=0.f, q0=0.f, q1=0.f;
  for (int r = blockIdx.x*4 + rg; r < N_NODES; r += gridDim.x*4){
    float2 v = bp2f(aggr_b[(size_t)r*64 + p]);
    s0 += v.x; s1 += v.y; q0 += v.x*v.x; q1 += v.y*v.y;
  }
  redS[rg][c0] = s0; redS[rg][c0+1] = s1;
  redQ[rg][c0] = q0; redQ[rg][c0+1] = q1;
  __syncthreads();
  if (rg == 0){
    #pragma unroll
    for (int g=1; g<4; g++){
      s0 += redS[g][c0]; s1 += redS[g][c0+1];
      q0 += redQ[g][c0]; q1 += redQ[g][c0+1];
    }
    atomicAdd(&stats[c0],     s0);
    atomicAdd(&stats[c0+1],   s1);
    atomicAdd(&stats[128+c0],   q0);
    atomicAdd(&stats[128+c0+1], q1);
  }
}

// ---------------- BN apply + ELU (+ residual), bf16 in/out ----------------
__global__ __launch_bounds__(256) void k_bn_apply(const unsigned* __restrict__ aggr_b,
                                                  const float* __restrict__ stats,
                                                  const float* __restrict__ gamma,
                                                  const float* __restrict__ beta,
                                                  u16* __restrict__ h, int residual){
  size_t i = (size_t)blockIdx.x*256 + threadIdx.x;
  if (i >= (size_t)N_NODES*64) return;
  int c = (int)((i & 63)*2);
  const float invn = 1.0f / (float)N_NODES;
  float mu0  = stats[c]   * invn,  mu1  = stats[c+1]   * invn;
  float var0 = stats[128+c]*invn - mu0*mu0;
  float var1 = stats[129+c]*invn - mu1*mu1;
  float sc0 = rsqrtf(var0 + 1e-5f) * gamma[c];
  float sc1 = rsqrtf(var1 + 1e-5f) * gamma[c+1];
  float2 v = bp2f(aggr_b[i]);
  float val0 = (v.x - mu0) * sc0 + beta[c];
  float val1 = (v.y - mu1) * sc1 + beta[c+1];
  val0 = val0 > 0.f ? val0 : expm1f(val0);
  val1 = val1 > 0.f ? val1 : expm1f(val1);
  unsigned* hp = (unsigned*)h + i;
  if (residual){
    float2 hv = bp2f(*hp);
    val0 += hv.x; val1 += hv.y;
  }
  *hp = packbf(val0, val1);
}

// ---------------- Pool: segmented mean, 4 row-groups in flight ----------------
__global__ __launch_bounds__(256) void k_pool_seg(const unsigned* __restrict__ h2,
                                                  const int* __restrict__ goff,
                                                  float* __restrict__ emb){
  __shared__ float redS[4][128];
  const int g = blockIdx.x, t = threadIdx.x;
  const int p = t & 63, rg = t >> 6;
  const int beg = goff[g], end = goff[g+1];
  float a0 = 0.f, a1 = 0.f;
  for (int r = beg + rg; r < end; r += 4){
    float2 v = bp2f(h2[(size_t)r*64 + p]);
    a0 += v.x; a1 += v.y;
  }
  redS[rg][p*2] = a0; redS[rg][p*2+1] = a1;
  __syncthreads();
  if (rg == 0){
    #pragma unroll
    for (int k=1;k<4;k++){ a0 += redS[k][p*2]; a1 += redS[k][p*2+1]; }
    float n = fmaxf((float)(end - beg), 1.f);
    emb[(size_t)g*HID_ + p*2]     = a0 / n;
    emb[(size_t)g*HID_ + p*2 + 1] = a1 / n;
  }
}

// ---------------- Per-task heads: 8 graphs per block (tw1 reuse) ----------------
#define HG 8
__global__ __launch_bounds__(128) void k_heads(const float* __restrict__ emb,
                                               const float* __restrict__ mf,
                                               const int* __restrict__ fpi,
                                               const float* __restrict__ tw1,
                                               const float* __restrict__ tb1,
                                               const float* __restrict__ tw2,
                                               const float* __restrict__ tb2,
                                               float* __restrict__ out){
  const int task = blockIdx.y, g0 = blockIdx.x*HG;
  const int j = threadIdx.x;
  __shared__ float fused[HG][160];
  __shared__ float red[HG][128];
  for (int idx = j; idx < HG*160; idx += 128){
    int g = idx / 160, i = idx % 160;
    float v;
    if (i < 128) v = emb[(size_t)(g0+g)*HID_ + i];
    else         v = mf[(size_t)(g0+g)*2048 + fpi[task*32 + (i-128)]];
    fused[g][i] = v;
  }
  __syncthreads();
  const float* w1 = tw1 + (size_t)task*160*128;
  float acc[HG];
  float b1 = tb1[task*128 + j];
  #pragma unroll
  for (int g=0; g<HG; g++) acc[g] = b1;
  for (int i=0; i<160; i++){
    float wv = w1[(size_t)i*128 + j];
    #pragma unroll
    for (int g=0; g<HG; g++) acc[g] += fused[g][i] * wv;
  }
  float t2 = tw2[task*128 + j];
  #pragma unroll
  for (int g=0; g<HG; g++){
    float v = acc[g] > 0.f ? acc[g] : 0.f;
    red[g][j] = v * t2;
  }
  __syncthreads();
  // 8 groups of 16 threads each reduce one graph's 128 values
  int g = j >> 4, l16 = j & 15;
  float s = 0.f;
  #pragma unroll
  for (int k=0;k<8;k++) s += red[g][l16 + k*16];
  s += __shfl_xor(s, 1, 16);
  s += __shfl_xor(s, 2, 16);
  s += __shfl_xor(s, 4, 16);
  s += __shfl_xor(s, 8, 16);
  if (l16 == 0) out[(size_t)(g0+g)*N_TASK + task] = s + tb2[task];
}

extern "C" void kernel_launch(void* const* d_in, const int* in_sizes, int n_in,
                              void* d_out, int out_size, void* d_ws, size_t ws_size,
                              hipStream_t stream){
  const float* x    = (const float*)d_in[0];
  const int*   ei   = (const int*)  d_in[1];
  const float* ea   = (const float*)d_in[2];
  const int*   batch= (const int*)  d_in[3];
  const float* mf   = (const float*)d_in[4];
  const int*   fpi  = (const int*)  d_in[5];
  const float* Wl0  = (const float*)d_in[6];
  const float* bl0  = (const float*)d_in[7];
  const float* Wr0  = (const float*)d_in[8];
  const float* br0  = (const float*)d_in[9];
  const float* We0  = (const float*)d_in[10];
  const float* att0 = (const float*)d_in[11];
  const float* g0   = (const float*)d_in[13];
  const float* b0   = (const float*)d_in[14];
  const float* Wl   = (const float*)d_in[15];
  const float* bl   = (const float*)d_in[16];
  const float* Wr   = (const float*)d_in[17];
  const float* br   = (const float*)d_in[18];
  const float* We   = (const float*)d_in[19];
  const float* att  = (const float*)d_in[20];
  const float* gg   = (const float*)d_in[22];
  const float* bb   = (const float*)d_in[23];
  const float* tw1  = (const float*)d_in[24];
  const float* tb1  = (const float*)d_in[25];
  const float* tw2  = (const float*)d_in[26];
  const float* tb2  = (const float*)d_in[27];
  float* out = (float*)d_out;

  char* w = (char*)d_ws;
  auto alloc = [&](size_t bytes)->char*{ char* r = w; w += (bytes + 255) & ~(size_t)255; return r; };
  u16*   xl     = (u16*)  alloc((size_t)N_NODES*HID_*2);
  u16*   xr     = (u16*)  alloc((size_t)N_NODES*HID_*2);
  u16*   h      = (u16*)  alloc((size_t)N_NODES*HID_*2);
  u16*   xbf    = (u16*)  alloc((size_t)N_NODES*F_NODE_*2);
  unsigned* aggr_b = (unsigned*)alloc((size_t)N_NODES*64*4);
  float* stats4 = (float*)alloc(4*256*4);
  float* emb    = (float*)alloc((size_t)N_GRAPH*HID_*4);
  int*   counts = (int*)  alloc((size_t)N_NODES*4);
  int*   offsets= (int*)  alloc((size_t)(N_NODES+1)*4);
  int*   cursor = (int*)  alloc((size_t)N_NODES*4);
  int*   incl   = (int*)  alloc((size_t)N_NODES*4);
  int*   bsum   = (int*)  alloc(256*4);
  int*   ssrc   = (int*)  alloc((size_t)N_EDGES*4);
  u16*   ea_b   = (u16*)  alloc((size_t)N_EDGES*F_EDGE_*2);
  int*   gcnt   = (int*)  alloc((size_t)N_GRAPH*4);
  int*   goff   = (int*)  alloc((size_t)(N_GRAPH+1)*4);
  u16*   Wzl0   = (u16*)  alloc((size_t)F_NODE_*128*2);
  u16*   Wzr0   = (u16*)  alloc((size_t)F_NODE_*128*2);
  u16*   Wzl123 = (u16*)  alloc((size_t)3*HID_*128*2);
  u16*   Wzr123 = (u16*)  alloc((size_t)3*HID_*128*2);

  const int eg256 = (N_EDGES + 255)/256;
  const int ng256 = (N_NODES + 255)/256;
  const int nscan = (N_NODES + 511)/512;
  const int gemm_grid = (N_NODES + 127)/128;

  // one-time: input cast + batched weight pre-swizzle (1 dispatch for all 8 W)
  hipLaunchKernelGGL(k_cast, dim3((N_NODES*F_NODE_ + 255)/256), dim3(256), 0, stream, x, xbf, N_NODES*F_NODE_);
  {
    WZ8 p;
    p.src[0] = Wl0; p.dst[0] = Wzl0; p.K[0] = F_NODE_;
    p.src[1] = Wr0; p.dst[1] = Wzr0; p.K[1] = F_NODE_;
    for (int i=0;i<3;i++){
      p.src[2+i] = Wl + (size_t)i*HID_*HID_; p.dst[2+i] = Wzl123 + (size_t)i*HID_*128; p.K[2+i] = HID_;
      p.src[5+i] = Wr + (size_t)i*HID_*HID_; p.dst[5+i] = Wzr123 + (size_t)i*HID_*128; p.K[5+i] = HID_;
    }
    hipLaunchKernelGGL(k_wswz_all, dim3((HID_*128 + 255)/256, 8), dim3(256), 0, stream, p);
  }

  // CSR build + graph offsets + stats zero
  hipMemsetAsync(counts, 0, (size_t)N_NODES*4, stream);
  hipMemsetAsync(gcnt,   0, (size_t)N_GRAPH*4, stream);
  hipMemsetAsync(stats4, 0, 4*256*4, stream);
  hipLaunchKernelGGL(k_hist,    dim3(eg256), dim3(256), 0, stream, ei, counts);
  hipLaunchKernelGGL(k_ghist,   dim3(ng256), dim3(256), 0, stream, batch, gcnt);
  hipLaunchKernelGGL(k_scan1,   dim3(nscan), dim3(512), 0, stream, counts, incl, bsum);
  hipLaunchKernelGGL(k_scan2,   dim3(1),     dim3(256), 0, stream, bsum, nscan);
  hipLaunchKernelGGL(k_scan3,   dim3(nscan), dim3(512), 0, stream, counts, incl, bsum, offsets, cursor);
  hipLaunchKernelGGL(k_gscan,   dim3(1),     dim3(1024),0, stream, gcnt, goff);
  hipLaunchKernelGGL(k_scatter, dim3(eg256), dim3(256), 0, stream, ei, cursor, ssrc, ea, ea_b);

  for (int layer = 0; layer < 4; layer++){
    const float *bl_, *br_, *We_, *att_, *g_, *b_;
    const u16 *Wzl_, *Wzr_, *Ain;
    int K;
    if (layer == 0){
      bl_=bl0; br_=br0; We_=We0; att_=att0; g_=g0; b_=b0;
      Wzl_ = Wzl0; Wzr_ = Wzr0; Ain = xbf; K = F_NODE_;
    } else {
      int i = layer - 1;
      bl_ = bl + (size_t)i*HID_;  br_ = br + (size_t)i*HID_;
      We_ = We + (size_t)i*F_EDGE_*HID_;
      att_= att + (size_t)i*HID_;
      g_  = gg + (size_t)i*HID_;  b_  = bb + (size_t)i*HID_;
      Wzl_ = Wzl123 + (size_t)i*HID_*128;
      Wzr_ = Wzr123 + (size_t)i*HID_*128;
      Ain = h; K = HID_;
    }
    float* stats = stats4 + layer*256;
    hipLaunchKernelGGL(k_gemm_pair, dim3(gemm_grid, 2), dim3(256), 0, stream,
                       Ain, Wzl_, Wzr_, bl_, br_, xl, xr, N_NODES, K);
    hipLaunchKernelGGL(k_gat, dim3(GAT_GRID), dim3(256), 0, stream,
                       xl, xr, ea_b, We_, att_, offsets, ssrc, aggr_b);
    hipLaunchKernelGGL(k_bn_stats, dim3(512), dim3(256), 0, stream, aggr_b, stats);
    hipLaunchKernelGGL(k_bn_apply, dim3((N_NODES*64 + 255)/256), dim3(256), 0, stream,
                       aggr_b, stats, g_, b_, h, layer > 0 ? 1 : 0);
  }
  hipLaunchKernelGGL(k_pool_seg, dim3(N_GRAPH), dim3(256), 0, stream, (const unsigned*)h, goff, emb);
  hipLaunchKernelGGL(k_heads, dim3(N_GRAPH/HG, N_TASK), dim3(128), 0, stream, emb, mf, fpi, tw1, tb1, tw2, tb2, out);
}

// Round 17
// 932.876 us; speedup vs baseline: 5.8898x; 1.1082x over previous
//
#include <hip/hip_runtime.h>
#include <hip/hip_bf16.h>

#define N_NODES 100000
#define N_EDGES 400000
#define F_NODE_ 64
#define F_EDGE_ 16
#define HID_ 128
#define N_GRAPH 1024
#define N_TASK 5

typedef unsigned short u16;
typedef __attribute__((ext_vector_type(8))) short frag8;   // 8 bf16 = 4 VGPRs
typedef __attribute__((ext_vector_type(4))) float f32x4;   // MFMA C/D
typedef __attribute__((ext_vector_type(2))) float f32x2;

__device__ __forceinline__ float bu2f(u16 v){ return __uint_as_float(((unsigned)v) << 16); }
__device__ __forceinline__ float2 bp2f(unsigned u){
  return make_float2(__uint_as_float(u << 16), __uint_as_float(u & 0xFFFF0000u));
}
__device__ __forceinline__ f32x2 bp2v(unsigned u){
  f32x2 r; r.x = __uint_as_float(u << 16); r.y = __uint_as_float(u & 0xFFFF0000u); return r;
}
__device__ __forceinline__ u16 f2bu(float f){
  __hip_bfloat16 h = __float2bfloat16(f);
  return *(u16*)&h;
}
__device__ __forceinline__ unsigned packbf(float a, float b){
  return (unsigned)f2bu(a) | ((unsigned)f2bu(b) << 16);
}

// ---------------- cast f32 -> bf16 ----------------
__global__ __launch_bounds__(256) void k_cast(const float* __restrict__ s, u16* __restrict__ d, int n){
  int i = blockIdx.x*256 + threadIdx.x;
  if (i < n) d[i] = f2bu(s[i]);
}

// ---------------- batched pre-swizzle: 8 W (K=64/128) + 4 We (K=16 zero-padded to 32) ----------------
struct WZ12 { const float* src[12]; u16* dst[12]; int Ks[12]; int Kd[12]; };
__global__ __launch_bounds__(256) void k_wswz_all(WZ12 p){
  const int s = blockIdx.y;
  const int Kd = p.Kd[s], Ks = p.Ks[s];
  int i = blockIdx.x*256 + threadIdx.x;
  if (i >= Kd*128) return;
  int k = i >> 7, n = i & 127;
  float v = (k < Ks) ? p.src[s][k*128 + n] : 0.f;
  int kk = k & 31, c = k >> 5;
  int quad = kk >> 3, j = kk & 7;
  int nt = n >> 4;
  int lane = quad*16 + (n & 15);
  p.dst[s][(((c*8 + nt)*64) + lane)*8 + j] = f2bu(v);
}

// ---------------- paired MFMA GEMMs (blockIdx.y = L/R), 128 rows/block ----------------
__global__ __launch_bounds__(256) void k_gemm_pair(const u16* __restrict__ A,
                                                   const u16* __restrict__ Wzl,
                                                   const u16* __restrict__ Wzr,
                                                   const float* __restrict__ bl,
                                                   const float* __restrict__ br,
                                                   u16* __restrict__ Cl,
                                                   u16* Cr,
                                                   int M, int K){
  const u16*   Wz   = blockIdx.y ? Wzr : Wzl;
  const float* bias = blockIdx.y ? br  : bl;
  u16*         C    = blockIdx.y ? Cr  : Cl;
  __shared__ u16 WS[128*128];
  const int t = threadIdx.x;
  {
    const uint4* src = (const uint4*)Wz;
    uint4* dst = (uint4*)WS;
    const int n = (K*128) >> 3;
    for (int i = t; i < n; i += 256) dst[i] = src[i];
  }
  __syncthreads();
  const int w = t >> 6, l = t & 63;
  const int m = l & 15, quad = l >> 4;
  const int rowA0 = blockIdx.x*128 + w*32 + m;
  const int rowA1 = rowA0 + 16;
  f32x4 acc[2][8];
  #pragma unroll
  for (int i=0;i<2;i++)
    #pragma unroll
    for (int j=0;j<8;j++) acc[i][j] = (f32x4){0.f,0.f,0.f,0.f};
  const int KC = K >> 5;
  for (int c = 0; c < KC; c++){
    frag8 a0 = {}, a1 = {};
    if (rowA0 < M) a0 = *(const frag8*)(A + (size_t)rowA0*K + c*32 + quad*8);
    if (rowA1 < M) a1 = *(const frag8*)(A + (size_t)rowA1*K + c*32 + quad*8);
    #pragma unroll
    for (int nt = 0; nt < 8; nt++){
      frag8 b = *(const frag8*)&WS[(((c*8 + nt)*64) + l)*8];
      acc[0][nt] = __builtin_amdgcn_mfma_f32_16x16x32_bf16(a0, b, acc[0][nt], 0,0,0);
      acc[1][nt] = __builtin_amdgcn_mfma_f32_16x16x32_bf16(a1, b, acc[1][nt], 0,0,0);
    }
  }
  #pragma unroll
  for (int rt = 0; rt < 2; rt++){
    int rbase = blockIdx.x*128 + w*32 + rt*16 + quad*4;
    #pragma unroll
    for (int nt = 0; nt < 8; nt++){
      int col = nt*16 + m;
      float bc = bias[col];
      #pragma unroll
      for (int r = 0; r < 4; r++){
        int row = rbase + r;
        if (row < M) C[(size_t)row*128 + col] = f2bu(acc[rt][nt][r] + bc);
      }
    }
  }
}

// ---------------- eproj = ea32 @ We (K=32), bf16 out, MFMA ----------------
__global__ __launch_bounds__(256) void k_eproj(const u16* __restrict__ ea32,
                                               const u16* __restrict__ Wez,
                                               u16* __restrict__ eproj){
  __shared__ u16 WS[32*128];   // 8 KB
  const int t = threadIdx.x;
  {
    const uint4* s4 = (const uint4*)Wez;
    uint4* d4 = (uint4*)WS;
    for (int i = t; i < 512; i += 256) d4[i] = s4[i];
  }
  __syncthreads();
  const int w = t >> 6, l = t & 63, m = l & 15, quad = l >> 4;
  const int row0 = blockIdx.x*64 + w*16 + m;
  f32x4 acc[8];
  #pragma unroll
  for (int i=0;i<8;i++) acc[i] = (f32x4){0.f,0.f,0.f,0.f};
  frag8 a = {};
  if (row0 < N_EDGES) a = *(const frag8*)(ea32 + (size_t)row0*32 + quad*8);
  #pragma unroll
  for (int nt = 0; nt < 8; nt++){
    frag8 b = *(const frag8*)&WS[(nt*64 + l)*8];
    acc[nt] = __builtin_amdgcn_mfma_f32_16x16x32_bf16(a, b, acc[nt], 0,0,0);
  }
  const int rbase = blockIdx.x*64 + w*16 + quad*4;
  #pragma unroll
  for (int nt = 0; nt < 8; nt++){
    int col = nt*16 + m;
    #pragma unroll
    for (int r = 0; r < 4; r++){
      int row = rbase + r;
      if (row < N_EDGES) eproj[(size_t)row*128 + col] = f2bu(acc[nt][r]);
    }
  }
}

// ---------------- merged edge + graph histograms ----------------
#define EG256 ((N_EDGES + 255)/256)
#define NG256 ((N_NODES + 255)/256)
__global__ __launch_bounds__(256) void k_hist2(const int* __restrict__ ei,
                                               const int* __restrict__ batch,
                                               int* __restrict__ counts,
                                               int* __restrict__ gcnt){
  int b = blockIdx.x;
  if (b < EG256){
    int e = b*256 + threadIdx.x;
    if (e < N_EDGES) atomicAdd(&counts[ei[N_EDGES + e]], 1);
  } else {
    int i = (b - EG256)*256 + threadIdx.x;
    if (i < N_NODES) atomicAdd(&gcnt[batch[i]], 1);
  }
}

__global__ __launch_bounds__(512) void k_scan1(const int* __restrict__ counts,
                                               int* __restrict__ incl,
                                               int* __restrict__ bsum){
  __shared__ int s[512];
  const int t = threadIdx.x;
  int i = blockIdx.x*512 + t;
  int v = (i < N_NODES) ? counts[i] : 0;
  s[t] = v;
  __syncthreads();
  for (int off = 1; off < 512; off <<= 1){
    int x = (t >= off) ? s[t - off] : 0;
    __syncthreads();
    s[t] += x;
    __syncthreads();
  }
  if (i < N_NODES) incl[i] = s[t];
  if (t == 511) bsum[blockIdx.x] = s[511];
}

__global__ __launch_bounds__(256) void k_scan2(int* __restrict__ bsum, int nb){
  __shared__ int s[256];
  const int t = threadIdx.x;
  int v = (t < nb) ? bsum[t] : 0;
  s[t] = v;
  __syncthreads();
  for (int off = 1; off < 256; off <<= 1){
    int x = (t >= off) ? s[t - off] : 0;
    __syncthreads();
    s[t] += x;
    __syncthreads();
  }
  if (t < nb) bsum[t] = s[t] - v;
}

__global__ __launch_bounds__(512) void k_scan3(const int* __restrict__ counts,
                                               const int* __restrict__ incl,
                                               const int* __restrict__ bsum,
                                               int* __restrict__ offsets,
                                               int* __restrict__ cursor){
  int i = blockIdx.x*512 + threadIdx.x;
  if (i >= N_NODES) return;
  int o = bsum[blockIdx.x] + incl[i];
  offsets[i + 1] = o;
  cursor[i]      = o - counts[i];
  if (i == 0) offsets[0] = 0;
}

__global__ __launch_bounds__(1024) void k_gscan(const int* __restrict__ gcnt, int* __restrict__ goff){
  __shared__ int s[1024];
  const int t = threadIdx.x;
  int v = gcnt[t];
  s[t] = v;
  __syncthreads();
  for (int off = 1; off < 1024; off <<= 1){
    int x = (t >= off) ? s[t - off] : 0;
    __syncthreads();
    s[t] += x;
    __syncthreads();
  }
  goff[t + 1] = s[t];
  if (t == 0) goff[0] = 0;
}

// scatter: src index + bf16 edge features into CSR order, zero-padded to 32
__global__ __launch_bounds__(256) void k_scatter(const int* __restrict__ ei,
                                                 int* __restrict__ cursor,
                                                 int* __restrict__ ssrc,
                                                 const float* __restrict__ ea,
                                                 u16* __restrict__ ea32){
  int e = blockIdx.x*256 + threadIdx.x;
  if (e >= N_EDGES) return;
  int dst = ei[N_EDGES + e];
  int pos = atomicAdd(&cursor[dst], 1);
  ssrc[pos] = ei[e];
  const float* s = ea + (size_t)e*F_EDGE_;
  unsigned p[8];
  #pragma unroll
  for (int k=0;k<8;k++) p[k] = packbf(s[2*k], s[2*k+1]);
  uint4* d4 = (uint4*)(ea32 + (size_t)pos*32);
  d4[0] = make_uint4(p[0],p[1],p[2],p[3]);
  d4[1] = make_uint4(p[4],p[5],p[6],p[7]);
  d4[2] = make_uint4(0,0,0,0);
  d4[3] = make_uint4(0,0,0,0);
}

// ---------------- Fused GAT v9-ep: eproj precomputed; aggr aliased onto xr ----------------
#define GAT_GRID 6250
__global__ __launch_bounds__(256) void k_gat_ep(const u16* __restrict__ xl,
                                                unsigned* xr_aggr,
                                                const u16* __restrict__ eproj,
                                                const float* __restrict__ att,
                                                const int* __restrict__ offsets,
                                                const int* __restrict__ ssrc){
  const int t = threadIdx.x;
  const int wave = t >> 6, lane = t & 63;
  const int c0 = lane*2;
  const float a0 = att[c0], a1 = att[c0+1];

  for (int node = blockIdx.x*4 + wave; node < N_NODES; node += GAT_GRID*4){
    const f32x2 xrv = bp2v(xr_aggr[(size_t)node*64 + lane]);
    f32x2 accv = {0.f, 0.f};
    float den = 0.f;
    const int beg = offsets[node], end = offsets[node+1];
    for (int i = beg; i < end; i += 4){
      const int mm = end - i;
      const int i1 = (mm > 1) ? i+1 : i;
      const int i2 = (mm > 2) ? i+2 : i;
      const int i3 = (mm > 3) ? i+3 : i;
      int s0 = ssrc[i], s1 = ssrc[i1], s2 = ssrc[i2], s3 = ssrc[i3];
      unsigned ep0 = *(const unsigned*)(eproj + (size_t)i *128 + c0);
      unsigned ep1 = *(const unsigned*)(eproj + (size_t)i1*128 + c0);
      unsigned ep2 = *(const unsigned*)(eproj + (size_t)i2*128 + c0);
      unsigned ep3 = *(const unsigned*)(eproj + (size_t)i3*128 + c0);
      f32x2 vl0 = bp2v(*(const unsigned*)(xl + (size_t)s0*HID_ + c0));
      f32x2 vl1 = bp2v(*(const unsigned*)(xl + (size_t)s1*HID_ + c0));
      f32x2 vl2 = bp2v(*(const unsigned*)(xl + (size_t)s2*HID_ + c0));
      f32x2 vl3 = bp2v(*(const unsigned*)(xl + (size_t)s3*HID_ + c0));
      f32x2 v0 = vl0 + xrv + bp2v(ep0);
      f32x2 v1 = vl1 + xrv + bp2v(ep1);
      f32x2 v2 = vl2 + xrv + bp2v(ep2);
      f32x2 v3 = vl3 + xrv + bp2v(ep3);
      f32x2 w0 = v0*0.2f, w1 = v1*0.2f, w2 = v2*0.2f, w3 = v3*0.2f;
      v0.x = fmaxf(v0.x,w0.x); v0.y = fmaxf(v0.y,w0.y);
      v1.x = fmaxf(v1.x,w1.x); v1.y = fmaxf(v1.y,w1.y);
      v2.x = fmaxf(v2.x,w2.x); v2.y = fmaxf(v2.y,w2.y);
      v3.x = fmaxf(v3.x,w3.x); v3.y = fmaxf(v3.y,w3.y);
      float sc0 = v0.x*a0 + v0.y*a1;
      float sc1 = v1.x*a0 + v1.y*a1;
      float sc2 = v2.x*a0 + v2.y*a1;
      float sc3 = v3.x*a0 + v3.y*a1;
      sc0 += __shfl_xor(sc0, 1); sc1 += __shfl_xor(sc1, 1); sc2 += __shfl_xor(sc2, 1); sc3 += __shfl_xor(sc3, 1);
      sc0 += __shfl_xor(sc0, 2); sc1 += __shfl_xor(sc1, 2); sc2 += __shfl_xor(sc2, 2); sc3 += __shfl_xor(sc3, 2);
      sc0 += __shfl_xor(sc0, 4); sc1 += __shfl_xor(sc1, 4); sc2 += __shfl_xor(sc2, 4); sc3 += __shfl_xor(sc3, 4);
      sc0 += __shfl_xor(sc0, 8); sc1 += __shfl_xor(sc1, 8); sc2 += __shfl_xor(sc2, 8); sc3 += __shfl_xor(sc3, 8);
      float p0 = __expf(sc0);
      float p1 = (mm > 1) ? __expf(sc1) : 0.f;
      float p2 = (mm > 2) ? __expf(sc2) : 0.f;
      float p3 = (mm > 3) ? __expf(sc3) : 0.f;
      accv += p0*vl0 + p1*vl1 + p2*vl2 + p3*vl3;
      den  += p0 + p1 + p2 + p3;
    }
    float inv = 1.0f / (den + 1e-16f);
    xr_aggr[(size_t)node*64 + lane] = packbf(accv.x*inv, accv.y*inv);
  }
}

// ---------------- Fused GAT fallback (R16-proven, ea stride 32); aggr aliased onto xr ----------------
__global__ __launch_bounds__(256) void k_gat_fb(const u16* __restrict__ xl,
                                                unsigned* xr_aggr,
                                                const u16* __restrict__ ea32,
                                                const float* __restrict__ We,
                                                const float* __restrict__ att,
                                                const int* __restrict__ offsets,
                                                const int* __restrict__ ssrc){
  const int t = threadIdx.x;
  const int wave = t >> 6, lane = t & 63;
  const int c0 = lane*2;
  const float a0 = att[c0], a1 = att[c0+1];
  f32x2 wreg[16];
  #pragma unroll
  for (int k=0;k<16;k++){
    float2 v = *(const float2*)&We[k*128 + c0];
    wreg[k].x = v.x; wreg[k].y = v.y;
  }
  for (int node = blockIdx.x*4 + wave; node < N_NODES; node += GAT_GRID*4){
    const f32x2 xrv = bp2v(xr_aggr[(size_t)node*64 + lane]);
    f32x2 accv = {0.f, 0.f};
    float den = 0.f;
    const int beg = offsets[node], end = offsets[node+1];
    for (int i = beg; i < end; i += 4){
      const int mm = end - i;
      const int i1 = (mm > 1) ? i+1 : i;
      const int i2 = (mm > 2) ? i+2 : i;
      const int i3 = (mm > 3) ? i+3 : i;
      int s0 = ssrc[i], s1 = ssrc[i1], s2 = ssrc[i2], s3 = ssrc[i3];
      uint4 ra0 = *(const uint4*)(ea32 + (size_t)i *32);
      uint4 rb0 = *(const uint4*)(ea32 + (size_t)i *32 + 8);
      uint4 ra1 = *(const uint4*)(ea32 + (size_t)i1*32);
      uint4 rb1 = *(const uint4*)(ea32 + (size_t)i1*32 + 8);
      uint4 ra2 = *(const uint4*)(ea32 + (size_t)i2*32);
      uint4 rb2 = *(const uint4*)(ea32 + (size_t)i2*32 + 8);
      uint4 ra3 = *(const uint4*)(ea32 + (size_t)i3*32);
      uint4 rb3 = *(const uint4*)(ea32 + (size_t)i3*32 + 8);
      f32x2 vl0 = bp2v(*(const unsigned*)(xl + (size_t)s0*HID_ + c0));
      f32x2 vl1 = bp2v(*(const unsigned*)(xl + (size_t)s1*HID_ + c0));
      f32x2 vl2 = bp2v(*(const unsigned*)(xl + (size_t)s2*HID_ + c0));
      f32x2 vl3 = bp2v(*(const unsigned*)(xl + (size_t)s3*HID_ + c0));
      f32x2 ee0 = {0.f,0.f}, ee1 = {0.f,0.f}, ee2 = {0.f,0.f}, ee3 = {0.f,0.f};
      #define EEK(u, kk, ee) { \
        unsigned su = __builtin_amdgcn_readfirstlane(u); \
        float plo = __uint_as_float(su << 16); \
        float phi = __uint_as_float(su & 0xFFFF0000u); \
        ee += plo*wreg[kk] + phi*wreg[kk+1]; }
      EEK(ra0.x, 0, ee0) EEK(ra0.y, 2, ee0) EEK(ra0.z, 4, ee0) EEK(ra0.w, 6, ee0)
      EEK(rb0.x, 8, ee0) EEK(rb0.y,10, ee0) EEK(rb0.z,12, ee0) EEK(rb0.w,14, ee0)
      EEK(ra1.x, 0, ee1) EEK(ra1.y, 2, ee1) EEK(ra1.z, 4, ee1) EEK(ra1.w, 6, ee1)
      EEK(rb1.x, 8, ee1) EEK(rb1.y,10, ee1) EEK(rb1.z,12, ee1) EEK(rb1.w,14, ee1)
      EEK(ra2.x, 0, ee2) EEK(ra2.y, 2, ee2) EEK(ra2.z, 4, ee2) EEK(ra2.w, 6, ee2)
      EEK(rb2.x, 8, ee2) EEK(rb2.y,10, ee2) EEK(rb2.z,12, ee2) EEK(rb2.w,14, ee2)
      EEK(ra3.x, 0, ee3) EEK(ra3.y, 2, ee3) EEK(ra3.z, 4, ee3) EEK(ra3.w, 6, ee3)
      EEK(rb3.x, 8, ee3) EEK(rb3.y,10, ee3) EEK(rb3.z,12, ee3) EEK(rb3.w,14, ee3)
      #undef EEK
      f32x2 v0 = vl0 + xrv + ee0;
      f32x2 v1 = vl1 + xrv + ee1;
      f32x2 v2 = vl2 + xrv + ee2;
      f32x2 v3 = vl3 + xrv + ee3;
      f32x2 w0 = v0*0.2f, w1 = v1*0.2f, w2 = v2*0.2f, w3 = v3*0.2f;
      v0.x = fmaxf(v0.x,w0.x); v0.y = fmaxf(v0.y,w0.y);
      v1.x = fmaxf(v1.x,w1.x); v1.y = fmaxf(v1.y,w1.y);
      v2.x = fmaxf(v2.x,w2.x); v2.y = fmaxf(v2.y,w2.y);
      v3.x = fmaxf(v3.x,w3.x); v3.y = fmaxf(v3.y,w3.y);
      float sc0 = v0.x*a0 + v0.y*a1;
      float sc1 = v1.x*a0 + v1.y*a1;
      float sc2 = v2.x*a0 + v2.y*a1;
      float sc3 = v3.x*a0 + v3.y*a1;
      sc0 += __shfl_xor(sc0, 1); sc1 += __shfl_xor(sc1, 1); sc2 += __shfl_xor(sc2, 1); sc3 += __shfl_xor(sc3, 1);
      sc0 += __shfl_xor(sc0, 2); sc1 += __shfl_xor(sc1, 2); sc2 += __shfl_xor(sc2, 2); sc3 += __shfl_xor(sc3, 2);
      sc0 += __shfl_xor(sc0, 4); sc1 += __shfl_xor(sc1, 4); sc2 += __shfl_xor(sc2, 4); sc3 += __shfl_xor(sc3, 4);
      sc0 += __shfl_xor(sc0, 8); sc1 += __shfl_xor(sc1, 8); sc2 += __shfl_xor(sc2, 8); sc3 += __shfl_xor(sc3, 8);
      float p0 = __expf(sc0);
      float p1 = (mm > 1) ? __expf(sc1) : 0.f;
      float p2 = (mm > 2) ? __expf(sc2) : 0.f;
      float p3 = (mm > 3) ? __expf(sc3) : 0.f;
      accv += p0*vl0 + p1*vl1 + p2*vl2 + p3*vl3;
      den  += p0 + p1 + p2 + p3;
    }
    float inv = 1.0f / (den + 1e-16f);
    xr_aggr[(size_t)node*64 + lane] = packbf(accv.x*inv, accv.y*inv);
  }
}

// ---------------- BN stats (bf16 aggr input) ----------------
__global__ __launch_bounds__(256) void k_bn_stats(const unsigned* __restrict__ aggr_b,
                                                  float* __restrict__ stats){
  __shared__ float redS[4][128], redQ[4][128];
  const int t = threadIdx.x;
  const int p = t & 63, rg = t >> 6;
  const int c0 = p*2;
  float s0=0.f, s1=0.f, q0=0.f, q1=0.f;
  for (int r = blockIdx.x*4 + rg; r < N_NODES; r += gridDim.x*4){
    float2 v = bp2f(aggr_b[(size_t)r*64 + p]);
    s0 += v.x; s1 += v.y; q0 += v.x*v.x; q1 += v.y*v.y;
  }
  redS[rg][c0] = s0; redS[rg][c0+1] = s1;
  redQ[rg][c0] = q0; redQ[rg][c0+1] = q1;
  __syncthreads();
  if (rg == 0){
    #pragma unroll
    for (int g=1; g<4; g++){
      s0 += redS[g][c0]; s1 += redS[g][c0+1];
      q0 += redQ[g][c0]; q1 += redQ[g][c0+1];
    }
    atomicAdd(&stats[c0],     s0);
    atomicAdd(&stats[c0+1],   s1);
    atomicAdd(&stats[128+c0],   q0);
    atomicAdd(&stats[128+c0+1], q1);
  }
}

// ---------------- BN apply + ELU (+ residual), bf16 in/out ----------------
__global__ __launch_bounds__(256) void k_bn_apply(const unsigned* __restrict__ aggr_b,
                                                  const float* __restrict__ stats,
                                                  const float* __restrict__ gamma,
                                                  const float* __restrict__ beta,
                                                  u16* __restrict__ h, int residual){
  size_t i = (size_t)blockIdx.x*256 + threadIdx.x;
  if (i >= (size_t)N_NODES*64) return;
  int c = (int)((i & 63)*2);
  const float invn = 1.0f / (float)N_NODES;
  float mu0  = stats[c]   * invn,  mu1  = stats[c+1]   * invn;
  float var0 = stats[128+c]*invn - mu0*mu0;
  float var1 = stats[129+c]*invn - mu1*mu1;
  float sc0 = rsqrtf(var0 + 1e-5f) * gamma[c];
  float sc1 = rsqrtf(var1 + 1e-5f) * gamma[c+1];
  float2 v = bp2f(aggr_b[i]);
  float val0 = (v.x - mu0) * sc0 + beta[c];
  float val1 = (v.y - mu1) * sc1 + beta[c+1];
  val0 = val0 > 0.f ? val0 : expm1f(val0);
  val1 = val1 > 0.f ? val1 : expm1f(val1);
  unsigned* hp = (unsigned*)h + i;
  if (residual){
    float2 hv = bp2f(*hp);
    val0 += hv.x; val1 += hv.y;
  }
  *hp = packbf(val0, val1);
}

// ---------------- Pool: segmented mean, 4 row-groups in flight ----------------
__global__ __launch_bounds__(256) void k_pool_seg(const unsigned* __restrict__ h2,
                                                  const int* __restrict__ goff,
                                                  float* __restrict__ emb){
  __shared__ float redS[4][128];
  const int g = blockIdx.x, t = threadIdx.x;
  const int p = t & 63, rg = t >> 6;
  const int beg = goff[g], end = goff[g+1];
  float a0 = 0.f, a1 = 0.f;
  for (int r = beg + rg; r < end; r += 4){
    float2 v = bp2f(h2[(size_t)r*64 + p]);
    a0 += v.x; a1 += v.y;
  }
  redS[rg][p*2] = a0; redS[rg][p*2+1] = a1;
  __syncthreads();
  if (rg == 0){
    #pragma unroll
    for (int k=1;k<4;k++){ a0 += redS[k][p*2]; a1 += redS[k][p*2+1]; }
    float n = fmaxf((float)(end - beg), 1.f);
    emb[(size_t)g*HID_ + p*2]     = a0 / n;
    emb[(size_t)g*HID_ + p*2 + 1] = a1 / n;
  }
}

// ---------------- Per-task heads: 8 graphs per block ----------------
#define HG 8
__global__ __launch_bounds__(128) void k_heads(const float* __restrict__ emb,
                                               const float* __restrict__ mf,
                                               const int* __restrict__ fpi,
                                               const float* __restrict__ tw1,
                                               const float* __restrict__ tb1,
                                               const float* __restrict__ tw2,
                                               const float* __restrict__ tb2,
                                               float* __restrict__ out){
  const int task = blockIdx.y, g0 = blockIdx.x*HG;
  const int j = threadIdx.x;
  __shared__ float fused[HG][160];
  __shared__ float red[HG][128];
  for (int idx = j; idx < HG*160; idx += 128){
    int g = idx / 160, i = idx % 160;
    float v;
    if (i < 128) v = emb[(size_t)(g0+g)*HID_ + i];
    else         v = mf[(size_t)(g0+g)*2048 + fpi[task*32 + (i-128)]];
    fused[g][i] = v;
  }
  __syncthreads();
  const float* w1 = tw1 + (size_t)task*160*128;
  float acc[HG];
  float b1 = tb1[task*128 + j];
  #pragma unroll
  for (int g=0; g<HG; g++) acc[g] = b1;
  for (int i=0; i<160; i++){
    float wv = w1[(size_t)i*128 + j];
    #pragma unroll
    for (int g=0; g<HG; g++) acc[g] += fused[g][i] * wv;
  }
  float t2 = tw2[task*128 + j];
  #pragma unroll
  for (int g=0; g<HG; g++){
    float v = acc[g] > 0.f ? acc[g] : 0.f;
    red[g][j] = v * t2;
  }
  __syncthreads();
  int g = j >> 4, l16 = j & 15;
  float s = 0.f;
  #pragma unroll
  for (int k=0;k<8;k++) s += red[g][l16 + k*16];
  s += __shfl_xor(s, 1, 16);
  s += __shfl_xor(s, 2, 16);
  s += __shfl_xor(s, 4, 16);
  s += __shfl_xor(s, 8, 16);
  if (l16 == 0) out[(size_t)(g0+g)*N_TASK + task] = s + tb2[task];
}

extern "C" void kernel_launch(void* const* d_in, const int* in_sizes, int n_in,
                              void* d_out, int out_size, void* d_ws, size_t ws_size,
                              hipStream_t stream){
  const float* x    = (const float*)d_in[0];
  const int*   ei   = (const int*)  d_in[1];
  const float* ea   = (const float*)d_in[2];
  const int*   batch= (const int*)  d_in[3];
  const float* mf   = (const float*)d_in[4];
  const int*   fpi  = (const int*)  d_in[5];
  const float* Wl0  = (const float*)d_in[6];
  const float* bl0  = (const float*)d_in[7];
  const float* Wr0  = (const float*)d_in[8];
  const float* br0  = (const float*)d_in[9];
  const float* We0  = (const float*)d_in[10];
  const float* att0 = (const float*)d_in[11];
  const float* g0   = (const float*)d_in[13];
  const float* b0   = (const float*)d_in[14];
  const float* Wl   = (const float*)d_in[15];
  const float* bl   = (const float*)d_in[16];
  const float* Wr   = (const float*)d_in[17];
  const float* br   = (const float*)d_in[18];
  const float* We   = (const float*)d_in[19];
  const float* att  = (const float*)d_in[20];
  const float* gg   = (const float*)d_in[22];
  const float* bb   = (const float*)d_in[23];
  const float* tw1  = (const float*)d_in[24];
  const float* tb1  = (const float*)d_in[25];
  const float* tw2  = (const float*)d_in[26];
  const float* tb2  = (const float*)d_in[27];
  float* out = (float*)d_out;

  char* w = (char*)d_ws;
  auto alloc = [&](size_t bytes)->char*{ char* r = w; w += (bytes + 255) & ~(size_t)255; return r; };
  u16*   xl     = (u16*)  alloc((size_t)N_NODES*HID_*2);
  unsigned* xr_aggr = (unsigned*)alloc((size_t)N_NODES*64*4);   // xr (bf16 pairs) and aggr share this
  u16*   h      = (u16*)  alloc((size_t)N_NODES*HID_*2);
  u16*   ea32   = (u16*)  alloc((size_t)N_EDGES*32*2);
  int*   counts = (int*)  alloc((size_t)N_NODES*4);             // contiguous zero region start
  int*   gcnt   = (int*)  alloc((size_t)N_GRAPH*4);
  float* stats4 = (float*)alloc(4*256*4);                       // contiguous zero region end
  int*   offsets= (int*)  alloc((size_t)(N_NODES+1)*4);
  int*   cursor = (int*)  alloc((size_t)N_NODES*4);
  int*   incl   = (int*)  alloc((size_t)N_NODES*4);
  int*   bsum   = (int*)  alloc(256*4);
  int*   ssrc   = (int*)  alloc((size_t)N_EDGES*4);
  int*   goff   = (int*)  alloc((size_t)(N_GRAPH+1)*4);
  float* emb    = (float*)alloc((size_t)N_GRAPH*HID_*4);
  u16*   Wzl0   = (u16*)  alloc((size_t)F_NODE_*128*2);
  u16*   Wzr0   = (u16*)  alloc((size_t)F_NODE_*128*2);
  u16*   Wzl123 = (u16*)  alloc((size_t)3*HID_*128*2);
  u16*   Wzr123 = (u16*)  alloc((size_t)3*HID_*128*2);
  u16*   Wez4   = (u16*)  alloc((size_t)4*32*128*2);
  u16*   eproj  = (u16*)  alloc((size_t)N_EDGES*HID_*2);        // 102.4 MB; first 12.8 MB doubles as xbf
  const size_t needed = (size_t)(w - (char*)d_ws);
  const int use_ep = (needed <= ws_size);
  u16* xbf = eproj;   // xbf region is within first 12.8 MB of eproj span (in-bounds even in fallback)

  const size_t zlen = (size_t)((char*)(stats4 + 4*256) - (char*)counts);

  const int nscan = (N_NODES + 511)/512;
  const int gemm_grid = (N_NODES + 127)/128;

  // prelude: cast + batched swizzle + single zero + merged hist + scans + scatter
  hipLaunchKernelGGL(k_cast, dim3((N_NODES*F_NODE_ + 255)/256), dim3(256), 0, stream, x, xbf, N_NODES*F_NODE_);
  {
    WZ12 p;
    p.src[0] = Wl0; p.dst[0] = Wzl0; p.Ks[0] = F_NODE_; p.Kd[0] = F_NODE_;
    p.src[1] = Wr0; p.dst[1] = Wzr0; p.Ks[1] = F_NODE_; p.Kd[1] = F_NODE_;
    for (int i=0;i<3;i++){
      p.src[2+i] = Wl + (size_t)i*HID_*HID_; p.dst[2+i] = Wzl123 + (size_t)i*HID_*128; p.Ks[2+i] = HID_; p.Kd[2+i] = HID_;
      p.src[5+i] = Wr + (size_t)i*HID_*HID_; p.dst[5+i] = Wzr123 + (size_t)i*HID_*128; p.Ks[5+i] = HID_; p.Kd[5+i] = HID_;
    }
    p.src[8] = We0; p.dst[8] = Wez4; p.Ks[8] = F_EDGE_; p.Kd[8] = 32;
    for (int i=0;i<3;i++){
      p.src[9+i] = We + (size_t)i*F_EDGE_*HID_; p.dst[9+i] = Wez4 + (size_t)(i+1)*32*128; p.Ks[9+i] = F_EDGE_; p.Kd[9+i] = 32;
    }
    hipLaunchKernelGGL(k_wswz_all, dim3((HID_*128 + 255)/256, 12), dim3(256), 0, stream, p);
  }
  hipMemsetAsync(counts, 0, zlen, stream);
  hipLaunchKernelGGL(k_hist2,  dim3(EG256 + NG256), dim3(256), 0, stream, ei, batch, counts, gcnt);
  hipLaunchKernelGGL(k_scan1,  dim3(nscan), dim3(512), 0, stream, counts, incl, bsum);
  hipLaunchKernelGGL(k_scan2,  dim3(1),     dim3(256), 0, stream, bsum, nscan);
  hipLaunchKernelGGL(k_scan3,  dim3(nscan), dim3(512), 0, stream, counts, incl, bsum, offsets, cursor);
  hipLaunchKernelGGL(k_gscan,  dim3(1),     dim3(1024),0, stream, gcnt, goff);
  hipLaunchKernelGGL(k_scatter,dim3(EG256), dim3(256), 0, stream, ei, cursor, ssrc, ea, ea32);

  for (int layer = 0; layer < 4; layer++){
    const float *bl_, *br_, *We_, *att_, *g_, *b_;
    const u16 *Wzl_, *Wzr_, *Ain;
    int K;
    if (layer == 0){
      bl_=bl0; br_=br0; We_=We0; att_=att0; g_=g0; b_=b0;
      Wzl_ = Wzl0; Wzr_ = Wzr0; Ain = xbf; K = F_NODE_;
    } else {
      int i = layer - 1;
      bl_ = bl + (size_t)i*HID_;  br_ = br + (size_t)i*HID_;
      We_ = We + (size_t)i*F_EDGE_*HID_;
      att_= att + (size_t)i*HID_;
      g_  = gg + (size_t)i*HID_;  b_  = bb + (size_t)i*HID_;
      Wzl_ = Wzl123 + (size_t)i*HID_*128;
      Wzr_ = Wzr123 + (size_t)i*HID_*128;
      Ain = h; K = HID_;
    }
    float* stats = stats4 + layer*256;
    hipLaunchKernelGGL(k_gemm_pair, dim3(gemm_grid, 2), dim3(256), 0, stream,
                       Ain, Wzl_, Wzr_, bl_, br_, xl, (u16*)xr_aggr, N_NODES, K);
    if (use_ep){
      hipLaunchKernelGGL(k_eproj, dim3((N_EDGES + 63)/64), dim3(256), 0, stream,
                         ea32, Wez4 + (size_t)layer*32*128, eproj);
      hipLaunchKernelGGL(k_gat_ep, dim3(GAT_GRID), dim3(256), 0, stream,
                         xl, xr_aggr, eproj, att_, offsets, ssrc);
    } else {
      hipLaunchKernelGGL(k_gat_fb, dim3(GAT_GRID), dim3(256), 0, stream,
                         xl, xr_aggr, ea32, We_, att_, offsets, ssrc);
    }
    hipLaunchKernelGGL(k_bn_stats, dim3(512), dim3(256), 0, stream, xr_aggr, stats);
    hipLaunchKernelGGL(k_bn_apply, dim3((N_NODES*64 + 255)/256), dim3(256), 0, stream,
                       xr_aggr, stats, g_, b_, h, layer > 0 ? 1 : 0);
  }
  hipLaunchKernelGGL(k_pool_seg, dim3(N_GRAPH), dim3(256), 0, stream, (const unsigned*)h, goff, emb);
  hipLaunchKernelGGL(k_heads, dim3(N_GRAPH/HG, N_TASK), dim3(128), 0, stream, emb, mf, fpi, tw1, tb1, tw2, tb2, out);
}

// Round 18
// 909.273 us; speedup vs baseline: 6.0426x; 1.0260x over previous
//
#include <hip/hip_runtime.h>
#include <hip/hip_bf16.h>

#define N_NODES 100000
#define N_EDGES 400000
#define F_NODE_ 64
#define F_EDGE_ 16
#define HID_ 128
#define N_GRAPH 1024
#define N_TASK 5

typedef unsigned short u16;
typedef __attribute__((ext_vector_type(8))) short frag8;   // 8 bf16 = 4 VGPRs
typedef __attribute__((ext_vector_type(4))) float f32x4;   // MFMA C/D
typedef __attribute__((ext_vector_type(2))) float f32x2;

__device__ __forceinline__ float bu2f(u16 v){ return __uint_as_float(((unsigned)v) << 16); }
__device__ __forceinline__ float2 bp2f(unsigned u){
  return make_float2(__uint_as_float(u << 16), __uint_as_float(u & 0xFFFF0000u));
}
__device__ __forceinline__ f32x2 bp2v(unsigned u){
  f32x2 r; r.x = __uint_as_float(u << 16); r.y = __uint_as_float(u & 0xFFFF0000u); return r;
}
__device__ __forceinline__ u16 f2bu(float f){
  __hip_bfloat16 h = __float2bfloat16(f);
  return *(u16*)&h;
}
__device__ __forceinline__ unsigned packbf(float a, float b){
  return (unsigned)f2bu(a) | ((unsigned)f2bu(b) << 16);
}

// ---------------- cast f32 -> bf16 fused with edge histogram ----------------
#define CAST_BLKS ((N_NODES*F_NODE_ + 255)/256)
#define EG256 ((N_EDGES + 255)/256)
__global__ __launch_bounds__(256) void k_cast_hist(const float* __restrict__ s, u16* __restrict__ d,
                                                   const int* __restrict__ ei, int* __restrict__ counts){
  int b = blockIdx.x;
  if (b < CAST_BLKS){
    int i = b*256 + threadIdx.x;
    if (i < N_NODES*F_NODE_) d[i] = f2bu(s[i]);
  } else {
    int e = (b - CAST_BLKS)*256 + threadIdx.x;
    if (e < N_EDGES) atomicAdd(&counts[ei[N_EDGES + e]], 1);
  }
}

// ---------------- batched pre-swizzle: 8 W (K=64/128) + 4 We (K=16 zero-padded to 32) ----------------
struct WZ12 { const float* src[12]; u16* dst[12]; int Ks[12]; int Kd[12]; };
__global__ __launch_bounds__(256) void k_wswz_all(WZ12 p){
  const int s = blockIdx.y;
  const int Kd = p.Kd[s], Ks = p.Ks[s];
  int i = blockIdx.x*256 + threadIdx.x;
  if (i >= Kd*128) return;
  int k = i >> 7, n = i & 127;
  float v = (k < Ks) ? p.src[s][k*128 + n] : 0.f;
  int kk = k & 31, c = k >> 5;
  int quad = kk >> 3, j = kk & 7;
  int nt = n >> 4;
  int lane = quad*16 + (n & 15);
  p.dst[s][(((c*8 + nt)*64) + lane)*8 + j] = f2bu(v);
}

// ---------------- paired MFMA GEMMs (blockIdx.y = L/R), 128 rows/block ----------------
__global__ __launch_bounds__(256) void k_gemm_pair(const u16* __restrict__ A,
                                                   const u16* __restrict__ Wzl,
                                                   const u16* __restrict__ Wzr,
                                                   const float* __restrict__ bl,
                                                   const float* __restrict__ br,
                                                   u16* __restrict__ Cl,
                                                   u16* Cr,
                                                   int M, int K){
  const u16*   Wz   = blockIdx.y ? Wzr : Wzl;
  const float* bias = blockIdx.y ? br  : bl;
  u16*         C    = blockIdx.y ? Cr  : Cl;
  __shared__ u16 WS[128*128];
  const int t = threadIdx.x;
  {
    const uint4* src = (const uint4*)Wz;
    uint4* dst = (uint4*)WS;
    const int n = (K*128) >> 3;
    for (int i = t; i < n; i += 256) dst[i] = src[i];
  }
  __syncthreads();
  const int w = t >> 6, l = t & 63;
  const int m = l & 15, quad = l >> 4;
  const int rowA0 = blockIdx.x*128 + w*32 + m;
  const int rowA1 = rowA0 + 16;
  f32x4 acc[2][8];
  #pragma unroll
  for (int i=0;i<2;i++)
    #pragma unroll
    for (int j=0;j<8;j++) acc[i][j] = (f32x4){0.f,0.f,0.f,0.f};
  const int KC = K >> 5;
  for (int c = 0; c < KC; c++){
    frag8 a0 = {}, a1 = {};
    if (rowA0 < M) a0 = *(const frag8*)(A + (size_t)rowA0*K + c*32 + quad*8);
    if (rowA1 < M) a1 = *(const frag8*)(A + (size_t)rowA1*K + c*32 + quad*8);
    #pragma unroll
    for (int nt = 0; nt < 8; nt++){
      frag8 b = *(const frag8*)&WS[(((c*8 + nt)*64) + l)*8];
      acc[0][nt] = __builtin_amdgcn_mfma_f32_16x16x32_bf16(a0, b, acc[0][nt], 0,0,0);
      acc[1][nt] = __builtin_amdgcn_mfma_f32_16x16x32_bf16(a1, b, acc[1][nt], 0,0,0);
    }
  }
  #pragma unroll
  for (int rt = 0; rt < 2; rt++){
    int rbase = blockIdx.x*128 + w*32 + rt*16 + quad*4;
    #pragma unroll
    for (int nt = 0; nt < 8; nt++){
      int col = nt*16 + m;
      float bc = bias[col];
      #pragma unroll
      for (int r = 0; r < 4; r++){
        int row = rbase + r;
        if (row < M) C[(size_t)row*128 + col] = f2bu(acc[rt][nt][r] + bc);
      }
    }
  }
}

// ---------------- eproj = ea32 @ We (K=32), bf16 out, MFMA ----------------
__global__ __launch_bounds__(256) void k_eproj(const u16* __restrict__ ea32,
                                               const u16* __restrict__ Wez,
                                               u16* __restrict__ eproj){
  __shared__ u16 WS[32*128];   // 8 KB
  const int t = threadIdx.x;
  {
    const uint4* s4 = (const uint4*)Wez;
    uint4* d4 = (uint4*)WS;
    for (int i = t; i < 512; i += 256) d4[i] = s4[i];
  }
  __syncthreads();
  const int w = t >> 6, l = t & 63, m = l & 15, quad = l >> 4;
  const int row0 = blockIdx.x*64 + w*16 + m;
  f32x4 acc[8];
  #pragma unroll
  for (int i=0;i<8;i++) acc[i] = (f32x4){0.f,0.f,0.f,0.f};
  frag8 a = {};
  if (row0 < N_EDGES) a = *(const frag8*)(ea32 + (size_t)row0*32 + quad*8);
  #pragma unroll
  for (int nt = 0; nt < 8; nt++){
    frag8 b = *(const frag8*)&WS[(nt*64 + l)*8];
    acc[nt] = __builtin_amdgcn_mfma_f32_16x16x32_bf16(a, b, acc[nt], 0,0,0);
  }
  const int rbase = blockIdx.x*64 + w*16 + quad*4;
  #pragma unroll
  for (int nt = 0; nt < 8; nt++){
    int col = nt*16 + m;
    #pragma unroll
    for (int r = 0; r < 4; r++){
      int row = rbase + r;
      if (row < N_EDGES) eproj[(size_t)row*128 + col] = f2bu(acc[nt][r]);
    }
  }
}

__global__ __launch_bounds__(512) void k_scan1(const int* __restrict__ counts,
                                               int* __restrict__ incl,
                                               int* __restrict__ bsum){
  __shared__ int s[512];
  const int t = threadIdx.x;
  int i = blockIdx.x*512 + t;
  int v = (i < N_NODES) ? counts[i] : 0;
  s[t] = v;
  __syncthreads();
  for (int off = 1; off < 512; off <<= 1){
    int x = (t >= off) ? s[t - off] : 0;
    __syncthreads();
    s[t] += x;
    __syncthreads();
  }
  if (i < N_NODES) incl[i] = s[t];
  if (t == 511) bsum[blockIdx.x] = s[511];
}

// scan of block sums + graph offsets via binary search on sorted batch (no atomics)
__global__ __launch_bounds__(256) void k_scan2(int* __restrict__ bsum, int nb,
                                               const int* __restrict__ batch,
                                               int* __restrict__ goff){
  __shared__ int s[256];
  const int t = threadIdx.x;
  int v = (t < nb) ? bsum[t] : 0;
  s[t] = v;
  __syncthreads();
  for (int off = 1; off < 256; off <<= 1){
    int x = (t >= off) ? s[t - off] : 0;
    __syncthreads();
    s[t] += x;
    __syncthreads();
  }
  if (t < nb) bsum[t] = s[t] - v;
  // goff[g] = lower_bound(batch, g), g in [0, N_GRAPH]
  for (int g = t; g <= N_GRAPH; g += 256){
    int lo = 0, hi = N_NODES;
    while (lo < hi){
      int mid = (lo + hi) >> 1;
      if (batch[mid] < g) lo = mid + 1; else hi = mid;
    }
    goff[g] = lo;
  }
}

__global__ __launch_bounds__(512) void k_scan3(const int* __restrict__ counts,
                                               const int* __restrict__ incl,
                                               const int* __restrict__ bsum,
                                               int* __restrict__ offsets,
                                               int* __restrict__ cursor){
  int i = blockIdx.x*512 + threadIdx.x;
  if (i >= N_NODES) return;
  int o = bsum[blockIdx.x] + incl[i];
  offsets[i + 1] = o;
  cursor[i]      = o - counts[i];
  if (i == 0) offsets[0] = 0;
}

// scatter: src index + bf16 edge features into CSR order, zero-padded to 32
__global__ __launch_bounds__(256) void k_scatter(const int* __restrict__ ei,
                                                 int* __restrict__ cursor,
                                                 int* __restrict__ ssrc,
                                                 const float* __restrict__ ea,
                                                 u16* __restrict__ ea32){
  int e = blockIdx.x*256 + threadIdx.x;
  if (e >= N_EDGES) return;
  int dst = ei[N_EDGES + e];
  int pos = atomicAdd(&cursor[dst], 1);
  ssrc[pos] = ei[e];
  const float* s = ea + (size_t)e*F_EDGE_;
  unsigned p[8];
  #pragma unroll
  for (int k=0;k<8;k++) p[k] = packbf(s[2*k], s[2*k+1]);
  uint4* d4 = (uint4*)(ea32 + (size_t)pos*32);
  d4[0] = make_uint4(p[0],p[1],p[2],p[3]);
  d4[1] = make_uint4(p[4],p[5],p[6],p[7]);
  d4[2] = make_uint4(0,0,0,0);
  d4[3] = make_uint4(0,0,0,0);
}

// ---------------- Fused GAT v9-ep: eproj precomputed; aggr aliased onto xr ----------------
#define GAT_GRID 6250
__global__ __launch_bounds__(256) void k_gat_ep(const u16* __restrict__ xl,
                                                unsigned* xr_aggr,
                                                const u16* __restrict__ eproj,
                                                const float* __restrict__ att,
                                                const int* __restrict__ offsets,
                                                const int* __restrict__ ssrc){
  const int t = threadIdx.x;
  const int wave = t >> 6, lane = t & 63;
  const int c0 = lane*2;
  const float a0 = att[c0], a1 = att[c0+1];

  for (int node = blockIdx.x*4 + wave; node < N_NODES; node += GAT_GRID*4){
    const f32x2 xrv = bp2v(xr_aggr[(size_t)node*64 + lane]);
    f32x2 accv = {0.f, 0.f};
    float den = 0.f;
    const int beg = offsets[node], end = offsets[node+1];
    for (int i = beg; i < end; i += 4){
      const int mm = end - i;
      const int i1 = (mm > 1) ? i+1 : i;
      const int i2 = (mm > 2) ? i+2 : i;
      const int i3 = (mm > 3) ? i+3 : i;
      int s0 = ssrc[i], s1 = ssrc[i1], s2 = ssrc[i2], s3 = ssrc[i3];
      unsigned ep0 = *(const unsigned*)(eproj + (size_t)i *128 + c0);
      unsigned ep1 = *(const unsigned*)(eproj + (size_t)i1*128 + c0);
      unsigned ep2 = *(const unsigned*)(eproj + (size_t)i2*128 + c0);
      unsigned ep3 = *(const unsigned*)(eproj + (size_t)i3*128 + c0);
      f32x2 vl0 = bp2v(*(const unsigned*)(xl + (size_t)s0*HID_ + c0));
      f32x2 vl1 = bp2v(*(const unsigned*)(xl + (size_t)s1*HID_ + c0));
      f32x2 vl2 = bp2v(*(const unsigned*)(xl + (size_t)s2*HID_ + c0));
      f32x2 vl3 = bp2v(*(const unsigned*)(xl + (size_t)s3*HID_ + c0));
      f32x2 v0 = vl0 + xrv + bp2v(ep0);
      f32x2 v1 = vl1 + xrv + bp2v(ep1);
      f32x2 v2 = vl2 + xrv + bp2v(ep2);
      f32x2 v3 = vl3 + xrv + bp2v(ep3);
      f32x2 w0 = v0*0.2f, w1 = v1*0.2f, w2 = v2*0.2f, w3 = v3*0.2f;
      v0.x = fmaxf(v0.x,w0.x); v0.y = fmaxf(v0.y,w0.y);
      v1.x = fmaxf(v1.x,w1.x); v1.y = fmaxf(v1.y,w1.y);
      v2.x = fmaxf(v2.x,w2.x); v2.y = fmaxf(v2.y,w2.y);
      v3.x = fmaxf(v3.x,w3.x); v3.y = fmaxf(v3.y,w3.y);
      float sc0 = v0.x*a0 + v0.y*a1;
      float sc1 = v1.x*a0 + v1.y*a1;
      float sc2 = v2.x*a0 + v2.y*a1;
      float sc3 = v3.x*a0 + v3.y*a1;
      sc0 += __shfl_xor(sc0, 1); sc1 += __shfl_xor(sc1, 1); sc2 += __shfl_xor(sc2, 1); sc3 += __shfl_xor(sc3, 1);
      sc0 += __shfl_xor(sc0, 2); sc1 += __shfl_xor(sc1, 2); sc2 += __shfl_xor(sc2, 2); sc3 += __shfl_xor(sc3, 2);
      sc0 += __shfl_xor(sc0, 4); sc1 += __shfl_xor(sc1, 4); sc2 += __shfl_xor(sc2, 4); sc3 += __shfl_xor(sc3, 4);
      sc0 += __shfl_xor(sc0, 8); sc1 += __shfl_xor(sc1, 8); sc2 += __shfl_xor(sc2, 8); sc3 += __shfl_xor(sc3, 8);
      float p0 = __expf(sc0);
      float p1 = (mm > 1) ? __expf(sc1) : 0.f;
      float p2 = (mm > 2) ? __expf(sc2) : 0.f;
      float p3 = (mm > 3) ? __expf(sc3) : 0.f;
      accv += p0*vl0 + p1*vl1 + p2*vl2 + p3*vl3;
      den  += p0 + p1 + p2 + p3;
    }
    float inv = 1.0f / (den + 1e-16f);
    xr_aggr[(size_t)node*64 + lane] = packbf(accv.x*inv, accv.y*inv);
  }
}

// ---------------- BN stats (bf16 aggr input) ----------------
__global__ __launch_bounds__(256) void k_bn_stats(const unsigned* __restrict__ aggr_b,
                                                  float* __restrict__ stats){
  __shared__ float redS[4][128], redQ[4][128];
  const int t = threadIdx.x;
  const int p = t & 63, rg = t >> 6;
  const int c0 = p*2;
  float s0=0.f, s1=0.f, q0=0.f, q1=0.f;
  for (int r = blockIdx.x*4 + rg; r < N_NODES; r += gridDim.x*4){
    float2 v = bp2f(aggr_b[(size_t)r*64 + p]);
    s0 += v.x; s1 += v.y; q0 += v.x*v.x; q1 += v.y*v.y;
  }
  redS[rg][c0] = s0; redS[rg][c0+1] = s1;
  redQ[rg][c0] = q0; redQ[rg][c0+1] = q1;
  __syncthreads();
  if (rg == 0){
    #pragma unroll
    for (int g=1; g<4; g++){
      s0 += redS[g][c0]; s1 += redS[g][c0+1];
      q0 += redQ[g][c0]; q1 += redQ[g][c0+1];
    }
    atomicAdd(&stats[c0],     s0);
    atomicAdd(&stats[c0+1],   s1);
    atomicAdd(&stats[128+c0],   q0);
    atomicAdd(&stats[128+c0+1], q1);
  }
}

// ---------------- BN apply + ELU (+ residual), bf16 in/out ----------------
__global__ __launch_bounds__(256) void k_bn_apply(const unsigned* __restrict__ aggr_b,
                                                  const float* __restrict__ stats,
                                                  const float* __restrict__ gamma,
                                                  const float* __restrict__ beta,
                                                  u16* __restrict__ h, int residual){
  size_t i = (size_t)blockIdx.x*256 + threadIdx.x;
  if (i >= (size_t)N_NODES*64) return;
  int c = (int)((i & 63)*2);
  const float invn = 1.0f / (float)N_NODES;
  float mu0  = stats[c]   * invn,  mu1  = stats[c+1]   * invn;
  float var0 = stats[128+c]*invn - mu0*mu0;
  float var1 = stats[129+c]*invn - mu1*mu1;
  float sc0 = rsqrtf(var0 + 1e-5f) * gamma[c];
  float sc1 = rsqrtf(var1 + 1e-5f) * gamma[c+1];
  float2 v = bp2f(aggr_b[i]);
  float val0 = (v.x - mu0) * sc0 + beta[c];
  float val1 = (v.y - mu1) * sc1 + beta[c+1];
  val0 = val0 > 0.f ? val0 : expm1f(val0);
  val1 = val1 > 0.f ? val1 : expm1f(val1);
  unsigned* hp = (unsigned*)h + i;
  if (residual){
    float2 hv = bp2f(*hp);
    val0 += hv.x; val1 += hv.y;
  }
  *hp = packbf(val0, val1);
}

// ---------------- Pool: segmented mean, 4 row-groups in flight ----------------
__global__ __launch_bounds__(256) void k_pool_seg(const unsigned* __restrict__ h2,
                                                  const int* __restrict__ goff,
                                                  float* __restrict__ emb){
  __shared__ float redS[4][128];
  const int g = blockIdx.x, t = threadIdx.x;
  const int p = t & 63, rg = t >> 6;
  const int beg = goff[g], end = goff[g+1];
  float a0 = 0.f, a1 = 0.f;
  for (int r = beg + rg; r < end; r += 4){
    float2 v = bp2f(h2[(size_t)r*64 + p]);
    a0 += v.x; a1 += v.y;
  }
  redS[rg][p*2] = a0; redS[rg][p*2+1] = a1;
  __syncthreads();
  if (rg == 0){
    #pragma unroll
    for (int k=1;k<4;k++){ a0 += redS[k][p*2]; a1 += redS[k][p*2+1]; }
    float n = fmaxf((float)(end - beg), 1.f);
    emb[(size_t)g*HID_ + p*2]     = a0 / n;
    emb[(size_t)g*HID_ + p*2 + 1] = a1 / n;
  }
}

// ---------------- Per-task heads: 8 graphs per block ----------------
#define HG 8
__global__ __launch_bounds__(128) void k_heads(const float* __restrict__ emb,
                                               const float* __restrict__ mf,
                                               const int* __restrict__ fpi,
                                               const float* __restrict__ tw1,
                                               const float* __restrict__ tb1,
                                               const float* __restrict__ tw2,
                                               const float* __restrict__ tb2,
                                               float* __restrict__ out){
  const int task = blockIdx.y, g0 = blockIdx.x*HG;
  const int j = threadIdx.x;
  __shared__ float fused[HG][160];
  __shared__ float red[HG][128];
  for (int idx = j; idx < HG*160; idx += 128){
    int g = idx / 160, i = idx % 160;
    float v;
    if (i < 128) v = emb[(size_t)(g0+g)*HID_ + i];
    else         v = mf[(size_t)(g0+g)*2048 + fpi[task*32 + (i-128)]];
    fused[g][i] = v;
  }
  __syncthreads();
  const float* w1 = tw1 + (size_t)task*160*128;
  float acc[HG];
  float b1 = tb1[task*128 + j];
  #pragma unroll
  for (int g=0; g<HG; g++) acc[g] = b1;
  for (int i=0; i<160; i++){
    float wv = w1[(size_t)i*128 + j];
    #pragma unroll
    for (int g=0; g<HG; g++) acc[g] += fused[g][i] * wv;
  }
  float t2 = tw2[task*128 + j];
  #pragma unroll
  for (int g=0; g<HG; g++){
    float v = acc[g] > 0.f ? acc[g] : 0.f;
    red[g][j] = v * t2;
  }
  __syncthreads();
  int g = j >> 4, l16 = j & 15;
  float s = 0.f;
  #pragma unroll
  for (int k=0;k<8;k++) s += red[g][l16 + k*16];
  s += __shfl_xor(s, 1, 16);
  s += __shfl_xor(s, 2, 16);
  s += __shfl_xor(s, 4, 16);
  s += __shfl_xor(s, 8, 16);
  if (l16 == 0) out[(size_t)(g0+g)*N_TASK + task] = s + tb2[task];
}

extern "C" void kernel_launch(void* const* d_in, const int* in_sizes, int n_in,
                              void* d_out, int out_size, void* d_ws, size_t ws_size,
                              hipStream_t stream){
  const float* x    = (const float*)d_in[0];
  const int*   ei   = (const int*)  d_in[1];
  const float* ea   = (const float*)d_in[2];
  const int*   batch= (const int*)  d_in[3];
  const float* mf   = (const float*)d_in[4];
  const int*   fpi  = (const int*)  d_in[5];
  const float* Wl0  = (const float*)d_in[6];
  const float* bl0  = (const float*)d_in[7];
  const float* Wr0  = (const float*)d_in[8];
  const float* br0  = (const float*)d_in[9];
  const float* We0  = (const float*)d_in[10];
  const float* att0 = (const float*)d_in[11];
  const float* g0   = (const float*)d_in[13];
  const float* b0   = (const float*)d_in[14];
  const float* Wl   = (const float*)d_in[15];
  const float* bl   = (const float*)d_in[16];
  const float* Wr   = (const float*)d_in[17];
  const float* br   = (const float*)d_in[18];
  const float* We   = (const float*)d_in[19];
  const float* att  = (const float*)d_in[20];
  const float* gg   = (const float*)d_in[22];
  const float* bb   = (const float*)d_in[23];
  const float* tw1  = (const float*)d_in[24];
  const float* tb1  = (const float*)d_in[25];
  const float* tw2  = (const float*)d_in[26];
  const float* tb2  = (const float*)d_in[27];
  float* out = (float*)d_out;

  char* w = (char*)d_ws;
  auto alloc = [&](size_t bytes)->char*{ char* r = w; w += (bytes + 255) & ~(size_t)255; return r; };
  u16*   xl     = (u16*)  alloc((size_t)N_NODES*HID_*2);
  unsigned* xr_aggr = (unsigned*)alloc((size_t)N_NODES*64*4);   // xr (bf16 pairs) and aggr share this
  u16*   h      = (u16*)  alloc((size_t)N_NODES*HID_*2);
  u16*   ea32   = (u16*)  alloc((size_t)N_EDGES*32*2);
  int*   counts = (int*)  alloc((size_t)N_NODES*4);             // zero region start
  float* stats4 = (float*)alloc(4*256*4);                       // zero region end
  int*   offsets= (int*)  alloc((size_t)(N_NODES+1)*4);
  int*   cursor = (int*)  alloc((size_t)N_NODES*4);
  int*   incl   = (int*)  alloc((size_t)N_NODES*4);
  int*   bsum   = (int*)  alloc(256*4);
  int*   ssrc   = (int*)  alloc((size_t)N_EDGES*4);
  int*   goff   = (int*)  alloc((size_t)(N_GRAPH+1)*4);
  float* emb    = (float*)alloc((size_t)N_GRAPH*HID_*4);
  u16*   Wzl0   = (u16*)  alloc((size_t)F_NODE_*128*2);
  u16*   Wzr0   = (u16*)  alloc((size_t)F_NODE_*128*2);
  u16*   Wzl123 = (u16*)  alloc((size_t)3*HID_*128*2);
  u16*   Wzr123 = (u16*)  alloc((size_t)3*HID_*128*2);
  u16*   Wez4   = (u16*)  alloc((size_t)4*32*128*2);
  u16*   eproj  = (u16*)  alloc((size_t)N_EDGES*HID_*2);        // 102.4 MB; first 12.8 MB doubles as xbf
  u16* xbf = eproj;

  const size_t zlen = (size_t)((char*)(stats4 + 4*256) - (char*)counts);
  const int nscan = (N_NODES + 511)/512;
  const int gemm_grid = (N_NODES + 127)/128;

  // prelude
  {
    WZ12 p;
    p.src[0] = Wl0; p.dst[0] = Wzl0; p.Ks[0] = F_NODE_; p.Kd[0] = F_NODE_;
    p.src[1] = Wr0; p.dst[1] = Wzr0; p.Ks[1] = F_NODE_; p.Kd[1] = F_NODE_;
    for (int i=0;i<3;i++){
      p.src[2+i] = Wl + (size_t)i*HID_*HID_; p.dst[2+i] = Wzl123 + (size_t)i*HID_*128; p.Ks[2+i] = HID_; p.Kd[2+i] = HID_;
      p.src[5+i] = Wr + (size_t)i*HID_*HID_; p.dst[5+i] = Wzr123 + (size_t)i*HID_*128; p.Ks[5+i] = HID_; p.Kd[5+i] = HID_;
    }
    p.src[8] = We0; p.dst[8] = Wez4; p.Ks[8] = F_EDGE_; p.Kd[8] = 32;
    for (int i=0;i<3;i++){
      p.src[9+i] = We + (size_t)i*F_EDGE_*HID_; p.dst[9+i] = Wez4 + (size_t)(i+1)*32*128; p.Ks[9+i] = F_EDGE_; p.Kd[9+i] = 32;
    }
    hipLaunchKernelGGL(k_wswz_all, dim3((HID_*128 + 255)/256, 12), dim3(256), 0, stream, p);
  }
  hipMemsetAsync(counts, 0, zlen, stream);
  hipLaunchKernelGGL(k_cast_hist, dim3(CAST_BLKS + EG256), dim3(256), 0, stream, x, xbf, ei, counts);
  hipLaunchKernelGGL(k_scan1,  dim3(nscan), dim3(512), 0, stream, counts, incl, bsum);
  hipLaunchKernelGGL(k_scan2,  dim3(1),     dim3(256), 0, stream, bsum, nscan, batch, goff);
  hipLaunchKernelGGL(k_scan3,  dim3(nscan), dim3(512), 0, stream, counts, incl, bsum, offsets, cursor);
  hipLaunchKernelGGL(k_scatter,dim3(EG256), dim3(256), 0, stream, ei, cursor, ssrc, ea, ea32);

  for (int layer = 0; layer < 4; layer++){
    const float *bl_, *br_, *att_, *g_, *b_;
    const u16 *Wzl_, *Wzr_, *Ain;
    int K;
    if (layer == 0){
      bl_=bl0; br_=br0; att_=att0; g_=g0; b_=b0;
      Wzl_ = Wzl0; Wzr_ = Wzr0; Ain = xbf; K = F_NODE_;
    } else {
      int i = layer - 1;
      bl_ = bl + (size_t)i*HID_;  br_ = br + (size_t)i*HID_;
      att_= att + (size_t)i*HID_;
      g_  = gg + (size_t)i*HID_;  b_  = bb + (size_t)i*HID_;
      Wzl_ = Wzl123 + (size_t)i*HID_*128;
      Wzr_ = Wzr123 + (size_t)i*HID_*128;
      Ain = h; K = HID_;
    }
    float* stats = stats4 + layer*256;
    hipLaunchKernelGGL(k_gemm_pair, dim3(gemm_grid, 2), dim3(256), 0, stream,
                       Ain, Wzl_, Wzr_, bl_, br_, xl, (u16*)xr_aggr, N_NODES, K);
    hipLaunchKernelGGL(k_eproj, dim3((N_EDGES + 63)/64), dim3(256), 0, stream,
                       ea32, Wez4 + (size_t)layer*32*128, eproj);
    hipLaunchKernelGGL(k_gat_ep, dim3(GAT_GRID), dim3(256), 0, stream,
                       xl, xr_aggr, eproj, att_, offsets, ssrc);
    hipLaunchKernelGGL(k_bn_stats, dim3(512), dim3(256), 0, stream, xr_aggr, stats);
    hipLaunchKernelGGL(k_bn_apply, dim3((N_NODES*64 + 255)/256), dim3(256), 0, stream,
                       xr_aggr, stats, g_, b_, h, layer > 0 ? 1 : 0);
  }
  hipLaunchKernelGGL(k_pool_seg, dim3(N_GRAPH), dim3(256), 0, stream, (const unsigned*)h, goff, emb);
  hipLaunchKernelGGL(k_heads, dim3(N_GRAPH/HG, N_TASK), dim3(128), 0, stream, emb, mf, fpi, tw1, tb1, tw2, tb2, out);
}

// Round 19
// 871.228 us; speedup vs baseline: 6.3065x; 1.0437x over previous
//
#include <hip/hip_runtime.h>
#include <hip/hip_bf16.h>

#define N_NODES 100000
#define N_EDGES 400000
#define F_NODE_ 64
#define F_EDGE_ 16
#define HID_ 128
#define N_GRAPH 1024
#define N_TASK 5

typedef unsigned short u16;
typedef __attribute__((ext_vector_type(8))) short frag8;   // 8 bf16 = 4 VGPRs
typedef __attribute__((ext_vector_type(4))) float f32x4;   // MFMA C/D
typedef __attribute__((ext_vector_type(2))) float f32x2;

__device__ __forceinline__ float bu2f(u16 v){ return __uint_as_float(((unsigned)v) << 16); }
__device__ __forceinline__ float2 bp2f(unsigned u){
  return make_float2(__uint_as_float(u << 16), __uint_as_float(u & 0xFFFF0000u));
}
__device__ __forceinline__ f32x2 bp2v(unsigned u){
  f32x2 r; r.x = __uint_as_float(u << 16); r.y = __uint_as_float(u & 0xFFFF0000u); return r;
}
__device__ __forceinline__ u16 f2bu(float f){
  __hip_bfloat16 h = __float2bfloat16(f);
  return *(u16*)&h;
}
__device__ __forceinline__ unsigned packbf(float a, float b){
  return (unsigned)f2bu(a) | ((unsigned)f2bu(b) << 16);
}

// ---------------- cast f32 -> bf16 fused with edge histogram ----------------
#define CAST_BLKS ((N_NODES*F_NODE_ + 255)/256)
#define EG256 ((N_EDGES + 255)/256)
__global__ __launch_bounds__(256) void k_cast_hist(const float* __restrict__ s, u16* __restrict__ d,
                                                   const int* __restrict__ ei, int* __restrict__ counts){
  int b = blockIdx.x;
  if (b < CAST_BLKS){
    int i = b*256 + threadIdx.x;
    if (i < N_NODES*F_NODE_) d[i] = f2bu(s[i]);
  } else {
    int e = (b - CAST_BLKS)*256 + threadIdx.x;
    if (e < N_EDGES) atomicAdd(&counts[ei[N_EDGES + e]], 1);
  }
}

// ---------------- batched pre-swizzle: 8 W (K=64/128) + 4 We (K=16 zero-padded to 32) ----------------
struct WZ12 { const float* src[12]; u16* dst[12]; int Ks[12]; int Kd[12]; };
__global__ __launch_bounds__(256) void k_wswz_all(WZ12 p){
  const int s = blockIdx.y;
  const int Kd = p.Kd[s], Ks = p.Ks[s];
  int i = blockIdx.x*256 + threadIdx.x;
  if (i >= Kd*128) return;
  int k = i >> 7, n = i & 127;
  float v = (k < Ks) ? p.src[s][k*128 + n] : 0.f;
  int kk = k & 31, c = k >> 5;
  int quad = kk >> 3, j = kk & 7;
  int nt = n >> 4;
  int lane = quad*16 + (n & 15);
  p.dst[s][(((c*8 + nt)*64) + lane)*8 + j] = f2bu(v);
}

// ---------------- fused: paired MFMA GEMMs + eproj MFMA GEMM (flat grid) ----------------
#define GEMM_GRID ((N_NODES + 127)/128)   // 782
#define EPROJ_GRID ((N_EDGES + 63)/64)    // 6250
__global__ __launch_bounds__(256) void k_gemm_eproj(const u16* __restrict__ A,
                                                    const u16* __restrict__ Wzl,
                                                    const u16* __restrict__ Wzr,
                                                    const float* __restrict__ bl,
                                                    const float* __restrict__ br,
                                                    u16* __restrict__ Cl,
                                                    u16* Cr,
                                                    int M, int K,
                                                    const u16* __restrict__ ea32,
                                                    const u16* __restrict__ Wez,
                                                    u16* __restrict__ eproj){
  __shared__ u16 WS[128*128];
  const int t = threadIdx.x;
  const int b = blockIdx.x;
  if (b < 2*GEMM_GRID){
    const int which = (b >= GEMM_GRID);
    const int bx = which ? b - GEMM_GRID : b;
    const u16*   Wz   = which ? Wzr : Wzl;
    const float* bias = which ? br  : bl;
    u16*         C    = which ? Cr  : Cl;
    {
      const uint4* src = (const uint4*)Wz;
      uint4* dst = (uint4*)WS;
      const int n = (K*128) >> 3;
      for (int i = t; i < n; i += 256) dst[i] = src[i];
    }
    __syncthreads();
    const int w = t >> 6, l = t & 63;
    const int m = l & 15, quad = l >> 4;
    const int rowA0 = bx*128 + w*32 + m;
    const int rowA1 = rowA0 + 16;
    f32x4 acc[2][8];
    #pragma unroll
    for (int i=0;i<2;i++)
      #pragma unroll
      for (int j=0;j<8;j++) acc[i][j] = (f32x4){0.f,0.f,0.f,0.f};
    const int KC = K >> 5;
    for (int c = 0; c < KC; c++){
      frag8 a0 = {}, a1 = {};
      if (rowA0 < M) a0 = *(const frag8*)(A + (size_t)rowA0*K + c*32 + quad*8);
      if (rowA1 < M) a1 = *(const frag8*)(A + (size_t)rowA1*K + c*32 + quad*8);
      #pragma unroll
      for (int nt = 0; nt < 8; nt++){
        frag8 bfr = *(const frag8*)&WS[(((c*8 + nt)*64) + l)*8];
        acc[0][nt] = __builtin_amdgcn_mfma_f32_16x16x32_bf16(a0, bfr, acc[0][nt], 0,0,0);
        acc[1][nt] = __builtin_amdgcn_mfma_f32_16x16x32_bf16(a1, bfr, acc[1][nt], 0,0,0);
      }
    }
    #pragma unroll
    for (int rt = 0; rt < 2; rt++){
      int rbase = bx*128 + w*32 + rt*16 + quad*4;
      #pragma unroll
      for (int nt = 0; nt < 8; nt++){
        int col = nt*16 + m;
        float bc = bias[col];
        #pragma unroll
        for (int r = 0; r < 4; r++){
          int row = rbase + r;
          if (row < M) C[(size_t)row*128 + col] = f2bu(acc[rt][nt][r] + bc);
        }
      }
    }
  } else {
    const int bx = b - 2*GEMM_GRID;
    {
      const uint4* s4 = (const uint4*)Wez;
      uint4* d4 = (uint4*)WS;
      for (int i = t; i < 512; i += 256) d4[i] = s4[i];
    }
    __syncthreads();
    const int w = t >> 6, l = t & 63, m = l & 15, quad = l >> 4;
    const int row0 = bx*64 + w*16 + m;
    f32x4 acc[8];
    #pragma unroll
    for (int i=0;i<8;i++) acc[i] = (f32x4){0.f,0.f,0.f,0.f};
    frag8 a = {};
    if (row0 < N_EDGES) a = *(const frag8*)(ea32 + (size_t)row0*32 + quad*8);
    #pragma unroll
    for (int nt = 0; nt < 8; nt++){
      frag8 bfr = *(const frag8*)&WS[(nt*64 + l)*8];
      acc[nt] = __builtin_amdgcn_mfma_f32_16x16x32_bf16(a, bfr, acc[nt], 0,0,0);
    }
    const int rbase = bx*64 + w*16 + quad*4;
    #pragma unroll
    for (int nt = 0; nt < 8; nt++){
      int col = nt*16 + m;
      #pragma unroll
      for (int r = 0; r < 4; r++){
        int row = rbase + r;
        if (row < N_EDGES) eproj[(size_t)row*128 + col] = f2bu(acc[nt][r]);
      }
    }
  }
}

__global__ __launch_bounds__(512) void k_scan1(const int* __restrict__ counts,
                                               int* __restrict__ incl,
                                               int* __restrict__ bsum){
  __shared__ int s[512];
  const int t = threadIdx.x;
  int i = blockIdx.x*512 + t;
  int v = (i < N_NODES) ? counts[i] : 0;
  s[t] = v;
  __syncthreads();
  for (int off = 1; off < 512; off <<= 1){
    int x = (t >= off) ? s[t - off] : 0;
    __syncthreads();
    s[t] += x;
    __syncthreads();
  }
  if (i < N_NODES) incl[i] = s[t];
  if (t == 511) bsum[blockIdx.x] = s[511];
}

// scan of block sums + graph offsets via binary search on sorted batch
__global__ __launch_bounds__(256) void k_scan2(int* __restrict__ bsum, int nb,
                                               const int* __restrict__ batch,
                                               int* __restrict__ goff){
  __shared__ int s[256];
  const int t = threadIdx.x;
  int v = (t < nb) ? bsum[t] : 0;
  s[t] = v;
  __syncthreads();
  for (int off = 1; off < 256; off <<= 1){
    int x = (t >= off) ? s[t - off] : 0;
    __syncthreads();
    s[t] += x;
    __syncthreads();
  }
  if (t < nb) bsum[t] = s[t] - v;
  for (int g = t; g <= N_GRAPH; g += 256){
    int lo = 0, hi = N_NODES;
    while (lo < hi){
      int mid = (lo + hi) >> 1;
      if (batch[mid] < g) lo = mid + 1; else hi = mid;
    }
    goff[g] = lo;
  }
}

__global__ __launch_bounds__(512) void k_scan3(const int* __restrict__ counts,
                                               const int* __restrict__ incl,
                                               const int* __restrict__ bsum,
                                               int* __restrict__ offsets,
                                               int* __restrict__ cursor){
  int i = blockIdx.x*512 + threadIdx.x;
  if (i >= N_NODES) return;
  int o = bsum[blockIdx.x] + incl[i];
  offsets[i + 1] = o;
  cursor[i]      = o - counts[i];
  if (i == 0) offsets[0] = 0;
}

// scatter: src index + bf16 edge features into CSR order, zero-padded to 32
__global__ __launch_bounds__(256) void k_scatter(const int* __restrict__ ei,
                                                 int* __restrict__ cursor,
                                                 int* __restrict__ ssrc,
                                                 const float* __restrict__ ea,
                                                 u16* __restrict__ ea32){
  int e = blockIdx.x*256 + threadIdx.x;
  if (e >= N_EDGES) return;
  int dst = ei[N_EDGES + e];
  int pos = atomicAdd(&cursor[dst], 1);
  ssrc[pos] = ei[e];
  const float* s = ea + (size_t)e*F_EDGE_;
  unsigned p[8];
  #pragma unroll
  for (int k=0;k<8;k++) p[k] = packbf(s[2*k], s[2*k+1]);
  uint4* d4 = (uint4*)(ea32 + (size_t)pos*32);
  d4[0] = make_uint4(p[0],p[1],p[2],p[3]);
  d4[1] = make_uint4(p[4],p[5],p[6],p[7]);
  d4[2] = make_uint4(0,0,0,0);
  d4[3] = make_uint4(0,0,0,0);
}

// ---------------- Fused GAT v10: eproj precomputed; 1 node per wave; aggr aliased onto xr ----------------
#define GAT_GRID 25000
__global__ __launch_bounds__(256) void k_gat_ep(const u16* __restrict__ xl,
                                                unsigned* xr_aggr,
                                                const u16* __restrict__ eproj,
                                                const float* __restrict__ att,
                                                const int* __restrict__ offsets,
                                                const int* __restrict__ ssrc){
  const int t = threadIdx.x;
  const int wave = t >> 6, lane = t & 63;
  const int c0 = lane*2;
  const float a0 = att[c0], a1 = att[c0+1];

  const int node = blockIdx.x*4 + wave;
  if (node >= N_NODES) return;
  {
    const f32x2 xrv = bp2v(xr_aggr[(size_t)node*64 + lane]);
    f32x2 accv = {0.f, 0.f};
    float den = 0.f;
    const int beg = offsets[node], end = offsets[node+1];
    for (int i = beg; i < end; i += 4){
      const int mm = end - i;
      const int i1 = (mm > 1) ? i+1 : i;
      const int i2 = (mm > 2) ? i+2 : i;
      const int i3 = (mm > 3) ? i+3 : i;
      int s0 = ssrc[i], s1 = ssrc[i1], s2 = ssrc[i2], s3 = ssrc[i3];
      unsigned ep0 = *(const unsigned*)(eproj + (size_t)i *128 + c0);
      unsigned ep1 = *(const unsigned*)(eproj + (size_t)i1*128 + c0);
      unsigned ep2 = *(const unsigned*)(eproj + (size_t)i2*128 + c0);
      unsigned ep3 = *(const unsigned*)(eproj + (size_t)i3*128 + c0);
      f32x2 vl0 = bp2v(*(const unsigned*)(xl + (size_t)s0*HID_ + c0));
      f32x2 vl1 = bp2v(*(const unsigned*)(xl + (size_t)s1*HID_ + c0));
      f32x2 vl2 = bp2v(*(const unsigned*)(xl + (size_t)s2*HID_ + c0));
      f32x2 vl3 = bp2v(*(const unsigned*)(xl + (size_t)s3*HID_ + c0));
      f32x2 v0 = vl0 + xrv + bp2v(ep0);
      f32x2 v1 = vl1 + xrv + bp2v(ep1);
      f32x2 v2 = vl2 + xrv + bp2v(ep2);
      f32x2 v3 = vl3 + xrv + bp2v(ep3);
      f32x2 w0 = v0*0.2f, w1 = v1*0.2f, w2 = v2*0.2f, w3 = v3*0.2f;
      v0.x = fmaxf(v0.x,w0.x); v0.y = fmaxf(v0.y,w0.y);
      v1.x = fmaxf(v1.x,w1.x); v1.y = fmaxf(v1.y,w1.y);
      v2.x = fmaxf(v2.x,w2.x); v2.y = fmaxf(v2.y,w2.y);
      v3.x = fmaxf(v3.x,w3.x); v3.y = fmaxf(v3.y,w3.y);
      float sc0 = v0.x*a0 + v0.y*a1;
      float sc1 = v1.x*a0 + v1.y*a1;
      float sc2 = v2.x*a0 + v2.y*a1;
      float sc3 = v3.x*a0 + v3.y*a1;
      sc0 += __shfl_xor(sc0, 1); sc1 += __shfl_xor(sc1, 1); sc2 += __shfl_xor(sc2, 1); sc3 += __shfl_xor(sc3, 1);
      sc0 += __shfl_xor(sc0, 2); sc1 += __shfl_xor(sc1, 2); sc2 += __shfl_xor(sc2, 2); sc3 += __shfl_xor(sc3, 2);
      sc0 += __shfl_xor(sc0, 4); sc1 += __shfl_xor(sc1, 4); sc2 += __shfl_xor(sc2, 4); sc3 += __shfl_xor(sc3, 4);
      sc0 += __shfl_xor(sc0, 8); sc1 += __shfl_xor(sc1, 8); sc2 += __shfl_xor(sc2, 8); sc3 += __shfl_xor(sc3, 8);
      float p0 = __expf(sc0);
      float p1 = (mm > 1) ? __expf(sc1) : 0.f;
      float p2 = (mm > 2) ? __expf(sc2) : 0.f;
      float p3 = (mm > 3) ? __expf(sc3) : 0.f;
      accv += p0*vl0 + p1*vl1 + p2*vl2 + p3*vl3;
      den  += p0 + p1 + p2 + p3;
    }
    float inv = 1.0f / (den + 1e-16f);
    xr_aggr[(size_t)node*64 + lane] = packbf(accv.x*inv, accv.y*inv);
  }
}

// ---------------- BN stats (bf16 aggr input) ----------------
__global__ __launch_bounds__(256) void k_bn_stats(const unsigned* __restrict__ aggr_b,
                                                  float* __restrict__ stats){
  __shared__ float redS[4][128], redQ[4][128];
  const int t = threadIdx.x;
  const int p = t & 63, rg = t >> 6;
  const int c0 = p*2;
  float s0=0.f, s1=0.f, q0=0.f, q1=0.f;
  for (int r = blockIdx.x*4 + rg; r < N_NODES; r += gridDim.x*4){
    float2 v = bp2f(aggr_b[(size_t)r*64 + p]);
    s0 += v.x; s1 += v.y; q0 += v.x*v.x; q1 += v.y*v.y;
  }
  redS[rg][c0] = s0; redS[rg][c0+1] = s1;
  redQ[rg][c0] = q0; redQ[rg][c0+1] = q1;
  __syncthreads();
  if (rg == 0){
    #pragma unroll
    for (int g=1; g<4; g++){
      s0 += redS[g][c0]; s1 += redS[g][c0+1];
      q0 += redQ[g][c0]; q1 += redQ[g][c0+1];
    }
    atomicAdd(&stats[c0],     s0);
    atomicAdd(&stats[c0+1],   s1);
    atomicAdd(&stats[128+c0],   q0);
    atomicAdd(&stats[128+c0+1], q1);
  }
}

// ---------------- BN apply + ELU (+ residual), bf16 in/out ----------------
__global__ __launch_bounds__(256) void k_bn_apply(const unsigned* __restrict__ aggr_b,
                                                  const float* __restrict__ stats,
                                                  const float* __restrict__ gamma,
                                                  const float* __restrict__ beta,
                                                  u16* __restrict__ h, int residual){
  size_t i = (size_t)blockIdx.x*256 + threadIdx.x;
  if (i >= (size_t)N_NODES*64) return;
  int c = (int)((i & 63)*2);
  const float invn = 1.0f / (float)N_NODES;
  float mu0  = stats[c]   * invn,  mu1  = stats[c+1]   * invn;
  float var0 = stats[128+c]*invn - mu0*mu0;
  float var1 = stats[129+c]*invn - mu1*mu1;
  float sc0 = rsqrtf(var0 + 1e-5f) * gamma[c];
  float sc1 = rsqrtf(var1 + 1e-5f) * gamma[c+1];
  float2 v = bp2f(aggr_b[i]);
  float val0 = (v.x - mu0) * sc0 + beta[c];
  float val1 = (v.y - mu1) * sc1 + beta[c+1];
  val0 = val0 > 0.f ? val0 : expm1f(val0);
  val1 = val1 > 0.f ? val1 : expm1f(val1);
  unsigned* hp = (unsigned*)h + i;
  if (residual){
    float2 hv = bp2f(*hp);
    val0 += hv.x; val1 += hv.y;
  }
  *hp = packbf(val0, val1);
}

// ---------------- Pool: segmented mean, 4 row-groups in flight ----------------
__global__ __launch_bounds__(256) void k_pool_seg(const unsigned* __restrict__ h2,
                                                  const int* __restrict__ goff,
                                                  float* __restrict__ emb){
  __shared__ float redS[4][128];
  const int g = blockIdx.x, t = threadIdx.x;
  const int p = t & 63, rg = t >> 6;
  const int beg = goff[g], end = goff[g+1];
  float a0 = 0.f, a1 = 0.f;
  for (int r = beg + rg; r < end; r += 4){
    float2 v = bp2f(h2[(size_t)r*64 + p]);
    a0 += v.x; a1 += v.y;
  }
  redS[rg][p*2] = a0; redS[rg][p*2+1] = a1;
  __syncthreads();
  if (rg == 0){
    #pragma unroll
    for (int k=1;k<4;k++){ a0 += redS[k][p*2]; a1 += redS[k][p*2+1]; }
    float n = fmaxf((float)(end - beg), 1.f);
    emb[(size_t)g*HID_ + p*2]     = a0 / n;
    emb[(size_t)g*HID_ + p*2 + 1] = a1 / n;
  }
}

// ---------------- Per-task heads: 8 graphs per block ----------------
#define HG 8
__global__ __launch_bounds__(128) void k_heads(const float* __restrict__ emb,
                                               const float* __restrict__ mf,
                                               const int* __restrict__ fpi,
                                               const float* __restrict__ tw1,
                                               const float* __restrict__ tb1,
                                               const float* __restrict__ tw2,
                                               const float* __restrict__ tb2,
                                               float* __restrict__ out){
  const int task = blockIdx.y, g0 = blockIdx.x*HG;
  const int j = threadIdx.x;
  __shared__ float fused[HG][160];
  __shared__ float red[HG][128];
  for (int idx = j; idx < HG*160; idx += 128){
    int g = idx / 160, i = idx % 160;
    float v;
    if (i < 128) v = emb[(size_t)(g0+g)*HID_ + i];
    else         v = mf[(size_t)(g0+g)*2048 + fpi[task*32 + (i-128)]];
    fused[g][i] = v;
  }
  __syncthreads();
  const float* w1 = tw1 + (size_t)task*160*128;
  float acc[HG];
  float b1 = tb1[task*128 + j];
  #pragma unroll
  for (int g=0; g<HG; g++) acc[g] = b1;
  for (int i=0; i<160; i++){
    float wv = w1[(size_t)i*128 + j];
    #pragma unroll
    for (int g=0; g<HG; g++) acc[g] += fused[g][i] * wv;
  }
  float t2 = tw2[task*128 + j];
  #pragma unroll
  for (int g=0; g<HG; g++){
    float v = acc[g] > 0.f ? acc[g] : 0.f;
    red[g][j] = v * t2;
  }
  __syncthreads();
  int g = j >> 4, l16 = j & 15;
  float s = 0.f;
  #pragma unroll
  for (int k=0;k<8;k++) s += red[g][l16 + k*16];
  s += __shfl_xor(s, 1, 16);
  s += __shfl_xor(s, 2, 16);
  s += __shfl_xor(s, 4, 16);
  s += __shfl_xor(s, 8, 16);
  if (l16 == 0) out[(size_t)(g0+g)*N_TASK + task] = s + tb2[task];
}

extern "C" void kernel_launch(void* const* d_in, const int* in_sizes, int n_in,
                              void* d_out, int out_size, void* d_ws, size_t ws_size,
                              hipStream_t stream){
  const float* x    = (const float*)d_in[0];
  const int*   ei   = (const int*)  d_in[1];
  const float* ea   = (const float*)d_in[2];
  const int*   batch= (const int*)  d_in[3];
  const float* mf   = (const float*)d_in[4];
  const int*   fpi  = (const int*)  d_in[5];
  const float* Wl0  = (const float*)d_in[6];
  const float* bl0  = (const float*)d_in[7];
  const float* Wr0  = (const float*)d_in[8];
  const float* br0  = (const float*)d_in[9];
  const float* We0  = (const float*)d_in[10];
  const float* att0 = (const float*)d_in[11];
  const float* g0   = (const float*)d_in[13];
  const float* b0   = (const float*)d_in[14];
  const float* Wl   = (const float*)d_in[15];
  const float* bl   = (const float*)d_in[16];
  const float* Wr   = (const float*)d_in[17];
  const float* br   = (const float*)d_in[18];
  const float* We   = (const float*)d_in[19];
  const float* att  = (const float*)d_in[20];
  const float* gg   = (const float*)d_in[22];
  const float* bb   = (const float*)d_in[23];
  const float* tw1  = (const float*)d_in[24];
  const float* tb1  = (const float*)d_in[25];
  const float* tw2  = (const float*)d_in[26];
  const float* tb2  = (const float*)d_in[27];
  float* out = (float*)d_out;

  char* w = (char*)d_ws;
  auto alloc = [&](size_t bytes)->char*{ char* r = w; w += (bytes + 255) & ~(size_t)255; return r; };
  u16*   xl     = (u16*)  alloc((size_t)N_NODES*HID_*2);
  unsigned* xr_aggr = (unsigned*)alloc((size_t)N_NODES*64*4);
  u16*   h      = (u16*)  alloc((size_t)N_NODES*HID_*2);
  u16*   ea32   = (u16*)  alloc((size_t)N_EDGES*32*2);
  int*   counts = (int*)  alloc((size_t)N_NODES*4);
  float* stats4 = (float*)alloc(4*256*4);
  int*   offsets= (int*)  alloc((size_t)(N_NODES+1)*4);
  int*   cursor = (int*)  alloc((size_t)N_NODES*4);
  int*   incl   = (int*)  alloc((size_t)N_NODES*4);
  int*   bsum   = (int*)  alloc(256*4);
  int*   ssrc   = (int*)  alloc((size_t)N_EDGES*4);
  int*   goff   = (int*)  alloc((size_t)(N_GRAPH+1)*4);
  float* emb    = (float*)alloc((size_t)N_GRAPH*HID_*4);
  u16*   Wzl0   = (u16*)  alloc((size_t)F_NODE_*128*2);
  u16*   Wzr0   = (u16*)  alloc((size_t)F_NODE_*128*2);
  u16*   Wzl123 = (u16*)  alloc((size_t)3*HID_*128*2);
  u16*   Wzr123 = (u16*)  alloc((size_t)3*HID_*128*2);
  u16*   Wez4   = (u16*)  alloc((size_t)4*32*128*2);
  u16*   eproj  = (u16*)  alloc((size_t)N_EDGES*HID_*2);
  u16* xbf = eproj;

  const size_t zlen = (size_t)((char*)(stats4 + 4*256) - (char*)counts);
  const int nscan = (N_NODES + 511)/512;

  // prelude
  {
    WZ12 p;
    p.src[0] = Wl0; p.dst[0] = Wzl0; p.Ks[0] = F_NODE_; p.Kd[0] = F_NODE_;
    p.src[1] = Wr0; p.dst[1] = Wzr0; p.Ks[1] = F_NODE_; p.Kd[1] = F_NODE_;
    for (int i=0;i<3;i++){
      p.src[2+i] = Wl + (size_t)i*HID_*HID_; p.dst[2+i] = Wzl123 + (size_t)i*HID_*128; p.Ks[2+i] = HID_; p.Kd[2+i] = HID_;
      p.src[5+i] = Wr + (size_t)i*HID_*HID_; p.dst[5+i] = Wzr123 + (size_t)i*HID_*128; p.Ks[5+i] = HID_; p.Kd[5+i] = HID_;
    }
    p.src[8] = We0; p.dst[8] = Wez4; p.Ks[8] = F_EDGE_; p.Kd[8] = 32;
    for (int i=0;i<3;i++){
      p.src[9+i] = We + (size_t)i*F_EDGE_*HID_; p.dst[9+i] = Wez4 + (size_t)(i+1)*32*128; p.Ks[9+i] = F_EDGE_; p.Kd[9+i] = 32;
    }
    hipLaunchKernelGGL(k_wswz_all, dim3((HID_*128 + 255)/256, 12), dim3(256), 0, stream, p);
  }
  hipMemsetAsync(counts, 0, zlen, stream);
  hipLaunchKernelGGL(k_cast_hist, dim3(CAST_BLKS + EG256), dim3(256), 0, stream, x, xbf, ei, counts);
  hipLaunchKernelGGL(k_scan1,  dim3(nscan), dim3(512), 0, stream, counts, incl, bsum);
  hipLaunchKernelGGL(k_scan2,  dim3(1),     dim3(256), 0, stream, bsum, nscan, batch, goff);
  hipLaunchKernelGGL(k_scan3,  dim3(nscan), dim3(512), 0, stream, counts, incl, bsum, offsets, cursor);
  hipLaunchKernelGGL(k_scatter,dim3(EG256), dim3(256), 0, stream, ei, cursor, ssrc, ea, ea32);

  for (int layer = 0; layer < 4; layer++){
    const float *bl_, *br_, *att_, *g_, *b_;
    const u16 *Wzl_, *Wzr_, *Ain;
    int K;
    if (layer == 0){
      bl_=bl0; br_=br0; att_=att0; g_=g0; b_=b0;
      Wzl_ = Wzl0; Wzr_ = Wzr0; Ain = xbf; K = F_NODE_;
    } else {
      int i = layer - 1;
      bl_ = bl + (size_t)i*HID_;  br_ = br + (size_t)i*HID_;
      att_= att + (size_t)i*HID_;
      g_  = gg + (size_t)i*HID_;  b_  = bb + (size_t)i*HID_;
      Wzl_ = Wzl123 + (size_t)i*HID_*128;
      Wzr_ = Wzr123 + (size_t)i*HID_*128;
      Ain = h; K = HID_;
    }
    float* stats = stats4 + layer*256;
    hipLaunchKernelGGL(k_gemm_eproj, dim3(2*GEMM_GRID + EPROJ_GRID), dim3(256), 0, stream,
                       Ain, Wzl_, Wzr_, bl_, br_, xl, (u16*)xr_aggr, N_NODES, K,
                       ea32, Wez4 + (size_t)layer*32*128, eproj);
    hipLaunchKernelGGL(k_gat_ep, dim3(GAT_GRID), dim3(256), 0, stream,
                       xl, xr_aggr, eproj, att_, offsets, ssrc);
    hipLaunchKernelGGL(k_bn_stats, dim3(512), dim3(256), 0, stream, xr_aggr, stats);
    hipLaunchKernelGGL(k_bn_apply, dim3((N_NODES*64 + 255)/256), dim3(256), 0, stream,
                       xr_aggr, stats, g_, b_, h, layer > 0 ? 1 : 0);
  }
  hipLaunchKernelGGL(k_pool_seg, dim3(N_GRAPH), dim3(256), 0, stream, (const unsigned*)h, goff, emb);
  hipLaunchKernelGGL(k_heads, dim3(N_GRAPH/HG, N_TASK), dim3(128), 0, stream, emb, mf, fpi, tw1, tb1, tw2, tb2, out);
}